// Round 20
// baseline (488.779 us; speedup 1.0000x reference)
//
#include <hip/hip_runtime.h>
#include <hip/hip_bf16.h>
#include <math.h>

// Problem constants
constexpr int Bn = 4, Cn = 256, Hn = 48, Wn = 48, HW = 2304;
constexpr float ATT_SCALE = 0.17677669529663687f;  // 1/sqrt(32)

typedef __attribute__((ext_vector_type(8))) short bf16x8;
typedef __attribute__((ext_vector_type(4))) float f32x4;

#define MFMA16(A, B, C) __builtin_amdgcn_mfma_f32_16x16x32_bf16(A, B, C, 0, 0, 0)

// ---------------- GroupNorm two-phase ----------------
__global__ void gn1_kernel(const float* __restrict__ x, float* __restrict__ part) {
  int bg = blockIdx.x >> 2, ck = blockIdx.x & 3;
  const float4* xp = (const float4*)(x + (size_t)bg * 18432 + ck * 4608);
  float s = 0.f, ss = 0.f;
  for (int i = threadIdx.x; i < 1152; i += 256) {
    float4 v = xp[i];
    s += v.x + v.y + v.z + v.w;
    ss += v.x * v.x + v.y * v.y + v.z * v.z + v.w * v.w;
  }
#pragma unroll
  for (int off = 32; off; off >>= 1) { s += __shfl_xor(s, off); ss += __shfl_xor(ss, off); }
  __shared__ float rs[4], rss[4];
  int wid = threadIdx.x >> 6;
  if ((threadIdx.x & 63) == 0) { rs[wid] = s; rss[wid] = ss; }
  __syncthreads();
  if (threadIdx.x == 0) {
    part[blockIdx.x * 2] = rs[0] + rs[1] + rs[2] + rs[3];
    part[blockIdx.x * 2 + 1] = rss[0] + rss[1] + rss[2] + rss[3];
  }
}

__global__ void gn2_kernel(const float* __restrict__ x, const float* __restrict__ part,
                           const float* __restrict__ gw, const float* __restrict__ gb,
                           float* __restrict__ y) {
  int bg = blockIdx.x >> 2, ck = blockIdx.x & 3;
  float s = part[bg * 8] + part[bg * 8 + 2] + part[bg * 8 + 4] + part[bg * 8 + 6];
  float ss = part[bg * 8 + 1] + part[bg * 8 + 3] + part[bg * 8 + 5] + part[bg * 8 + 7];
  float mean = s * (1.f / 18432.f);
  float var = ss * (1.f / 18432.f) - mean * mean;
  float inv = rsqrtf(var + 1e-5f);
  int g = bg & 31;
  const float4* xp = (const float4*)(x + (size_t)bg * 18432 + ck * 4608);
  float4* yp = (float4*)(y + (size_t)bg * 18432 + ck * 4608);
  for (int i = threadIdx.x; i < 1152; i += 256) {
    int c = (g << 3) + ((ck * 1152 + i) / 576);
    float w = gw[c] * inv, b = gb[c];
    float4 v = xp[i];
    v.x = (v.x - mean) * w + b; v.y = (v.y - mean) * w + b;
    v.z = (v.z - mean) * w + b; v.w = (v.w - mean) * w + b;
    yp[i] = v;
  }
}

// ---------------- Depthwise 3x3 -> hi/lo bf16 chunk-planar [img][8ci][2304][32] ----------------
__global__ void dw3x3_kernel(const float* __restrict__ in, const float* __restrict__ wd,
                             __hip_bfloat16* __restrict__ oh, __hip_bfloat16* __restrict__ ol) {
  int bc = blockIdx.x;
  int c = bc & 255;
  const float* ip = in + (size_t)bc * HW;
  const size_t ob = ((size_t)((bc >> 8) * 8 + (c >> 5)) * HW) * 32 + (c & 31);
  float w[9];
#pragma unroll
  for (int k = 0; k < 9; ++k) w[k] = wd[c * 9 + k];
  for (int p = threadIdx.x; p < HW; p += 256) {
    int yy = p / 48, xx = p - yy * 48;
    float a = 0.f;
#pragma unroll
    for (int ky = 0; ky < 3; ++ky) {
      int y2 = yy + ky - 1;
      if ((unsigned)y2 < 48u) {
#pragma unroll
        for (int kx = 0; kx < 3; ++kx) {
          int x2 = xx + kx - 1;
          if ((unsigned)x2 < 48u) a += ip[y2 * 48 + x2] * w[ky * 3 + kx];
        }
      }
    }
    __hip_bfloat16 h = __float2bfloat16(a);
    oh[ob + (size_t)p * 32] = h;
    ol[ob + (size_t)p * 32] = __float2bfloat16(a - __bfloat162float(h));
  }
}

// ---------------- pack 1x1 weights f32 [O][256] -> chunk-planar hi/lo bf16 [(c/32)][O][32] ----------------
__global__ void pwpack_kernel(const float* __restrict__ w, __hip_bfloat16* __restrict__ WH,
                              __hip_bfloat16* __restrict__ WL, int O) {
  int q = blockIdx.x * 256 + threadIdx.x;   // o*256 + c
  int o = q >> 8, c = q & 255;
  float v = w[q];
  __hip_bfloat16 h = __float2bfloat16(v);
  size_t idx = ((size_t)(c >> 5) * O + o) * 32 + (c & 31);
  WH[idx] = h;
  WL[idx] = __float2bfloat16(v - __bfloat162float(h));
}

// ---------------- Pointwise 1x1 conv v5: LDS-free hi/lo MFMA GEMM ----------------
template <bool RES>
__global__ void __launch_bounds__(256)
pw5_kernel(const __hip_bfloat16* __restrict__ XH, const __hip_bfloat16* __restrict__ XL,
           const __hip_bfloat16* __restrict__ WH, const __hip_bfloat16* __restrict__ WL,
           const float* __restrict__ bias, const float* __restrict__ res, size_t res_bs,
           float* __restrict__ out, size_t out_bs, int CO) {
  const int tid = threadIdx.x;
  const int wv = tid >> 6, lane = tid & 63, lm = lane & 15, kg = lane >> 4;
  const int px0 = blockIdx.x * 128;
  const int ob = blockIdx.y * 64;
  const int img = blockIdx.z;

  f32x4 acc[4][2];
#pragma unroll
  for (int mt = 0; mt < 4; ++mt) {
    acc[mt][0] = (f32x4){0.f, 0.f, 0.f, 0.f};
    acc[mt][1] = (f32x4){0.f, 0.f, 0.f, 0.f};
  }

  const size_t bb = (size_t)img * 589824 + (size_t)(px0 + wv * 32 + lm) * 32 + kg * 8;
#pragma unroll
  for (int ci = 0; ci < 8; ++ci) {
    const size_t bo = bb + (size_t)ci * 73728;
    bf16x8 BH0 = *(const bf16x8*)(XH + bo);
    bf16x8 BH1 = *(const bf16x8*)(XH + bo + 512);
    bf16x8 BL0 = *(const bf16x8*)(XL + bo);
    bf16x8 BL1 = *(const bf16x8*)(XL + bo + 512);
    const size_t wb = ((size_t)ci * CO + ob + lm) * 32 + kg * 8;
#pragma unroll
    for (int mt = 0; mt < 4; ++mt) {
      bf16x8 AH = *(const bf16x8*)(WH + wb + mt * 512);
      bf16x8 AL = *(const bf16x8*)(WL + wb + mt * 512);
      acc[mt][0] = MFMA16(AH, BH0, acc[mt][0]);
      acc[mt][0] = MFMA16(AH, BL0, acc[mt][0]);
      acc[mt][0] = MFMA16(AL, BH0, acc[mt][0]);
      acc[mt][1] = MFMA16(AH, BH1, acc[mt][1]);
      acc[mt][1] = MFMA16(AH, BL1, acc[mt][1]);
      acc[mt][1] = MFMA16(AL, BH1, acc[mt][1]);
    }
  }

#pragma unroll
  for (int mt = 0; mt < 4; ++mt) {
#pragma unroll
    for (int g = 0; g < 2; ++g) {
      int px = px0 + wv * 32 + g * 16 + lm;
#pragma unroll
      for (int r = 0; r < 4; ++r) {
        int o = ob + mt * 16 + kg * 4 + r;
        float v = acc[mt][g][r] + bias[o];
        if (RES) v += res[(size_t)img * res_bs + (size_t)o * HW + px];
        out[(size_t)img * out_bs + (size_t)o * HW + px] = v;
      }
    }
  }
}

// ---------------- L2 norm over 256 channels, in place (4 cgroups x 64 px) ----------------
__global__ void l2n_kernel(float* __restrict__ t, size_t bstride) {
  int pxl = threadIdx.x & 63;
  int cg = threadIdx.x >> 6;
  int p = blockIdx.x * 64 + pxl;
  float* q = t + (size_t)blockIdx.y * bstride + p;
  float ss = 0.f;
#pragma unroll 8
  for (int c = cg * 64; c < cg * 64 + 64; ++c) { float v = q[(size_t)c * HW]; ss += v * v; }
  __shared__ float part[4][64];
  __shared__ float sinv[64];
  part[cg][pxl] = ss;
  __syncthreads();
  if (threadIdx.x < 64) {
    float tot = part[0][pxl] + part[1][pxl] + part[2][pxl] + part[3][pxl];
    sinv[pxl] = 1.f / fmaxf(sqrtf(tot), 1e-12f);
  }
  __syncthreads();
  float inv = sinv[pxl];
#pragma unroll 8
  for (int c = cg * 64; c < cg * 64 + 64; ++c) q[(size_t)c * HW] *= inv;
}

// ---------------- DFT matrix setup: bf16 hi/lo tables in ws ----------------
__global__ void dftmat_kernel(__hip_bfloat16* __restrict__ mt) {
  int t = blockIdx.x * 256 + threadIdx.x;
  const float TP = 6.283185307179586f;
  if (t < 4096) {
    int up = t >> 6, w = t & 63;
    float v = 0.f;
    if (w < 48 && up < 50) {
      int u = (up < 25) ? up : up - 25;
      float ang = TP * (float)((w * u) % 48) / 48.f;
      v = ((up < 25) ? cosf(ang) : -sinf(ang)) * (1.f / 48.f);
    }
    __hip_bfloat16 h = __float2bfloat16(v);
    mt[t] = h; mt[4096 + t] = __float2bfloat16(v - __bfloat162float(h));
  } else if (t < 7168) {
    int q = t - 4096;
    int vv = q >> 6, h = q & 63;
    float c = 0.f, s = 0.f;
    if (h < 48) {
      float ang = TP * (float)((vv * h) % 48) / 48.f;
      c = cosf(ang); s = sinf(ang);
    }
    __hip_bfloat16 ch = __float2bfloat16(c);
    mt[8192 + q] = ch; mt[11264 + q] = __float2bfloat16(c - __bfloat162float(ch));
    __hip_bfloat16 sh = __float2bfloat16(s);
    mt[14336 + q] = sh; mt[17408 + q] = __float2bfloat16(s - __bfloat162float(sh));
  } else if (t < 8704) {
    int q = t - 7168;
    int w = q >> 5, u = q & 31;
    float c = 0.f, s = 0.f;
    if (u < 25) {
      float ang = TP * (float)((u * w) % 48) / 48.f;
      c = cosf(ang); s = -sinf(ang);
    }
    __hip_bfloat16 ch = __float2bfloat16(c);
    mt[20480 + q] = ch; mt[22016 + q] = __float2bfloat16(c - __bfloat162float(ch));
    __hip_bfloat16 sh = __float2bfloat16(s);
    mt[23552 + q] = sh; mt[25088 + q] = __float2bfloat16(s - __bfloat162float(sh));
  }
}

// ---------------- rfft2 via MFMA (hi/lo split ~= fp32) + abs/angle -> bf16 ----------------
template <bool TLAY>
__global__ void __launch_bounds__(256)
rfft2_mfma(const float* __restrict__ in, size_t bstride, const __hip_bfloat16* __restrict__ mt,
           __hip_bfloat16* __restrict__ amp, __hip_bfloat16* __restrict__ pha) {
  const int bc = blockIdx.x;
  const int bi = bc >> 8, ch = bc & 255;
  const float* ip = in + (size_t)bi * bstride + (size_t)ch * HW;
  __shared__ __align__(16) __hip_bfloat16 XH[48 * 72], XL[48 * 72];
  __shared__ __align__(16) __hip_bfloat16 Yt[4][32 * 72];  // 0 reH 1 reL 2 imH 3 imL; [u][h]
  const int tid = threadIdx.x;
  const int lane = tid & 63, lm = lane & 15, kg = lane >> 4, wv = tid >> 6;

  for (int i = tid; i < 48 * 72; i += 256) {
    int r = i / 72, w = i - r * 72;
    float v = (w < 48) ? ip[r * 48 + w] : 0.f;
    __hip_bfloat16 h = __float2bfloat16(v);
    XH[i] = h;
    XL[i] = __float2bfloat16(v - __bfloat162float(h));
  }
  for (int i = tid; i < 4 * 32 * 72; i += 256) ((unsigned short*)Yt)[i] = 0;
  __syncthreads();

  {
    const __hip_bfloat16* W1TH = mt;
    const __hip_bfloat16* W1TL = mt + 4096;
    const int brow = wv * 16 + lm;
    bf16x8 BH0 = *(const bf16x8*)(W1TH + brow * 64 + kg * 8);
    bf16x8 BH1 = *(const bf16x8*)(W1TH + brow * 64 + 32 + kg * 8);
    bf16x8 BL0 = *(const bf16x8*)(W1TL + brow * 64 + kg * 8);
    bf16x8 BL1 = *(const bf16x8*)(W1TL + brow * 64 + 32 + kg * 8);
#pragma unroll
    for (int mtI = 0; mtI < 3; ++mtI) {
      f32x4 acc = {0.f, 0.f, 0.f, 0.f};
      bf16x8 AH = *(const bf16x8*)(&XH[(mtI * 16 + lm) * 72 + kg * 8]);
      bf16x8 AL = *(const bf16x8*)(&XL[(mtI * 16 + lm) * 72 + kg * 8]);
      acc = MFMA16(AH, BH0, acc); acc = MFMA16(AH, BL0, acc); acc = MFMA16(AL, BH0, acc);
      AH = *(const bf16x8*)(&XH[(mtI * 16 + lm) * 72 + 32 + kg * 8]);
      AL = *(const bf16x8*)(&XL[(mtI * 16 + lm) * 72 + 32 + kg * 8]);
      acc = MFMA16(AH, BH1, acc); acc = MFMA16(AH, BL1, acc); acc = MFMA16(AL, BH1, acc);
      if (brow < 50) {
        int aidx = (brow < 25) ? 0 : 2;
        int u = (brow < 25) ? brow : brow - 25;
#pragma unroll
        for (int r = 0; r < 4; ++r) {
          int h = mtI * 16 + kg * 4 + r;
          float v = acc[r];
          __hip_bfloat16 hh = __float2bfloat16(v);
          Yt[aidx][u * 72 + h] = hh;
          Yt[aidx + 1][u * 72 + h] = __float2bfloat16(v - __bfloat162float(hh));
        }
      }
    }
  }
  __syncthreads();

  {
    const __hip_bfloat16* M2CH = mt + 8192;
    const __hip_bfloat16* M2CL = mt + 11264;
    const __hip_bfloat16* M2SH = mt + 14336;
    const __hip_bfloat16* M2SL = mt + 17408;
    for (int t = wv; t < 6; t += 4) {
      int mtI = t >> 1, ntI = t & 1;
      f32x4 aC1 = {0.f,0.f,0.f,0.f}, aS1 = {0.f,0.f,0.f,0.f};
      f32x4 aC2 = {0.f,0.f,0.f,0.f}, aS2 = {0.f,0.f,0.f,0.f};
#pragma unroll
      for (int ks = 0; ks < 2; ++ks) {
        int arow = mtI * 16 + lm;
        int k0 = ks * 32 + kg * 8;
        bf16x8 CH = *(const bf16x8*)(M2CH + arow * 64 + k0);
        bf16x8 CL = *(const bf16x8*)(M2CL + arow * 64 + k0);
        bf16x8 SH = *(const bf16x8*)(M2SH + arow * 64 + k0);
        bf16x8 SL = *(const bf16x8*)(M2SL + arow * 64 + k0);
        int brow = ntI * 16 + lm;
        bf16x8 ReH = *(const bf16x8*)(&Yt[0][brow * 72 + k0]);
        bf16x8 ReL = *(const bf16x8*)(&Yt[1][brow * 72 + k0]);
        bf16x8 ImH = *(const bf16x8*)(&Yt[2][brow * 72 + k0]);
        bf16x8 ImL = *(const bf16x8*)(&Yt[3][brow * 72 + k0]);
        aC1 = MFMA16(CH, ReH, aC1); aC1 = MFMA16(CH, ReL, aC1); aC1 = MFMA16(CL, ReH, aC1);
        aS2 = MFMA16(SH, ImH, aS2); aS2 = MFMA16(SH, ImL, aS2); aS2 = MFMA16(SL, ImH, aS2);
        aC2 = MFMA16(CH, ImH, aC2); aC2 = MFMA16(CH, ImL, aC2); aC2 = MFMA16(CL, ImH, aC2);
        aS1 = MFMA16(SH, ReH, aS1); aS1 = MFMA16(SH, ReL, aS1); aS1 = MFMA16(SL, ReH, aS1);
      }
      int u = ntI * 16 + lm;
      if (u < 25) {
#pragma unroll
        for (int r = 0; r < 4; ++r) {
          int v = mtI * 16 + kg * 4 + r;
          float zre = aC1[r] + aS2[r];
          float zim = aC2[r] - aS1[r];
          float am = sqrtf(zre * zre + zim * zim);
          float ph = atan2f(zim, zre);
          int i = v * 25 + u;
          size_t o;
          if (TLAY) o = ((size_t)(bc >> 5) * 1200 + i) * 32 + (bc & 31);
          else      o = (size_t)bc * 1200 + i;
          amp[o] = __float2bfloat16(am);
          pha[o] = __float2bfloat16(ph);
        }
      }
    }
  }
}

// ---------------- polar + irfft2 via MFMA -> hi/lo bf16 chunk-planar ----------------
__global__ void __launch_bounds__(256)
polar_irfft2_mfma(const float* __restrict__ amp, const float* __restrict__ pha,
                  const __hip_bfloat16* __restrict__ mt,
                  __hip_bfloat16* __restrict__ oh, __hip_bfloat16* __restrict__ ol) {
  const int bc = blockIdx.x;
  __shared__ __align__(16) __hip_bfloat16 Zt[4][32 * 72];
  __shared__ __align__(16) __hip_bfloat16 Yp[4][48 * 56];
  const int tid = threadIdx.x;
  const int lane = tid & 63, lm = lane & 15, kg = lane >> 4, wv = tid >> 6;

  for (int i = tid; i < 4 * 32 * 72; i += 256) ((unsigned short*)Zt)[i] = 0;
  for (int i = tid; i < 4 * 48 * 56; i += 256) ((unsigned short*)Yp)[i] = 0;
  __syncthreads();
  for (int i = tid; i < 1200; i += 256) {
    int v = i / 25, u = i - v * 25;
    float a = amp[(size_t)bc * 1200 + i];
    float p = pha[(size_t)bc * 1200 + i];
    float sc = (u == 0 || u == 24) ? (1.f / 48.f) : (2.f / 48.f);
    float zre = a * cosf(p) * sc;
    float zim = a * sinf(p) * sc;
    __hip_bfloat16 h0 = __float2bfloat16(zre);
    Zt[0][u * 72 + v] = h0;
    Zt[1][u * 72 + v] = __float2bfloat16(zre - __bfloat162float(h0));
    __hip_bfloat16 h1 = __float2bfloat16(zim);
    Zt[2][u * 72 + v] = h1;
    Zt[3][u * 72 + v] = __float2bfloat16(zim - __bfloat162float(h1));
  }
  __syncthreads();

  {
    const __hip_bfloat16* M2CH = mt + 8192;
    const __hip_bfloat16* M2CL = mt + 11264;
    const __hip_bfloat16* M2SH = mt + 14336;
    const __hip_bfloat16* M2SL = mt + 17408;
    for (int t = wv; t < 6; t += 4) {
      int mtI = t >> 1, ntI = t & 1;
      f32x4 aC1 = {0.f,0.f,0.f,0.f}, aS1 = {0.f,0.f,0.f,0.f};
      f32x4 aC2 = {0.f,0.f,0.f,0.f}, aS2 = {0.f,0.f,0.f,0.f};
#pragma unroll
      for (int ks = 0; ks < 2; ++ks) {
        int arow = mtI * 16 + lm;
        int k0 = ks * 32 + kg * 8;
        bf16x8 CH = *(const bf16x8*)(M2CH + arow * 64 + k0);
        bf16x8 CL = *(const bf16x8*)(M2CL + arow * 64 + k0);
        bf16x8 SH = *(const bf16x8*)(M2SH + arow * 64 + k0);
        bf16x8 SL = *(const bf16x8*)(M2SL + arow * 64 + k0);
        int brow = ntI * 16 + lm;
        bf16x8 ReH = *(const bf16x8*)(&Zt[0][brow * 72 + k0]);
        bf16x8 ReL = *(const bf16x8*)(&Zt[1][brow * 72 + k0]);
        bf16x8 ImH = *(const bf16x8*)(&Zt[2][brow * 72 + k0]);
        bf16x8 ImL = *(const bf16x8*)(&Zt[3][brow * 72 + k0]);
        aC1 = MFMA16(CH, ReH, aC1); aC1 = MFMA16(CH, ReL, aC1); aC1 = MFMA16(CL, ReH, aC1);
        aS2 = MFMA16(SH, ImH, aS2); aS2 = MFMA16(SH, ImL, aS2); aS2 = MFMA16(SL, ImH, aS2);
        aC2 = MFMA16(CH, ImH, aC2); aC2 = MFMA16(CH, ImL, aC2); aC2 = MFMA16(CL, ImH, aC2);
        aS1 = MFMA16(SH, ReH, aS1); aS1 = MFMA16(SH, ReL, aS1); aS1 = MFMA16(SL, ReH, aS1);
      }
      int u = ntI * 16 + lm;
      if (u < 25) {
#pragma unroll
        for (int r = 0; r < 4; ++r) {
          int h = mtI * 16 + kg * 4 + r;
          float yre = aC1[r] - aS2[r];
          float yim = aS1[r] + aC2[r];
          __hip_bfloat16 h0 = __float2bfloat16(yre);
          Yp[0][h * 56 + u] = h0;
          Yp[1][h * 56 + u] = __float2bfloat16(yre - __bfloat162float(h0));
          __hip_bfloat16 h1 = __float2bfloat16(yim);
          Yp[2][h * 56 + u] = h1;
          Yp[3][h * 56 + u] = __float2bfloat16(yim - __bfloat162float(h1));
        }
      }
    }
  }
  __syncthreads();

  {
    const __hip_bfloat16* W3CH = mt + 20480;
    const __hip_bfloat16* W3CL = mt + 22016;
    const __hip_bfloat16* W3SH = mt + 23552;   // -sin
    const __hip_bfloat16* W3SL = mt + 25088;
    const int cch = bc & 255;
    const size_t obase = ((size_t)((bc >> 8) * 8 + (cch >> 5)) * HW) * 32 + (cch & 31);
    for (int t = wv; t < 9; t += 4) {
      int mtI = t / 3, ntI = t - (t / 3) * 3;
      f32x4 acc = {0.f, 0.f, 0.f, 0.f};
      int k0 = kg * 8;
      bf16x8 AH = *(const bf16x8*)(&Yp[0][(mtI * 16 + lm) * 56 + k0]);
      bf16x8 AL = *(const bf16x8*)(&Yp[1][(mtI * 16 + lm) * 56 + k0]);
      bf16x8 IH = *(const bf16x8*)(&Yp[2][(mtI * 16 + lm) * 56 + k0]);
      bf16x8 IL = *(const bf16x8*)(&Yp[3][(mtI * 16 + lm) * 56 + k0]);
      int brow = ntI * 16 + lm;
      bf16x8 CH = *(const bf16x8*)(W3CH + brow * 32 + k0);
      bf16x8 CL = *(const bf16x8*)(W3CL + brow * 32 + k0);
      bf16x8 SH = *(const bf16x8*)(W3SH + brow * 32 + k0);
      bf16x8 SL = *(const bf16x8*)(W3SL + brow * 32 + k0);
      acc = MFMA16(AH, CH, acc); acc = MFMA16(AH, CL, acc); acc = MFMA16(AL, CH, acc);
      acc = MFMA16(IH, SH, acc); acc = MFMA16(IH, SL, acc); acc = MFMA16(IL, SH, acc);
#pragma unroll
      for (int r = 0; r < 4; ++r) {
        int h = mtI * 16 + kg * 4 + r;
        int p = h * 48 + brow;
        float v = acc[r];
        __hip_bfloat16 hh = __float2bfloat16(v);
        oh[obase + (size_t)p * 32] = hh;
        ol[obase + (size_t)p * 32] = __float2bfloat16(v - __bfloat162float(hh));
      }
    }
  }
}

// ---------------- MFMA attention v6: v5 loop, 4 independent m-tiles per 256-thread block ----------------
// grid 1200 = 8 XCDs x 150; unit = (lin>>3)*4 + wv in [0,600); pair = xcd*8 + unit/75.
__global__ void __launch_bounds__(256)
attn_mfma6(const __hip_bfloat16* __restrict__ Qb, const __hip_bfloat16* __restrict__ Kb,
           const __hip_bfloat16* __restrict__ Vb, float* __restrict__ Ob) {
  const int tid = threadIdx.x;
  const int wv = tid >> 6;
  const int lane = tid & 63;
  const int lm = lane & 15, kg = lane >> 4;
  const int lin = blockIdx.x;
  const int xcd = lin & 7;
  const int unit = (lin >> 3) * 4 + wv;      // 0..599 within this XCD
  const int pr = xcd * 8 + unit / 75;        // 0..63
  const int m0 = (unit % 75) * 16;
  const int z = pr >> 5;
  const int bh = pr & 31;
  const __hip_bfloat16* Qt = Qb + (size_t)z * 1228800;
  const __hip_bfloat16* Kt = Kb + (size_t)z * 1228800;
  const __hip_bfloat16* Vc = Vb + (size_t)z * 1228800;
  float* Om = Ob + (size_t)z * 1228800;
  __shared__ unsigned short Pl[4][2][16][40];
  __shared__ float fl[4][16];
  __shared__ float linv[4][16];
  const __hip_bfloat16* Qp = Qt + ((size_t)bh * 1200 + m0) * 32;
  const __hip_bfloat16* Kp = Kt + (size_t)bh * 38400;
  const __hip_bfloat16* Vp = Vc + (size_t)bh * 38400;
  const bf16x8 qf = *(const bf16x8*)(Qp + lm * 32 + kg * 8);
  const float Cs = ATT_SCALE * 1.44269504f;

  f32x4 acc0 = {0.f, 0.f, 0.f, 0.f}, acc1 = {0.f, 0.f, 0.f, 0.f};
  float psum = 0.f, mreg = -3.0e38f;

  for (int G = 0; G < 19; ++G) {
    const int n0 = G * 64;
    const bool s3ok = (G < 18);      // keys n0+48..n0+63 valid
    bf16x8 kf0 = *(const bf16x8*)(Kp + (size_t)(n0 + lm) * 32 + kg * 8);
    bf16x8 kf1 = *(const bf16x8*)(Kp + (size_t)(n0 + 16 + lm) * 32 + kg * 8);
    bf16x8 kf2 = *(const bf16x8*)(Kp + (size_t)(n0 + 32 + lm) * 32 + kg * 8);
    f32x4 d0 = {0.f, 0.f, 0.f, 0.f}; d0 = MFMA16(kf0, qf, d0);
    f32x4 d1 = {0.f, 0.f, 0.f, 0.f}; d1 = MFMA16(kf1, qf, d1);
    f32x4 d2 = {0.f, 0.f, 0.f, 0.f}; d2 = MFMA16(kf2, qf, d2);
    f32x4 d3 = {0.f, 0.f, 0.f, 0.f};
    if (s3ok) {
      bf16x8 kf3 = *(const bf16x8*)(Kp + (size_t)(n0 + 48 + lm) * 32 + kg * 8);
      d3 = MFMA16(kf3, qf, d3);
    }
    float tm = fmaxf(fmaxf(fmaxf(d0[0], d0[1]), fmaxf(d0[2], d0[3])),
                     fmaxf(fmaxf(d1[0], d1[1]), fmaxf(d1[2], d1[3])));
    tm = fmaxf(tm, fmaxf(fmaxf(d2[0], d2[1]), fmaxf(d2[2], d2[3])));
    if (s3ok) tm = fmaxf(tm, fmaxf(fmaxf(d3[0], d3[1]), fmaxf(d3[2], d3[3])));
    tm = fmaxf(tm, __shfl_xor(tm, 16));
    tm = fmaxf(tm, __shfl_xor(tm, 32));
    const bool grow = (__ballot(tm > mreg) != 0ull);   // wave-uniform
    if (grow) {
      float nm = fmaxf(mreg, tm);
      float ff = exp2f((mreg - nm) * Cs);
      mreg = nm;
      if (kg == 0) fl[wv][lm] = ff;
      psum *= ff;
    }
    const float mb = mreg * Cs;
    float p0 = exp2f(d0[0] * Cs - mb), p1 = exp2f(d0[1] * Cs - mb);
    float p2 = exp2f(d0[2] * Cs - mb), p3 = exp2f(d0[3] * Cs - mb);
    float p4 = exp2f(d1[0] * Cs - mb), p5 = exp2f(d1[1] * Cs - mb);
    float p6 = exp2f(d1[2] * Cs - mb), p7 = exp2f(d1[3] * Cs - mb);
    float p8 = exp2f(d2[0] * Cs - mb), p9 = exp2f(d2[1] * Cs - mb);
    float pa_ = exp2f(d2[2] * Cs - mb), pb_ = exp2f(d2[3] * Cs - mb);
    float ps = p0 + p1 + p2 + p3 + p4 + p5 + p6 + p7 + p8 + p9 + pa_ + pb_;
    ushort4 w0, w1, w2, w3;
    w0.x = __builtin_bit_cast(unsigned short, __float2bfloat16(p0));
    w0.y = __builtin_bit_cast(unsigned short, __float2bfloat16(p1));
    w0.z = __builtin_bit_cast(unsigned short, __float2bfloat16(p2));
    w0.w = __builtin_bit_cast(unsigned short, __float2bfloat16(p3));
    w1.x = __builtin_bit_cast(unsigned short, __float2bfloat16(p4));
    w1.y = __builtin_bit_cast(unsigned short, __float2bfloat16(p5));
    w1.z = __builtin_bit_cast(unsigned short, __float2bfloat16(p6));
    w1.w = __builtin_bit_cast(unsigned short, __float2bfloat16(p7));
    w2.x = __builtin_bit_cast(unsigned short, __float2bfloat16(p8));
    w2.y = __builtin_bit_cast(unsigned short, __float2bfloat16(p9));
    w2.z = __builtin_bit_cast(unsigned short, __float2bfloat16(pa_));
    w2.w = __builtin_bit_cast(unsigned short, __float2bfloat16(pb_));
    if (s3ok) {
      float pc_ = exp2f(d3[0] * Cs - mb), pd_ = exp2f(d3[1] * Cs - mb);
      float pe_ = exp2f(d3[2] * Cs - mb), pf_ = exp2f(d3[3] * Cs - mb);
      ps += pc_ + pd_ + pe_ + pf_;
      w3.x = __builtin_bit_cast(unsigned short, __float2bfloat16(pc_));
      w3.y = __builtin_bit_cast(unsigned short, __float2bfloat16(pd_));
      w3.z = __builtin_bit_cast(unsigned short, __float2bfloat16(pe_));
      w3.w = __builtin_bit_cast(unsigned short, __float2bfloat16(pf_));
    } else {
      w3.x = w3.y = w3.z = w3.w = 0;
    }
    psum += ps;
    *(ushort4*)(&Pl[wv][0][lm][kg * 4]) = w0;
    *(ushort4*)(&Pl[wv][0][lm][16 + kg * 4]) = w1;
    *(ushort4*)(&Pl[wv][1][lm][kg * 4]) = w2;
    *(ushort4*)(&Pl[wv][1][lm][16 + kg * 4]) = w3;
    if (grow) {
      float4 f4 = *(const float4*)(&fl[wv][kg * 4]);
      acc0[0] *= f4.x; acc0[1] *= f4.y; acc0[2] *= f4.z; acc0[3] *= f4.w;
      acc1[0] *= f4.x; acc1[1] *= f4.y; acc1[2] *= f4.z; acc1[3] *= f4.w;
    }
    bf16x8 pa0 = *(const bf16x8*)(&Pl[wv][0][lm][kg * 8]);
    bf16x8 pa1 = *(const bf16x8*)(&Pl[wv][1][lm][kg * 8]);
    bf16x8 v00 = *(const bf16x8*)(Vp + (size_t)lm * 1200 + n0 + kg * 8);
    bf16x8 v01 = *(const bf16x8*)(Vp + (size_t)(16 + lm) * 1200 + n0 + kg * 8);
    bf16x8 v10 = *(const bf16x8*)(Vp + (size_t)lm * 1200 + n0 + 32 + kg * 8);
    bf16x8 v11 = *(const bf16x8*)(Vp + (size_t)(16 + lm) * 1200 + n0 + 32 + kg * 8);
    acc0 = MFMA16(pa0, v00, acc0);
    acc1 = MFMA16(pa0, v01, acc1);
    acc0 = MFMA16(pa1, v10, acc0);
    acc1 = MFMA16(pa1, v11, acc1);
  }
  psum += __shfl_xor(psum, 16);
  psum += __shfl_xor(psum, 32);
  if (kg == 0) linv[wv][lm] = 1.f / psum;
  __syncthreads();
#pragma unroll
  for (int r = 0; r < 4; ++r) {
    int m = m0 + kg * 4 + r;
    float li = linv[wv][kg * 4 + r];
    Om[(size_t)bh * 38400 + (size_t)lm * 1200 + m] = acc0[r] * li;
    Om[(size_t)bh * 38400 + (size_t)(16 + lm) * 1200 + m] = acc1[r] * li;
  }
}

// ---------------- pack ATT (f32 NCHW) -> bf16 chunk-planar padded [b][8ci][50][50][32] ----------------
__global__ void packx_kernel(const float* __restrict__ in, __hip_bfloat16* __restrict__ xp) {
  int y = blockIdx.x;     // 0..47
  int b = blockIdx.y;     // 0..3
  int c = threadIdx.x;    // 0..255
  const float* ip = in + ((size_t)(b * 256 + c) * 48 + y) * 48;
  __hip_bfloat16* op = xp + ((size_t)(b * 8 + (c >> 5)) * 2500 + (size_t)(y + 1) * 50 + 1) * 32 + (c & 31);
  for (int x = 0; x < 48; ++x) op[x * 32] = __float2bfloat16(ip[x]);
}

// ---------------- pack weights f32 [O][CIN][9] -> bf16 [tap][CIN/32][O][32] ----------------
template <int CIN>
__global__ void packw_kernel(const float* __restrict__ w, __hip_bfloat16* __restrict__ wp, int O) {
  int t = blockIdx.x * 256 + threadIdx.x;   // o*CIN + c
  int o = t / CIN, c = t - o * CIN;
  if (o >= O) return;
  constexpr int NC = CIN / 32;
#pragma unroll
  for (int tap = 0; tap < 9; ++tap)
    wp[(((size_t)tap * NC + (c >> 5)) * O + o) * 32 + (c & 31)] = __float2bfloat16(w[(size_t)t * 9 + tap]);
}

// ---------------- addpack: (a + b) f32 NCHW -> hi/lo bf16 chunk-planar ----------------
__global__ void addpack_kernel(const float* __restrict__ a, const float* __restrict__ b,
                               __hip_bfloat16* __restrict__ oh, __hip_bfloat16* __restrict__ ol) {
  int i = blockIdx.x * 256 + threadIdx.x;   // float4 index over U/4
  float4 x = ((const float4*)a)[i];
  float4 y = ((const float4*)b)[i];
  x.x += y.x; x.y += y.y; x.z += y.z; x.w += y.w;
  int e = i * 4;
  int img = e / 589824, rem = e - img * 589824;
  int c = rem / 2304, px = rem - c * 2304;
  size_t ob = ((size_t)(img * 8 + (c >> 5)) * HW) * 32 + (c & 31);
  float vv[4] = {x.x, x.y, x.z, x.w};
#pragma unroll
  for (int j = 0; j < 4; ++j) {
    __hip_bfloat16 h = __float2bfloat16(vv[j]);
    oh[ob + (size_t)(px + j) * 32] = h;
    ol[ob + (size_t)(px + j) * 32] = __float2bfloat16(vv[j] - __bfloat162float(h));
  }
}

// ---------------- MFMA 3x3 conv v8: LDS-staged chunks (proven: 0 bank conflicts) ----------------
template <int CIN, int CO, bool TO_PAD, int KS>
__global__ void __launch_bounds__(256)
mfconv3x3(const __hip_bfloat16* __restrict__ Xp, const __hip_bfloat16* __restrict__ Wp,
          __hip_bfloat16* __restrict__ Op, float* __restrict__ Of) {
  constexpr int NC = CIN / 32;
  constexpr int KC = NC / KS;
  constexpr int MT = CO / 32;
  const int q = gridDim.x >> 3;
  const int swz = (blockIdx.x & 7) * q + (blockIdx.x >> 3);
  const int mt = swz % MT;
  const int ks = (swz / MT) % KS;
  const int rq = swz / (MT * KS);       // 0..47
  const int img = rq / 12;
  const int y0b = (rq % 12) * 4;
  const int tid = threadIdx.x;
  const int wv = tid >> 6;
  const int y = y0b + wv;
  const int lane = tid & 63;
  const int lm = lane & 15, kg = lane >> 4;
  const int o0 = mt * 32;
  const int ci0 = ks * KC;

  __shared__ __hip_bfloat16 Als[9216];   // [tap][32o][32c]
  __shared__ __hip_bfloat16 Bls[9600];   // [6 rows][50][32c]

  f32x4 acc[2][3];
#pragma unroll
  for (int f = 0; f < 2; ++f)
#pragma unroll
    for (int g = 0; g < 3; ++g) acc[f][g] = (f32x4){0.f, 0.f, 0.f, 0.f};

  for (int ci = 0; ci < KC; ++ci) {
    const int cic = ci0 + ci;
    const size_t wst = ((size_t)cic * CO + o0) * 32;
    const size_t bst = ((size_t)(img * NC + cic) * 2500 + (size_t)y0b * 50) * 32;
    __syncthreads();
    for (int c = tid; c < 2352; c += 256) {
      if (c < 1152) {
        int tap = c >> 7, rem = c & 127;
        float4 v = *(const float4*)(Wp + wst + (size_t)tap * (NC * CO * 32) + rem * 8);
        *(float4*)(&Als[c * 8]) = v;
      } else {
        int c2 = c - 1152;
        float4 v = *(const float4*)(Xp + bst + (size_t)c2 * 8);
        *(float4*)(&Bls[c2 * 8]) = v;
      }
    }
    __syncthreads();
#pragma unroll
    for (int tap = 0; tap < 9; ++tap) {
      const int dy = tap / 3 - 1, dx = tap - (tap / 3) * 3 - 1;
      bf16x8 A0 = *(const bf16x8*)(&Als[tap * 1024 + lm * 32 + kg * 8]);
      bf16x8 A1 = *(const bf16x8*)(&Als[tap * 1024 + 512 + lm * 32 + kg * 8]);
      const int bbase = ((wv + 1 + dy) * 50 + 1 + dx + lm) * 32 + kg * 8;
      bf16x8 B0 = *(const bf16x8*)(&Bls[bbase]);
      bf16x8 B1 = *(const bf16x8*)(&Bls[bbase + 512]);
      bf16x8 B2 = *(const bf16x8*)(&Bls[bbase + 1024]);
      acc[0][0] = MFMA16(A0, B0, acc[0][0]);
      acc[0][1] = MFMA16(A0, B1, acc[0][1]);
      acc[0][2] = MFMA16(A0, B2, acc[0][2]);
      acc[1][0] = MFMA16(A1, B0, acc[1][0]);
      acc[1][1] = MFMA16(A1, B1, acc[1][1]);
      acc[1][2] = MFMA16(A1, B2, acc[1][2]);
    }
  }

  if (TO_PAD) {
    const int cio = o0 >> 5;
#pragma unroll
    for (int f = 0; f < 2; ++f) {
      const int cc = f * 16 + kg * 4;
#pragma unroll
      for (int g = 0; g < 3; ++g) {
        int x = g * 16 + lm;
        ushort4 st;
        float v0 = acc[f][g][0], v1 = acc[f][g][1], v2 = acc[f][g][2], v3 = acc[f][g][3];
        v0 = v0 / (1.f + __expf(-v0)); v1 = v1 / (1.f + __expf(-v1));
        v2 = v2 / (1.f + __expf(-v2)); v3 = v3 / (1.f + __expf(-v3));
        st.x = __builtin_bit_cast(unsigned short, __float2bfloat16(v0));
        st.y = __builtin_bit_cast(unsigned short, __float2bfloat16(v1));
        st.z = __builtin_bit_cast(unsigned short, __float2bfloat16(v2));
        st.w = __builtin_bit_cast(unsigned short, __float2bfloat16(v3));
        *(ushort4*)(Op + (((size_t)(img * (CO / 32) + cio) * 2500 + (size_t)(y + 1) * 50 + (x + 1)) * 32 + cc)) = st;
      }
    }
  } else {
    float* Ofp = Of + (size_t)ks * 4 * CO * HW;
#pragma unroll
    for (int f = 0; f < 2; ++f)
#pragma unroll
      for (int g = 0; g < 3; ++g) {
        int x = g * 16 + lm;
#pragma unroll
        for (int r = 0; r < 4; ++r) {
          int o = o0 + f * 16 + kg * 4 + r;
          Ofp[((size_t)img * CO + o) * HW + y * 48 + x] = acc[f][g][r];
        }
      }
  }
}

extern "C" void kernel_launch(void* const* d_in, const int* in_sizes, int n_in,
                              void* d_out, int out_size, void* d_ws, size_t ws_size,
                              hipStream_t stream) {
  (void)in_sizes; (void)n_in; (void)out_size; (void)ws_size;
  const float* x      = (const float*)d_in[0];
  const float* cond   = (const float*)d_in[1];
  const float* gn_w   = (const float*)d_in[2];
  const float* gn_b   = (const float*)d_in[3];
  const float* q_dw   = (const float*)d_in[4];
  const float* q_pw_w = (const float*)d_in[5];
  const float* q_pw_b = (const float*)d_in[6];
  const float* kv_dw  = (const float*)d_in[7];
  const float* kv_pw_w= (const float*)d_in[8];
  const float* kv_pw_b= (const float*)d_in[9];
  const float* ao_w   = (const float*)d_in[10];
  const float* ao_b   = (const float*)d_in[11];
  const float* w1     = (const float*)d_in[12];
  const float* w2     = (const float*)d_in[13];
  const float* w3     = (const float*)d_in[14];
  const float* b3     = (const float*)d_in[15];
  float* ws = (float*)d_ws;
  float* Yo = (float*)d_out;

  const size_t U = 2359296;   // 4*256*48*48 (floats)
  const size_t Hf = 1228800;  // 4*256*48*25 (floats)
  const size_t CS = 589824;   // 256*2304
  const size_t CS2 = 1179648; // 512*2304

  float* XN  = ws;             // [0,U)
  __hip_bfloat16* DWH = (__hip_bfloat16*)(ws + U);       // [U,2U) as 2x bf16 planes
  __hip_bfloat16* DWL = DWH + 2359296;
  float* Qb  = ws + 2 * U;
  float* KV  = ws + 3 * U;     // 2U extent
  __hip_bfloat16* AQT = (__hip_bfloat16*)(ws + 5 * U);
  __hip_bfloat16* PQT = AQT + 1228800;
  __hip_bfloat16* AKT = AQT + 2 * 1228800;
  __hip_bfloat16* PKT = AQT + 3 * 1228800;
  __hip_bfloat16* AVc = AQT + 4 * 1228800;
  __hip_bfloat16* PVc = AQT + 5 * 1228800;
  float* AO  = ws + 5 * U + 3 * Hf;
  float* PO  = AO + Hf;
  __hip_bfloat16* OUTH = (__hip_bfloat16*)(ws + U);      // reuse dead DW region
  __hip_bfloat16* OUTL = OUTH + 2359296;
  float* ATT = ws + 5 * U;
  __hip_bfloat16* Xp1 = (__hip_bfloat16*)(ws + U);
  __hip_bfloat16* Xp2 = (__hip_bfloat16*)(ws + 2 * U);
  __hip_bfloat16* Wp1 = (__hip_bfloat16*)(ws + 2 * U + 2600000);
  __hip_bfloat16* Wp2 = (__hip_bfloat16*)(ws + 2 * U + 3200000);
  float* H2  = ws;             // K-split partial 0 at [0,U); partial 1 at [U,2U)
  float* H2b = ws + U;
  __hip_bfloat16* H2H = (__hip_bfloat16*)(ws + 5 * U + 3 * Hf);  // reuse dead AO/PO
  __hip_bfloat16* H2L = H2H + 2359296;
  // pw weights (chunk-planar hi/lo bf16) + DFT matrices + gn partials in dead tail
  __hip_bfloat16* BW = (__hip_bfloat16*)(ws + 5 * U + 5 * Hf);
  __hip_bfloat16* QWH = BW,            * QWL = BW + 65536;
  __hip_bfloat16* KWH = BW + 131072,   * KWL = BW + 262144;
  __hip_bfloat16* AWH = BW + 393216,   * AWL = BW + 458752;
  __hip_bfloat16* W3H = BW + 524288,   * W3L = BW + 589824;
  __hip_bfloat16* MT  = BW + 655360;   // 26624 bf16
  float* GNP = ws + 5 * U + 5 * Hf + 341000;   // 1024 floats

  // 0. one-time-per-launch precompute
  pwpack_kernel<<<256, 256, 0, stream>>>(q_pw_w, QWH, QWL, 256);
  pwpack_kernel<<<512, 256, 0, stream>>>(kv_pw_w, KWH, KWL, 512);
  pwpack_kernel<<<256, 256, 0, stream>>>(ao_w, AWH, AWL, 256);
  pwpack_kernel<<<256, 256, 0, stream>>>(w3, W3H, W3L, 256);
  dftmat_kernel<<<34, 256, 0, stream>>>(MT);
  // 1. GroupNorm
  gn1_kernel<<<512, 256, 0, stream>>>(x, GNP);
  gn2_kernel<<<512, 256, 0, stream>>>(x, GNP, gn_w, gn_b, XN);
  // 2-3. q path: dw -> hi/lo chunk-planar; pw5 LDS-free GEMM
  dw3x3_kernel<<<1024, 256, 0, stream>>>(XN, q_dw, DWH, DWL);
  pw5_kernel<false><<<dim3(18, 4, 4), 256, 0, stream>>>(DWH, DWL, QWH, QWL, q_pw_b, nullptr, 0, Qb, CS, 256);
  // 4-5. kv path
  dw3x3_kernel<<<1024, 256, 0, stream>>>(cond, kv_dw, DWH, DWL);
  pw5_kernel<false><<<dim3(18, 8, 4), 256, 0, stream>>>(DWH, DWL, KWH, KWL, kv_pw_b, nullptr, 0, KV, CS2, 512);
  // 6. L2 norm (q, k, v)
  l2n_kernel<<<dim3(36, 4), 256, 0, stream>>>(Qb, CS);
  l2n_kernel<<<dim3(36, 4), 256, 0, stream>>>(KV, CS2);
  l2n_kernel<<<dim3(36, 4), 256, 0, stream>>>(KV + CS, CS2);
  // 7. rfft2 via MFMA + abs/angle -> bf16 (Q,K token-major; V channel-major)
  rfft2_mfma<true ><<<1024, 256, 0, stream>>>(Qb, CS, MT, AQT, PQT);
  rfft2_mfma<true ><<<1024, 256, 0, stream>>>(KV, CS2, MT, AKT, PKT);
  rfft2_mfma<false><<<1024, 256, 0, stream>>>(KV + CS, CS2, MT, AVc, PVc);
  // 8. MFMA attention v6: 4 independent m-tiles per block (TLP), 64-key tiles + defer-max
  attn_mfma6<<<1200, 256, 0, stream>>>(AQT, AKT, AVc, AO);
  // 9. polar + irfft2 via MFMA -> hi/lo chunk-planar
  polar_irfft2_mfma<<<1024, 256, 0, stream>>>(AO, PO, MT, OUTH, OUTL);
  // 10. attn_out = 1x1(out) + b + xn  -> ATT (f32 NCHW)
  pw5_kernel<true><<<dim3(18, 4, 4), 256, 0, stream>>>(OUTH, OUTL, AWH, AWL, ao_b, XN, CS, ATT, CS, 256);
  // 11. FFN via bf16 MFMA (chunk-planar layouts, LDS-staged)
  hipMemsetAsync(Xp1, 0, 2560000 * sizeof(__hip_bfloat16), stream);
  hipMemsetAsync(Xp2, 0, 5120000 * sizeof(__hip_bfloat16), stream);
  packx_kernel<<<dim3(48, 4), 256, 0, stream>>>(ATT, Xp1);
  packw_kernel<256><<<512, 256, 0, stream>>>(w1, Wp1, 512);
  packw_kernel<512><<<512, 256, 0, stream>>>(w2, Wp2, 256);
  mfconv3x3<256, 512, true, 1><<<768, 256, 0, stream>>>(Xp1, Wp1, Xp2, nullptr);
  mfconv3x3<512, 256, false, 2><<<768, 256, 0, stream>>>(Xp2, Wp2, nullptr, H2);
  // merge K-split partials + pack to hi/lo chunk-planar
  addpack_kernel<<<2304, 256, 0, stream>>>(H2, H2b, H2H, H2L);
  // 12. out = 1x1(h2) + b3 + attn_out
  pw5_kernel<true><<<dim3(18, 4, 4), 256, 0, stream>>>(H2H, H2L, W3H, W3L, b3, ATT, CS, Yo, CS, 256);
}

// Round 21
// 479.739 us; speedup vs baseline: 1.0188x; 1.0188x over previous
//
#include <hip/hip_runtime.h>
#include <hip/hip_bf16.h>
#include <math.h>

// Problem constants
constexpr int Bn = 4, Cn = 256, Hn = 48, Wn = 48, HW = 2304;
constexpr float ATT_SCALE = 0.17677669529663687f;  // 1/sqrt(32)

typedef __attribute__((ext_vector_type(8))) short bf16x8;
typedef __attribute__((ext_vector_type(4))) float f32x4;

#define MFMA16(A, B, C) __builtin_amdgcn_mfma_f32_16x16x32_bf16(A, B, C, 0, 0, 0)

// ---------------- GroupNorm two-phase ----------------
__global__ void gn1_kernel(const float* __restrict__ x, float* __restrict__ part) {
  int bg = blockIdx.x >> 2, ck = blockIdx.x & 3;
  const float4* xp = (const float4*)(x + (size_t)bg * 18432 + ck * 4608);
  float s = 0.f, ss = 0.f;
  for (int i = threadIdx.x; i < 1152; i += 256) {
    float4 v = xp[i];
    s += v.x + v.y + v.z + v.w;
    ss += v.x * v.x + v.y * v.y + v.z * v.z + v.w * v.w;
  }
#pragma unroll
  for (int off = 32; off; off >>= 1) { s += __shfl_xor(s, off); ss += __shfl_xor(ss, off); }
  __shared__ float rs[4], rss[4];
  int wid = threadIdx.x >> 6;
  if ((threadIdx.x & 63) == 0) { rs[wid] = s; rss[wid] = ss; }
  __syncthreads();
  if (threadIdx.x == 0) {
    part[blockIdx.x * 2] = rs[0] + rs[1] + rs[2] + rs[3];
    part[blockIdx.x * 2 + 1] = rss[0] + rss[1] + rss[2] + rss[3];
  }
}

__global__ void gn2_kernel(const float* __restrict__ x, const float* __restrict__ part,
                           const float* __restrict__ gw, const float* __restrict__ gb,
                           float* __restrict__ y) {
  int bg = blockIdx.x >> 2, ck = blockIdx.x & 3;
  float s = part[bg * 8] + part[bg * 8 + 2] + part[bg * 8 + 4] + part[bg * 8 + 6];
  float ss = part[bg * 8 + 1] + part[bg * 8 + 3] + part[bg * 8 + 5] + part[bg * 8 + 7];
  float mean = s * (1.f / 18432.f);
  float var = ss * (1.f / 18432.f) - mean * mean;
  float inv = rsqrtf(var + 1e-5f);
  int g = bg & 31;
  const float4* xp = (const float4*)(x + (size_t)bg * 18432 + ck * 4608);
  float4* yp = (float4*)(y + (size_t)bg * 18432 + ck * 4608);
  for (int i = threadIdx.x; i < 1152; i += 256) {
    int c = (g << 3) + ((ck * 1152 + i) / 576);
    float w = gw[c] * inv, b = gb[c];
    float4 v = xp[i];
    v.x = (v.x - mean) * w + b; v.y = (v.y - mean) * w + b;
    v.z = (v.z - mean) * w + b; v.w = (v.w - mean) * w + b;
    yp[i] = v;
  }
}

// ---------------- Depthwise 3x3 -> hi/lo bf16 chunk-planar [img][8ci][2304][32] ----------------
__global__ void dw3x3_kernel(const float* __restrict__ in, const float* __restrict__ wd,
                             __hip_bfloat16* __restrict__ oh, __hip_bfloat16* __restrict__ ol) {
  int bc = blockIdx.x;
  int c = bc & 255;
  const float* ip = in + (size_t)bc * HW;
  const size_t ob = ((size_t)((bc >> 8) * 8 + (c >> 5)) * HW) * 32 + (c & 31);
  float w[9];
#pragma unroll
  for (int k = 0; k < 9; ++k) w[k] = wd[c * 9 + k];
  for (int p = threadIdx.x; p < HW; p += 256) {
    int yy = p / 48, xx = p - yy * 48;
    float a = 0.f;
#pragma unroll
    for (int ky = 0; ky < 3; ++ky) {
      int y2 = yy + ky - 1;
      if ((unsigned)y2 < 48u) {
#pragma unroll
        for (int kx = 0; kx < 3; ++kx) {
          int x2 = xx + kx - 1;
          if ((unsigned)x2 < 48u) a += ip[y2 * 48 + x2] * w[ky * 3 + kx];
        }
      }
    }
    __hip_bfloat16 h = __float2bfloat16(a);
    oh[ob + (size_t)p * 32] = h;
    ol[ob + (size_t)p * 32] = __float2bfloat16(a - __bfloat162float(h));
  }
}

// ---------------- pack 1x1 weights f32 [O][256] -> chunk-planar hi/lo bf16 [(c/32)][O][32] ----------------
__global__ void pwpack_kernel(const float* __restrict__ w, __hip_bfloat16* __restrict__ WH,
                              __hip_bfloat16* __restrict__ WL, int O) {
  int q = blockIdx.x * 256 + threadIdx.x;   // o*256 + c
  int o = q >> 8, c = q & 255;
  float v = w[q];
  __hip_bfloat16 h = __float2bfloat16(v);
  size_t idx = ((size_t)(c >> 5) * O + o) * 32 + (c & 31);
  WH[idx] = h;
  WL[idx] = __float2bfloat16(v - __bfloat162float(h));
}

// ---------------- Pointwise 1x1 conv v5: LDS-free hi/lo MFMA GEMM ----------------
template <bool RES>
__global__ void __launch_bounds__(256)
pw5_kernel(const __hip_bfloat16* __restrict__ XH, const __hip_bfloat16* __restrict__ XL,
           const __hip_bfloat16* __restrict__ WH, const __hip_bfloat16* __restrict__ WL,
           const float* __restrict__ bias, const float* __restrict__ res, size_t res_bs,
           float* __restrict__ out, size_t out_bs, int CO) {
  const int tid = threadIdx.x;
  const int wv = tid >> 6, lane = tid & 63, lm = lane & 15, kg = lane >> 4;
  const int px0 = blockIdx.x * 128;
  const int ob = blockIdx.y * 64;
  const int img = blockIdx.z;

  f32x4 acc[4][2];
#pragma unroll
  for (int mt = 0; mt < 4; ++mt) {
    acc[mt][0] = (f32x4){0.f, 0.f, 0.f, 0.f};
    acc[mt][1] = (f32x4){0.f, 0.f, 0.f, 0.f};
  }

  const size_t bb = (size_t)img * 589824 + (size_t)(px0 + wv * 32 + lm) * 32 + kg * 8;
#pragma unroll
  for (int ci = 0; ci < 8; ++ci) {
    const size_t bo = bb + (size_t)ci * 73728;
    bf16x8 BH0 = *(const bf16x8*)(XH + bo);
    bf16x8 BH1 = *(const bf16x8*)(XH + bo + 512);
    bf16x8 BL0 = *(const bf16x8*)(XL + bo);
    bf16x8 BL1 = *(const bf16x8*)(XL + bo + 512);
    const size_t wb = ((size_t)ci * CO + ob + lm) * 32 + kg * 8;
#pragma unroll
    for (int mt = 0; mt < 4; ++mt) {
      bf16x8 AH = *(const bf16x8*)(WH + wb + mt * 512);
      bf16x8 AL = *(const bf16x8*)(WL + wb + mt * 512);
      acc[mt][0] = MFMA16(AH, BH0, acc[mt][0]);
      acc[mt][0] = MFMA16(AH, BL0, acc[mt][0]);
      acc[mt][0] = MFMA16(AL, BH0, acc[mt][0]);
      acc[mt][1] = MFMA16(AH, BH1, acc[mt][1]);
      acc[mt][1] = MFMA16(AH, BL1, acc[mt][1]);
      acc[mt][1] = MFMA16(AL, BH1, acc[mt][1]);
    }
  }

#pragma unroll
  for (int mt = 0; mt < 4; ++mt) {
#pragma unroll
    for (int g = 0; g < 2; ++g) {
      int px = px0 + wv * 32 + g * 16 + lm;
#pragma unroll
      for (int r = 0; r < 4; ++r) {
        int o = ob + mt * 16 + kg * 4 + r;
        float v = acc[mt][g][r] + bias[o];
        if (RES) v += res[(size_t)img * res_bs + (size_t)o * HW + px];
        out[(size_t)img * out_bs + (size_t)o * HW + px] = v;
      }
    }
  }
}

// ---------------- L2 norm over 256 channels, in place (4 cgroups x 64 px) ----------------
__global__ void l2n_kernel(float* __restrict__ t, size_t bstride) {
  int pxl = threadIdx.x & 63;
  int cg = threadIdx.x >> 6;
  int p = blockIdx.x * 64 + pxl;
  float* q = t + (size_t)blockIdx.y * bstride + p;
  float ss = 0.f;
#pragma unroll 8
  for (int c = cg * 64; c < cg * 64 + 64; ++c) { float v = q[(size_t)c * HW]; ss += v * v; }
  __shared__ float part[4][64];
  __shared__ float sinv[64];
  part[cg][pxl] = ss;
  __syncthreads();
  if (threadIdx.x < 64) {
    float tot = part[0][pxl] + part[1][pxl] + part[2][pxl] + part[3][pxl];
    sinv[pxl] = 1.f / fmaxf(sqrtf(tot), 1e-12f);
  }
  __syncthreads();
  float inv = sinv[pxl];
#pragma unroll 8
  for (int c = cg * 64; c < cg * 64 + 64; ++c) q[(size_t)c * HW] *= inv;
}

// ---------------- DFT matrix setup: bf16 hi/lo tables in ws ----------------
__global__ void dftmat_kernel(__hip_bfloat16* __restrict__ mt) {
  int t = blockIdx.x * 256 + threadIdx.x;
  const float TP = 6.283185307179586f;
  if (t < 4096) {
    int up = t >> 6, w = t & 63;
    float v = 0.f;
    if (w < 48 && up < 50) {
      int u = (up < 25) ? up : up - 25;
      float ang = TP * (float)((w * u) % 48) / 48.f;
      v = ((up < 25) ? cosf(ang) : -sinf(ang)) * (1.f / 48.f);
    }
    __hip_bfloat16 h = __float2bfloat16(v);
    mt[t] = h; mt[4096 + t] = __float2bfloat16(v - __bfloat162float(h));
  } else if (t < 7168) {
    int q = t - 4096;
    int vv = q >> 6, h = q & 63;
    float c = 0.f, s = 0.f;
    if (h < 48) {
      float ang = TP * (float)((vv * h) % 48) / 48.f;
      c = cosf(ang); s = sinf(ang);
    }
    __hip_bfloat16 ch = __float2bfloat16(c);
    mt[8192 + q] = ch; mt[11264 + q] = __float2bfloat16(c - __bfloat162float(ch));
    __hip_bfloat16 sh = __float2bfloat16(s);
    mt[14336 + q] = sh; mt[17408 + q] = __float2bfloat16(s - __bfloat162float(sh));
  } else if (t < 8704) {
    int q = t - 7168;
    int w = q >> 5, u = q & 31;
    float c = 0.f, s = 0.f;
    if (u < 25) {
      float ang = TP * (float)((u * w) % 48) / 48.f;
      c = cosf(ang); s = -sinf(ang);
    }
    __hip_bfloat16 ch = __float2bfloat16(c);
    mt[20480 + q] = ch; mt[22016 + q] = __float2bfloat16(c - __bfloat162float(ch));
    __hip_bfloat16 sh = __float2bfloat16(s);
    mt[23552 + q] = sh; mt[25088 + q] = __float2bfloat16(s - __bfloat162float(sh));
  }
}

// ---------------- rfft2 via MFMA (hi/lo split ~= fp32) + abs/angle -> bf16 ----------------
template <bool TLAY>
__global__ void __launch_bounds__(256)
rfft2_mfma(const float* __restrict__ in, size_t bstride, const __hip_bfloat16* __restrict__ mt,
           __hip_bfloat16* __restrict__ amp, __hip_bfloat16* __restrict__ pha) {
  const int bc = blockIdx.x;
  const int bi = bc >> 8, ch = bc & 255;
  const float* ip = in + (size_t)bi * bstride + (size_t)ch * HW;
  __shared__ __align__(16) __hip_bfloat16 XH[48 * 72], XL[48 * 72];
  __shared__ __align__(16) __hip_bfloat16 Yt[4][32 * 72];  // 0 reH 1 reL 2 imH 3 imL; [u][h]
  const int tid = threadIdx.x;
  const int lane = tid & 63, lm = lane & 15, kg = lane >> 4, wv = tid >> 6;

  for (int i = tid; i < 48 * 72; i += 256) {
    int r = i / 72, w = i - r * 72;
    float v = (w < 48) ? ip[r * 48 + w] : 0.f;
    __hip_bfloat16 h = __float2bfloat16(v);
    XH[i] = h;
    XL[i] = __float2bfloat16(v - __bfloat162float(h));
  }
  for (int i = tid; i < 4 * 32 * 72; i += 256) ((unsigned short*)Yt)[i] = 0;
  __syncthreads();

  {
    const __hip_bfloat16* W1TH = mt;
    const __hip_bfloat16* W1TL = mt + 4096;
    const int brow = wv * 16 + lm;
    bf16x8 BH0 = *(const bf16x8*)(W1TH + brow * 64 + kg * 8);
    bf16x8 BH1 = *(const bf16x8*)(W1TH + brow * 64 + 32 + kg * 8);
    bf16x8 BL0 = *(const bf16x8*)(W1TL + brow * 64 + kg * 8);
    bf16x8 BL1 = *(const bf16x8*)(W1TL + brow * 64 + 32 + kg * 8);
#pragma unroll
    for (int mtI = 0; mtI < 3; ++mtI) {
      f32x4 acc = {0.f, 0.f, 0.f, 0.f};
      bf16x8 AH = *(const bf16x8*)(&XH[(mtI * 16 + lm) * 72 + kg * 8]);
      bf16x8 AL = *(const bf16x8*)(&XL[(mtI * 16 + lm) * 72 + kg * 8]);
      acc = MFMA16(AH, BH0, acc); acc = MFMA16(AH, BL0, acc); acc = MFMA16(AL, BH0, acc);
      AH = *(const bf16x8*)(&XH[(mtI * 16 + lm) * 72 + 32 + kg * 8]);
      AL = *(const bf16x8*)(&XL[(mtI * 16 + lm) * 72 + 32 + kg * 8]);
      acc = MFMA16(AH, BH1, acc); acc = MFMA16(AH, BL1, acc); acc = MFMA16(AL, BH1, acc);
      if (brow < 50) {
        int aidx = (brow < 25) ? 0 : 2;
        int u = (brow < 25) ? brow : brow - 25;
#pragma unroll
        for (int r = 0; r < 4; ++r) {
          int h = mtI * 16 + kg * 4 + r;
          float v = acc[r];
          __hip_bfloat16 hh = __float2bfloat16(v);
          Yt[aidx][u * 72 + h] = hh;
          Yt[aidx + 1][u * 72 + h] = __float2bfloat16(v - __bfloat162float(hh));
        }
      }
    }
  }
  __syncthreads();

  {
    const __hip_bfloat16* M2CH = mt + 8192;
    const __hip_bfloat16* M2CL = mt + 11264;
    const __hip_bfloat16* M2SH = mt + 14336;
    const __hip_bfloat16* M2SL = mt + 17408;
    for (int t = wv; t < 6; t += 4) {
      int mtI = t >> 1, ntI = t & 1;
      f32x4 aC1 = {0.f,0.f,0.f,0.f}, aS1 = {0.f,0.f,0.f,0.f};
      f32x4 aC2 = {0.f,0.f,0.f,0.f}, aS2 = {0.f,0.f,0.f,0.f};
#pragma unroll
      for (int ks = 0; ks < 2; ++ks) {
        int arow = mtI * 16 + lm;
        int k0 = ks * 32 + kg * 8;
        bf16x8 CH = *(const bf16x8*)(M2CH + arow * 64 + k0);
        bf16x8 CL = *(const bf16x8*)(M2CL + arow * 64 + k0);
        bf16x8 SH = *(const bf16x8*)(M2SH + arow * 64 + k0);
        bf16x8 SL = *(const bf16x8*)(M2SL + arow * 64 + k0);
        int brow = ntI * 16 + lm;
        bf16x8 ReH = *(const bf16x8*)(&Yt[0][brow * 72 + k0]);
        bf16x8 ReL = *(const bf16x8*)(&Yt[1][brow * 72 + k0]);
        bf16x8 ImH = *(const bf16x8*)(&Yt[2][brow * 72 + k0]);
        bf16x8 ImL = *(const bf16x8*)(&Yt[3][brow * 72 + k0]);
        aC1 = MFMA16(CH, ReH, aC1); aC1 = MFMA16(CH, ReL, aC1); aC1 = MFMA16(CL, ReH, aC1);
        aS2 = MFMA16(SH, ImH, aS2); aS2 = MFMA16(SH, ImL, aS2); aS2 = MFMA16(SL, ImH, aS2);
        aC2 = MFMA16(CH, ImH, aC2); aC2 = MFMA16(CH, ImL, aC2); aC2 = MFMA16(CL, ImH, aC2);
        aS1 = MFMA16(SH, ReH, aS1); aS1 = MFMA16(SH, ReL, aS1); aS1 = MFMA16(SL, ReH, aS1);
      }
      int u = ntI * 16 + lm;
      if (u < 25) {
#pragma unroll
        for (int r = 0; r < 4; ++r) {
          int v = mtI * 16 + kg * 4 + r;
          float zre = aC1[r] + aS2[r];
          float zim = aC2[r] - aS1[r];
          float am = sqrtf(zre * zre + zim * zim);
          float ph = atan2f(zim, zre);
          int i = v * 25 + u;
          size_t o;
          if (TLAY) o = ((size_t)(bc >> 5) * 1200 + i) * 32 + (bc & 31);
          else      o = (size_t)bc * 1200 + i;
          amp[o] = __float2bfloat16(am);
          pha[o] = __float2bfloat16(ph);
        }
      }
    }
  }
}

// ---------------- polar + irfft2 via MFMA -> hi/lo bf16 chunk-planar ----------------
__global__ void __launch_bounds__(256)
polar_irfft2_mfma(const float* __restrict__ amp, const float* __restrict__ pha,
                  const __hip_bfloat16* __restrict__ mt,
                  __hip_bfloat16* __restrict__ oh, __hip_bfloat16* __restrict__ ol) {
  const int bc = blockIdx.x;
  __shared__ __align__(16) __hip_bfloat16 Zt[4][32 * 72];
  __shared__ __align__(16) __hip_bfloat16 Yp[4][48 * 56];
  const int tid = threadIdx.x;
  const int lane = tid & 63, lm = lane & 15, kg = lane >> 4, wv = tid >> 6;

  for (int i = tid; i < 4 * 32 * 72; i += 256) ((unsigned short*)Zt)[i] = 0;
  for (int i = tid; i < 4 * 48 * 56; i += 256) ((unsigned short*)Yp)[i] = 0;
  __syncthreads();
  for (int i = tid; i < 1200; i += 256) {
    int v = i / 25, u = i - v * 25;
    float a = amp[(size_t)bc * 1200 + i];
    float p = pha[(size_t)bc * 1200 + i];
    float sc = (u == 0 || u == 24) ? (1.f / 48.f) : (2.f / 48.f);
    float zre = a * cosf(p) * sc;
    float zim = a * sinf(p) * sc;
    __hip_bfloat16 h0 = __float2bfloat16(zre);
    Zt[0][u * 72 + v] = h0;
    Zt[1][u * 72 + v] = __float2bfloat16(zre - __bfloat162float(h0));
    __hip_bfloat16 h1 = __float2bfloat16(zim);
    Zt[2][u * 72 + v] = h1;
    Zt[3][u * 72 + v] = __float2bfloat16(zim - __bfloat162float(h1));
  }
  __syncthreads();

  {
    const __hip_bfloat16* M2CH = mt + 8192;
    const __hip_bfloat16* M2CL = mt + 11264;
    const __hip_bfloat16* M2SH = mt + 14336;
    const __hip_bfloat16* M2SL = mt + 17408;
    for (int t = wv; t < 6; t += 4) {
      int mtI = t >> 1, ntI = t & 1;
      f32x4 aC1 = {0.f,0.f,0.f,0.f}, aS1 = {0.f,0.f,0.f,0.f};
      f32x4 aC2 = {0.f,0.f,0.f,0.f}, aS2 = {0.f,0.f,0.f,0.f};
#pragma unroll
      for (int ks = 0; ks < 2; ++ks) {
        int arow = mtI * 16 + lm;
        int k0 = ks * 32 + kg * 8;
        bf16x8 CH = *(const bf16x8*)(M2CH + arow * 64 + k0);
        bf16x8 CL = *(const bf16x8*)(M2CL + arow * 64 + k0);
        bf16x8 SH = *(const bf16x8*)(M2SH + arow * 64 + k0);
        bf16x8 SL = *(const bf16x8*)(M2SL + arow * 64 + k0);
        int brow = ntI * 16 + lm;
        bf16x8 ReH = *(const bf16x8*)(&Zt[0][brow * 72 + k0]);
        bf16x8 ReL = *(const bf16x8*)(&Zt[1][brow * 72 + k0]);
        bf16x8 ImH = *(const bf16x8*)(&Zt[2][brow * 72 + k0]);
        bf16x8 ImL = *(const bf16x8*)(&Zt[3][brow * 72 + k0]);
        aC1 = MFMA16(CH, ReH, aC1); aC1 = MFMA16(CH, ReL, aC1); aC1 = MFMA16(CL, ReH, aC1);
        aS2 = MFMA16(SH, ImH, aS2); aS2 = MFMA16(SH, ImL, aS2); aS2 = MFMA16(SL, ImH, aS2);
        aC2 = MFMA16(CH, ImH, aC2); aC2 = MFMA16(CH, ImL, aC2); aC2 = MFMA16(CL, ImH, aC2);
        aS1 = MFMA16(SH, ReH, aS1); aS1 = MFMA16(SH, ReL, aS1); aS1 = MFMA16(SL, ReH, aS1);
      }
      int u = ntI * 16 + lm;
      if (u < 25) {
#pragma unroll
        for (int r = 0; r < 4; ++r) {
          int h = mtI * 16 + kg * 4 + r;
          float yre = aC1[r] - aS2[r];
          float yim = aS1[r] + aC2[r];
          __hip_bfloat16 h0 = __float2bfloat16(yre);
          Yp[0][h * 56 + u] = h0;
          Yp[1][h * 56 + u] = __float2bfloat16(yre - __bfloat162float(h0));
          __hip_bfloat16 h1 = __float2bfloat16(yim);
          Yp[2][h * 56 + u] = h1;
          Yp[3][h * 56 + u] = __float2bfloat16(yim - __bfloat162float(h1));
        }
      }
    }
  }
  __syncthreads();

  {
    const __hip_bfloat16* W3CH = mt + 20480;
    const __hip_bfloat16* W3CL = mt + 22016;
    const __hip_bfloat16* W3SH = mt + 23552;   // -sin
    const __hip_bfloat16* W3SL = mt + 25088;
    const int cch = bc & 255;
    const size_t obase = ((size_t)((bc >> 8) * 8 + (cch >> 5)) * HW) * 32 + (cch & 31);
    for (int t = wv; t < 9; t += 4) {
      int mtI = t / 3, ntI = t - (t / 3) * 3;
      f32x4 acc = {0.f, 0.f, 0.f, 0.f};
      int k0 = kg * 8;
      bf16x8 AH = *(const bf16x8*)(&Yp[0][(mtI * 16 + lm) * 56 + k0]);
      bf16x8 AL = *(const bf16x8*)(&Yp[1][(mtI * 16 + lm) * 56 + k0]);
      bf16x8 IH = *(const bf16x8*)(&Yp[2][(mtI * 16 + lm) * 56 + k0]);
      bf16x8 IL = *(const bf16x8*)(&Yp[3][(mtI * 16 + lm) * 56 + k0]);
      int brow = ntI * 16 + lm;
      bf16x8 CH = *(const bf16x8*)(W3CH + brow * 32 + k0);
      bf16x8 CL = *(const bf16x8*)(W3CL + brow * 32 + k0);
      bf16x8 SH = *(const bf16x8*)(W3SH + brow * 32 + k0);
      bf16x8 SL = *(const bf16x8*)(W3SL + brow * 32 + k0);
      acc = MFMA16(AH, CH, acc); acc = MFMA16(AH, CL, acc); acc = MFMA16(AL, CH, acc);
      acc = MFMA16(IH, SH, acc); acc = MFMA16(IH, SL, acc); acc = MFMA16(IL, SH, acc);
#pragma unroll
      for (int r = 0; r < 4; ++r) {
        int h = mtI * 16 + kg * 4 + r;
        int p = h * 48 + brow;
        float v = acc[r];
        __hip_bfloat16 hh = __float2bfloat16(v);
        oh[obase + (size_t)p * 32] = hh;
        ol[obase + (size_t)p * 32] = __float2bfloat16(v - __bfloat162float(hh));
      }
    }
  }
}

// ---------------- MFMA attention v5p: v5 + s_setprio around MFMA clusters ----------------
// 1-D grid 4800 = 8 XCDs x 8 (bh,z) pairs x 75 m-tiles. 19 key-tiles of 64 (last: 48 valid).
__global__ void __launch_bounds__(64)
attn_mfma5(const __hip_bfloat16* __restrict__ Qb, const __hip_bfloat16* __restrict__ Kb,
           const __hip_bfloat16* __restrict__ Vb, float* __restrict__ Ob) {
  const int lin = blockIdx.x;
  const int xcd = lin & 7;
  const int idx = lin >> 3;          // 0..599
  const int pr = xcd * 8 + idx / 75; // 0..63
  const int m0 = (idx % 75) * 16;
  const int z = pr >> 5;
  const int bh = pr & 31;
  const __hip_bfloat16* Qt = Qb + (size_t)z * 1228800;
  const __hip_bfloat16* Kt = Kb + (size_t)z * 1228800;
  const __hip_bfloat16* Vc = Vb + (size_t)z * 1228800;
  float* Om = Ob + (size_t)z * 1228800;
  const int lane = threadIdx.x;
  const int lm = lane & 15, kg = lane >> 4;
  __shared__ unsigned short Pl[2][16][40];
  __shared__ float fl[16];
  __shared__ float linv[16];
  const __hip_bfloat16* Qp = Qt + ((size_t)bh * 1200 + m0) * 32;
  const __hip_bfloat16* Kp = Kt + (size_t)bh * 38400;
  const __hip_bfloat16* Vp = Vc + (size_t)bh * 38400;
  const bf16x8 qf = *(const bf16x8*)(Qp + lm * 32 + kg * 8);
  const float Cs = ATT_SCALE * 1.44269504f;

  f32x4 acc0 = {0.f, 0.f, 0.f, 0.f}, acc1 = {0.f, 0.f, 0.f, 0.f};
  float psum = 0.f, mreg = -3.0e38f;

  for (int G = 0; G < 19; ++G) {
    const int n0 = G * 64;
    const bool s3ok = (G < 18);      // keys n0+48..n0+63 valid
    bf16x8 kf0 = *(const bf16x8*)(Kp + (size_t)(n0 + lm) * 32 + kg * 8);
    bf16x8 kf1 = *(const bf16x8*)(Kp + (size_t)(n0 + 16 + lm) * 32 + kg * 8);
    bf16x8 kf2 = *(const bf16x8*)(Kp + (size_t)(n0 + 32 + lm) * 32 + kg * 8);
    __builtin_amdgcn_s_setprio(1);
    f32x4 d0 = {0.f, 0.f, 0.f, 0.f}; d0 = MFMA16(kf0, qf, d0);
    f32x4 d1 = {0.f, 0.f, 0.f, 0.f}; d1 = MFMA16(kf1, qf, d1);
    f32x4 d2 = {0.f, 0.f, 0.f, 0.f}; d2 = MFMA16(kf2, qf, d2);
    f32x4 d3 = {0.f, 0.f, 0.f, 0.f};
    if (s3ok) {
      bf16x8 kf3 = *(const bf16x8*)(Kp + (size_t)(n0 + 48 + lm) * 32 + kg * 8);
      d3 = MFMA16(kf3, qf, d3);
    }
    __builtin_amdgcn_s_setprio(0);
    float tm = fmaxf(fmaxf(fmaxf(d0[0], d0[1]), fmaxf(d0[2], d0[3])),
                     fmaxf(fmaxf(d1[0], d1[1]), fmaxf(d1[2], d1[3])));
    tm = fmaxf(tm, fmaxf(fmaxf(d2[0], d2[1]), fmaxf(d2[2], d2[3])));
    if (s3ok) tm = fmaxf(tm, fmaxf(fmaxf(d3[0], d3[1]), fmaxf(d3[2], d3[3])));
    tm = fmaxf(tm, __shfl_xor(tm, 16));
    tm = fmaxf(tm, __shfl_xor(tm, 32));
    const bool grow = (__ballot(tm > mreg) != 0ull);   // wave-uniform
    if (grow) {
      float nm = fmaxf(mreg, tm);
      float ff = exp2f((mreg - nm) * Cs);
      mreg = nm;
      if (kg == 0) fl[lm] = ff;
      psum *= ff;
    }
    const float mb = mreg * Cs;
    float p0 = exp2f(d0[0] * Cs - mb), p1 = exp2f(d0[1] * Cs - mb);
    float p2 = exp2f(d0[2] * Cs - mb), p3 = exp2f(d0[3] * Cs - mb);
    float p4 = exp2f(d1[0] * Cs - mb), p5 = exp2f(d1[1] * Cs - mb);
    float p6 = exp2f(d1[2] * Cs - mb), p7 = exp2f(d1[3] * Cs - mb);
    float p8 = exp2f(d2[0] * Cs - mb), p9 = exp2f(d2[1] * Cs - mb);
    float pa_ = exp2f(d2[2] * Cs - mb), pb_ = exp2f(d2[3] * Cs - mb);
    float ps = p0 + p1 + p2 + p3 + p4 + p5 + p6 + p7 + p8 + p9 + pa_ + pb_;
    ushort4 w0, w1, w2, w3;
    w0.x = __builtin_bit_cast(unsigned short, __float2bfloat16(p0));
    w0.y = __builtin_bit_cast(unsigned short, __float2bfloat16(p1));
    w0.z = __builtin_bit_cast(unsigned short, __float2bfloat16(p2));
    w0.w = __builtin_bit_cast(unsigned short, __float2bfloat16(p3));
    w1.x = __builtin_bit_cast(unsigned short, __float2bfloat16(p4));
    w1.y = __builtin_bit_cast(unsigned short, __float2bfloat16(p5));
    w1.z = __builtin_bit_cast(unsigned short, __float2bfloat16(p6));
    w1.w = __builtin_bit_cast(unsigned short, __float2bfloat16(p7));
    w2.x = __builtin_bit_cast(unsigned short, __float2bfloat16(p8));
    w2.y = __builtin_bit_cast(unsigned short, __float2bfloat16(p9));
    w2.z = __builtin_bit_cast(unsigned short, __float2bfloat16(pa_));
    w2.w = __builtin_bit_cast(unsigned short, __float2bfloat16(pb_));
    if (s3ok) {
      float pc_ = exp2f(d3[0] * Cs - mb), pd_ = exp2f(d3[1] * Cs - mb);
      float pe_ = exp2f(d3[2] * Cs - mb), pf_ = exp2f(d3[3] * Cs - mb);
      ps += pc_ + pd_ + pe_ + pf_;
      w3.x = __builtin_bit_cast(unsigned short, __float2bfloat16(pc_));
      w3.y = __builtin_bit_cast(unsigned short, __float2bfloat16(pd_));
      w3.z = __builtin_bit_cast(unsigned short, __float2bfloat16(pe_));
      w3.w = __builtin_bit_cast(unsigned short, __float2bfloat16(pf_));
    } else {
      w3.x = w3.y = w3.z = w3.w = 0;
    }
    psum += ps;
    *(ushort4*)(&Pl[0][lm][kg * 4]) = w0;
    *(ushort4*)(&Pl[0][lm][16 + kg * 4]) = w1;
    *(ushort4*)(&Pl[1][lm][kg * 4]) = w2;
    *(ushort4*)(&Pl[1][lm][16 + kg * 4]) = w3;
    if (grow) {
      float4 f4 = *(const float4*)(&fl[kg * 4]);
      acc0[0] *= f4.x; acc0[1] *= f4.y; acc0[2] *= f4.z; acc0[3] *= f4.w;
      acc1[0] *= f4.x; acc1[1] *= f4.y; acc1[2] *= f4.z; acc1[3] *= f4.w;
    }
    bf16x8 pa0 = *(const bf16x8*)(&Pl[0][lm][kg * 8]);
    bf16x8 pa1 = *(const bf16x8*)(&Pl[1][lm][kg * 8]);
    bf16x8 v00 = *(const bf16x8*)(Vp + (size_t)lm * 1200 + n0 + kg * 8);
    bf16x8 v01 = *(const bf16x8*)(Vp + (size_t)(16 + lm) * 1200 + n0 + kg * 8);
    bf16x8 v10 = *(const bf16x8*)(Vp + (size_t)lm * 1200 + n0 + 32 + kg * 8);
    bf16x8 v11 = *(const bf16x8*)(Vp + (size_t)(16 + lm) * 1200 + n0 + 32 + kg * 8);
    __builtin_amdgcn_s_setprio(1);
    acc0 = MFMA16(pa0, v00, acc0);
    acc1 = MFMA16(pa0, v01, acc1);
    acc0 = MFMA16(pa1, v10, acc0);
    acc1 = MFMA16(pa1, v11, acc1);
    __builtin_amdgcn_s_setprio(0);
  }
  psum += __shfl_xor(psum, 16);
  psum += __shfl_xor(psum, 32);
  if (kg == 0) linv[lm] = 1.f / psum;
  __syncthreads();
#pragma unroll
  for (int r = 0; r < 4; ++r) {
    int m = m0 + kg * 4 + r;
    float li = linv[kg * 4 + r];
    Om[(size_t)bh * 38400 + (size_t)lm * 1200 + m] = acc0[r] * li;
    Om[(size_t)bh * 38400 + (size_t)(16 + lm) * 1200 + m] = acc1[r] * li;
  }
}

// ---------------- pack weights f32 [O][CIN][9] -> bf16 [tap][CIN/32][O][32] ----------------
template <int CIN>
__global__ void packw_kernel(const float* __restrict__ w, __hip_bfloat16* __restrict__ wp, int O) {
  int t = blockIdx.x * 256 + threadIdx.x;   // o*CIN + c
  int o = t / CIN, c = t - o * CIN;
  if (o >= O) return;
  constexpr int NC = CIN / 32;
#pragma unroll
  for (int tap = 0; tap < 9; ++tap)
    wp[(((size_t)tap * NC + (c >> 5)) * O + o) * 32 + (c & 31)] = __float2bfloat16(w[(size_t)t * 9 + tap]);
}

// ---------------- packx: ATT f32 NCHW -> bf16 chunk-planar padded [b][8ci][50][50][32] ----------------
__global__ void packx_kernel(const float* __restrict__ in, __hip_bfloat16* __restrict__ xp) {
  int y = blockIdx.x;     // 0..47
  int b = blockIdx.y;     // 0..3
  int c = threadIdx.x;    // 0..255
  const float* ip = in + ((size_t)(b * 256 + c) * 48 + y) * 48;
  __hip_bfloat16* op = xp + ((size_t)(b * 8 + (c >> 5)) * 2500 + (size_t)(y + 1) * 50 + 1) * 32 + (c & 31);
  for (int x = 0; x < 48; ++x) op[x * 32] = __float2bfloat16(ip[x]);
}

// ---------------- addpack: (a + b) f32 NCHW -> hi/lo bf16 chunk-planar ----------------
__global__ void addpack_kernel(const float* __restrict__ a, const float* __restrict__ b,
                               __hip_bfloat16* __restrict__ oh, __hip_bfloat16* __restrict__ ol) {
  int i = blockIdx.x * 256 + threadIdx.x;   // float4 index over U/4
  float4 x = ((const float4*)a)[i];
  float4 y = ((const float4*)b)[i];
  x.x += y.x; x.y += y.y; x.z += y.z; x.w += y.w;
  int e = i * 4;
  int img = e / 589824, rem = e - img * 589824;
  int c = rem / 2304, px = rem - c * 2304;
  size_t ob = ((size_t)(img * 8 + (c >> 5)) * HW) * 32 + (c & 31);
  float vv[4] = {x.x, x.y, x.z, x.w};
#pragma unroll
  for (int j = 0; j < 4; ++j) {
    __hip_bfloat16 h = __float2bfloat16(vv[j]);
    oh[ob + (size_t)(px + j) * 32] = h;
    ol[ob + (size_t)(px + j) * 32] = __float2bfloat16(vv[j] - __bfloat162float(h));
  }
}

// ---------------- MFMA 3x3 conv v8: LDS-staged chunks (proven: 0 bank conflicts) ----------------
template <int CIN, int CO, bool TO_PAD, int KS>
__global__ void __launch_bounds__(256)
mfconv3x3(const __hip_bfloat16* __restrict__ Xp, const __hip_bfloat16* __restrict__ Wp,
          __hip_bfloat16* __restrict__ Op, float* __restrict__ Of) {
  constexpr int NC = CIN / 32;
  constexpr int KC = NC / KS;
  constexpr int MT = CO / 32;
  const int q = gridDim.x >> 3;
  const int swz = (blockIdx.x & 7) * q + (blockIdx.x >> 3);
  const int mt = swz % MT;
  const int ks = (swz / MT) % KS;
  const int rq = swz / (MT * KS);       // 0..47
  const int img = rq / 12;
  const int y0b = (rq % 12) * 4;
  const int tid = threadIdx.x;
  const int wv = tid >> 6;
  const int y = y0b + wv;
  const int lane = tid & 63;
  const int lm = lane & 15, kg = lane >> 4;
  const int o0 = mt * 32;
  const int ci0 = ks * KC;

  __shared__ __hip_bfloat16 Als[9216];   // [tap][32o][32c]
  __shared__ __hip_bfloat16 Bls[9600];   // [6 rows][50][32c]

  f32x4 acc[2][3];
#pragma unroll
  for (int f = 0; f < 2; ++f)
#pragma unroll
    for (int g = 0; g < 3; ++g) acc[f][g] = (f32x4){0.f, 0.f, 0.f, 0.f};

  for (int ci = 0; ci < KC; ++ci) {
    const int cic = ci0 + ci;
    const size_t wst = ((size_t)cic * CO + o0) * 32;
    const size_t bst = ((size_t)(img * NC + cic) * 2500 + (size_t)y0b * 50) * 32;
    __syncthreads();
    for (int c = tid; c < 2352; c += 256) {
      if (c < 1152) {
        int tap = c >> 7, rem = c & 127;
        float4 v = *(const float4*)(Wp + wst + (size_t)tap * (NC * CO * 32) + rem * 8);
        *(float4*)(&Als[c * 8]) = v;
      } else {
        int c2 = c - 1152;
        float4 v = *(const float4*)(Xp + bst + (size_t)c2 * 8);
        *(float4*)(&Bls[c2 * 8]) = v;
      }
    }
    __syncthreads();
#pragma unroll
    for (int tap = 0; tap < 9; ++tap) {
      const int dy = tap / 3 - 1, dx = tap - (tap / 3) * 3 - 1;
      bf16x8 A0 = *(const bf16x8*)(&Als[tap * 1024 + lm * 32 + kg * 8]);
      bf16x8 A1 = *(const bf16x8*)(&Als[tap * 1024 + 512 + lm * 32 + kg * 8]);
      const int bbase = ((wv + 1 + dy) * 50 + 1 + dx + lm) * 32 + kg * 8;
      bf16x8 B0 = *(const bf16x8*)(&Bls[bbase]);
      bf16x8 B1 = *(const bf16x8*)(&Bls[bbase + 512]);
      bf16x8 B2 = *(const bf16x8*)(&Bls[bbase + 1024]);
      acc[0][0] = MFMA16(A0, B0, acc[0][0]);
      acc[0][1] = MFMA16(A0, B1, acc[0][1]);
      acc[0][2] = MFMA16(A0, B2, acc[0][2]);
      acc[1][0] = MFMA16(A1, B0, acc[1][0]);
      acc[1][1] = MFMA16(A1, B1, acc[1][1]);
      acc[1][2] = MFMA16(A1, B2, acc[1][2]);
    }
  }

  if (TO_PAD) {
    const int cio = o0 >> 5;
#pragma unroll
    for (int f = 0; f < 2; ++f) {
      const int cc = f * 16 + kg * 4;
#pragma unroll
      for (int g = 0; g < 3; ++g) {
        int x = g * 16 + lm;
        ushort4 st;
        float v0 = acc[f][g][0], v1 = acc[f][g][1], v2 = acc[f][g][2], v3 = acc[f][g][3];
        v0 = v0 / (1.f + __expf(-v0)); v1 = v1 / (1.f + __expf(-v1));
        v2 = v2 / (1.f + __expf(-v2)); v3 = v3 / (1.f + __expf(-v3));
        st.x = __builtin_bit_cast(unsigned short, __float2bfloat16(v0));
        st.y = __builtin_bit_cast(unsigned short, __float2bfloat16(v1));
        st.z = __builtin_bit_cast(unsigned short, __float2bfloat16(v2));
        st.w = __builtin_bit_cast(unsigned short, __float2bfloat16(v3));
        *(ushort4*)(Op + (((size_t)(img * (CO / 32) + cio) * 2500 + (size_t)(y + 1) * 50 + (x + 1)) * 32 + cc)) = st;
      }
    }
  } else {
    float* Ofp = Of + (size_t)ks * 4 * CO * HW;
#pragma unroll
    for (int f = 0; f < 2; ++f)
#pragma unroll
      for (int g = 0; g < 3; ++g) {
        int x = g * 16 + lm;
#pragma unroll
        for (int r = 0; r < 4; ++r) {
          int o = o0 + f * 16 + kg * 4 + r;
          Ofp[((size_t)img * CO + o) * HW + y * 48 + x] = acc[f][g][r];
        }
      }
  }
}

extern "C" void kernel_launch(void* const* d_in, const int* in_sizes, int n_in,
                              void* d_out, int out_size, void* d_ws, size_t ws_size,
                              hipStream_t stream) {
  (void)in_sizes; (void)n_in; (void)out_size; (void)ws_size;
  const float* x      = (const float*)d_in[0];
  const float* cond   = (const float*)d_in[1];
  const float* gn_w   = (const float*)d_in[2];
  const float* gn_b   = (const float*)d_in[3];
  const float* q_dw   = (const float*)d_in[4];
  const float* q_pw_w = (const float*)d_in[5];
  const float* q_pw_b = (const float*)d_in[6];
  const float* kv_dw  = (const float*)d_in[7];
  const float* kv_pw_w= (const float*)d_in[8];
  const float* kv_pw_b= (const float*)d_in[9];
  const float* ao_w   = (const float*)d_in[10];
  const float* ao_b   = (const float*)d_in[11];
  const float* w1     = (const float*)d_in[12];
  const float* w2     = (const float*)d_in[13];
  const float* w3     = (const float*)d_in[14];
  const float* b3     = (const float*)d_in[15];
  float* ws = (float*)d_ws;
  float* Yo = (float*)d_out;

  const size_t U = 2359296;   // 4*256*48*48 (floats)
  const size_t Hf = 1228800;  // 4*256*48*25 (floats)
  const size_t CS = 589824;   // 256*2304
  const size_t CS2 = 1179648; // 512*2304

  float* XN  = ws;             // [0,U)
  __hip_bfloat16* DWH = (__hip_bfloat16*)(ws + U);       // [U,2U) as 2x bf16 planes
  __hip_bfloat16* DWL = DWH + 2359296;
  float* Qb  = ws + 2 * U;
  float* KV  = ws + 3 * U;     // 2U extent
  __hip_bfloat16* AQT = (__hip_bfloat16*)(ws + 5 * U);
  __hip_bfloat16* PQT = AQT + 1228800;
  __hip_bfloat16* AKT = AQT + 2 * 1228800;
  __hip_bfloat16* PKT = AQT + 3 * 1228800;
  __hip_bfloat16* AVc = AQT + 4 * 1228800;
  __hip_bfloat16* PVc = AQT + 5 * 1228800;
  float* AO  = ws + 5 * U + 3 * Hf;
  float* PO  = AO + Hf;
  __hip_bfloat16* OUTH = (__hip_bfloat16*)(ws + U);      // reuse dead DW region
  __hip_bfloat16* OUTL = OUTH + 2359296;
  float* ATT = ws + 5 * U;
  __hip_bfloat16* Xp1 = (__hip_bfloat16*)(ws + U);
  __hip_bfloat16* Xp2 = (__hip_bfloat16*)(ws + 2 * U);
  __hip_bfloat16* Wp1 = (__hip_bfloat16*)(ws + 2 * U + 2600000);
  __hip_bfloat16* Wp2 = (__hip_bfloat16*)(ws + 2 * U + 3200000);
  float* H2  = ws;             // K-split partial 0 at [0,U); partial 1 at [U,2U)
  float* H2b = ws + U;
  __hip_bfloat16* H2H = (__hip_bfloat16*)(ws + 5 * U + 3 * Hf);  // reuse dead AO/PO
  __hip_bfloat16* H2L = H2H + 2359296;
  // pw weights (chunk-planar hi/lo bf16) + DFT matrices + gn partials in dead tail
  __hip_bfloat16* BW = (__hip_bfloat16*)(ws + 5 * U + 5 * Hf);
  __hip_bfloat16* QWH = BW,            * QWL = BW + 65536;
  __hip_bfloat16* KWH = BW + 131072,   * KWL = BW + 262144;
  __hip_bfloat16* AWH = BW + 393216,   * AWL = BW + 458752;
  __hip_bfloat16* W3H = BW + 524288,   * W3L = BW + 589824;
  __hip_bfloat16* MT  = BW + 655360;   // 26624 bf16
  float* GNP = ws + 5 * U + 5 * Hf + 341000;   // 1024 floats

  // 0. one-time-per-launch precompute
  pwpack_kernel<<<256, 256, 0, stream>>>(q_pw_w, QWH, QWL, 256);
  pwpack_kernel<<<512, 256, 0, stream>>>(kv_pw_w, KWH, KWL, 512);
  pwpack_kernel<<<256, 256, 0, stream>>>(ao_w, AWH, AWL, 256);
  pwpack_kernel<<<256, 256, 0, stream>>>(w3, W3H, W3L, 256);
  dftmat_kernel<<<34, 256, 0, stream>>>(MT);
  // 1. GroupNorm
  gn1_kernel<<<512, 256, 0, stream>>>(x, GNP);
  gn2_kernel<<<512, 256, 0, stream>>>(x, GNP, gn_w, gn_b, XN);
  // 2-3. q path: dw -> hi/lo chunk-planar; pw5 LDS-free GEMM
  dw3x3_kernel<<<1024, 256, 0, stream>>>(XN, q_dw, DWH, DWL);
  pw5_kernel<false><<<dim3(18, 4, 4), 256, 0, stream>>>(DWH, DWL, QWH, QWL, q_pw_b, nullptr, 0, Qb, CS, 256);
  // 4-5. kv path
  dw3x3_kernel<<<1024, 256, 0, stream>>>(cond, kv_dw, DWH, DWL);
  pw5_kernel<false><<<dim3(18, 8, 4), 256, 0, stream>>>(DWH, DWL, KWH, KWL, kv_pw_b, nullptr, 0, KV, CS2, 512);
  // 6. L2 norm (q, k, v)
  l2n_kernel<<<dim3(36, 4), 256, 0, stream>>>(Qb, CS);
  l2n_kernel<<<dim3(36, 4), 256, 0, stream>>>(KV, CS2);
  l2n_kernel<<<dim3(36, 4), 256, 0, stream>>>(KV + CS, CS2);
  // 7. rfft2 via MFMA + abs/angle -> bf16 (Q,K token-major; V channel-major)
  rfft2_mfma<true ><<<1024, 256, 0, stream>>>(Qb, CS, MT, AQT, PQT);
  rfft2_mfma<true ><<<1024, 256, 0, stream>>>(KV, CS2, MT, AKT, PKT);
  rfft2_mfma<false><<<1024, 256, 0, stream>>>(KV + CS, CS2, MT, AVc, PVc);
  // 8. MFMA attention v5 + setprio: 64-key tiles + defer-max + XCD swizzle
  attn_mfma5<<<4800, 64, 0, stream>>>(AQT, AKT, AVc, AO);
  // 9. polar + irfft2 via MFMA -> hi/lo chunk-planar
  polar_irfft2_mfma<<<1024, 256, 0, stream>>>(AO, PO, MT, OUTH, OUTL);
  // 10. attn_out = 1x1(out) + b + xn  -> ATT (f32 NCHW)
  pw5_kernel<true><<<dim3(18, 4, 4), 256, 0, stream>>>(OUTH, OUTL, AWH, AWL, ao_b, XN, CS, ATT, CS, 256);
  // 11. FFN via bf16 MFMA (chunk-planar layouts, LDS-staged)
  hipMemsetAsync(Xp1, 0, 2560000 * sizeof(__hip_bfloat16), stream);
  hipMemsetAsync(Xp2, 0, 5120000 * sizeof(__hip_bfloat16), stream);
  packx_kernel<<<dim3(48, 4), 256, 0, stream>>>(ATT, Xp1);
  packw_kernel<256><<<512, 256, 0, stream>>>(w1, Wp1, 512);
  packw_kernel<512><<<512, 256, 0, stream>>>(w2, Wp2, 256);
  mfconv3x3<256, 512, true, 1><<<768, 256, 0, stream>>>(Xp1, Wp1, Xp2, nullptr);
  mfconv3x3<512, 256, false, 2><<<768, 256, 0, stream>>>(Xp2, Wp2, nullptr, H2);
  // merge K-split partials + pack to hi/lo chunk-planar
  addpack_kernel<<<2304, 256, 0, stream>>>(H2, H2b, H2H, H2L);
  // 12. out = 1x1(h2) + b3 + attn_out
  pw5_kernel<true><<<dim3(18, 4, 4), 256, 0, stream>>>(H2H, H2L, W3H, W3L, b3, ATT, CS, Yo, CS, 256);
}

// Round 23
// 428.327 us; speedup vs baseline: 1.1411x; 1.1200x over previous
//
#include <hip/hip_runtime.h>
#include <hip/hip_bf16.h>
#include <math.h>

// Problem constants
constexpr int Bn = 4, Cn = 256, Hn = 48, Wn = 48, HW = 2304;
constexpr float ATT_SCALE = 0.17677669529663687f;  // 1/sqrt(32)

typedef __attribute__((ext_vector_type(8))) short bf16x8;
typedef __attribute__((ext_vector_type(4))) float f32x4;

#define MFMA16(A, B, C) __builtin_amdgcn_mfma_f32_16x16x32_bf16(A, B, C, 0, 0, 0)

// ---------------- GroupNorm two-phase ----------------
__global__ void gn1_kernel(const float* __restrict__ x, float* __restrict__ part) {
  int bg = blockIdx.x >> 2, ck = blockIdx.x & 3;
  const float4* xp = (const float4*)(x + (size_t)bg * 18432 + ck * 4608);
  float s = 0.f, ss = 0.f;
  for (int i = threadIdx.x; i < 1152; i += 256) {
    float4 v = xp[i];
    s += v.x + v.y + v.z + v.w;
    ss += v.x * v.x + v.y * v.y + v.z * v.z + v.w * v.w;
  }
#pragma unroll
  for (int off = 32; off; off >>= 1) { s += __shfl_xor(s, off); ss += __shfl_xor(ss, off); }
  __shared__ float rs[4], rss[4];
  int wid = threadIdx.x >> 6;
  if ((threadIdx.x & 63) == 0) { rs[wid] = s; rss[wid] = ss; }
  __syncthreads();
  if (threadIdx.x == 0) {
    part[blockIdx.x * 2] = rs[0] + rs[1] + rs[2] + rs[3];
    part[blockIdx.x * 2 + 1] = rss[0] + rss[1] + rss[2] + rss[3];
  }
}

__global__ void gn2_kernel(const float* __restrict__ x, const float* __restrict__ part,
                           const float* __restrict__ gw, const float* __restrict__ gb,
                           float* __restrict__ y) {
  int bg = blockIdx.x >> 2, ck = blockIdx.x & 3;
  float s = part[bg * 8] + part[bg * 8 + 2] + part[bg * 8 + 4] + part[bg * 8 + 6];
  float ss = part[bg * 8 + 1] + part[bg * 8 + 3] + part[bg * 8 + 5] + part[bg * 8 + 7];
  float mean = s * (1.f / 18432.f);
  float var = ss * (1.f / 18432.f) - mean * mean;
  float inv = rsqrtf(var + 1e-5f);
  int g = bg & 31;
  const float4* xp = (const float4*)(x + (size_t)bg * 18432 + ck * 4608);
  float4* yp = (float4*)(y + (size_t)bg * 18432 + ck * 4608);
  for (int i = threadIdx.x; i < 1152; i += 256) {
    int c = (g << 3) + ((ck * 1152 + i) / 576);
    float w = gw[c] * inv, b = gb[c];
    float4 v = xp[i];
    v.x = (v.x - mean) * w + b; v.y = (v.y - mean) * w + b;
    v.z = (v.z - mean) * w + b; v.w = (v.w - mean) * w + b;
    yp[i] = v;
  }
}

// ---------------- Depthwise 3x3 -> hi/lo bf16 chunk-planar [img][8ci][2304][32] ----------------
__global__ void dw3x3_kernel(const float* __restrict__ in, const float* __restrict__ wd,
                             __hip_bfloat16* __restrict__ oh, __hip_bfloat16* __restrict__ ol) {
  int bc = blockIdx.x;
  int c = bc & 255;
  const float* ip = in + (size_t)bc * HW;
  const size_t ob = ((size_t)((bc >> 8) * 8 + (c >> 5)) * HW) * 32 + (c & 31);
  float w[9];
#pragma unroll
  for (int k = 0; k < 9; ++k) w[k] = wd[c * 9 + k];
  for (int p = threadIdx.x; p < HW; p += 256) {
    int yy = p / 48, xx = p - yy * 48;
    float a = 0.f;
#pragma unroll
    for (int ky = 0; ky < 3; ++ky) {
      int y2 = yy + ky - 1;
      if ((unsigned)y2 < 48u) {
#pragma unroll
        for (int kx = 0; kx < 3; ++kx) {
          int x2 = xx + kx - 1;
          if ((unsigned)x2 < 48u) a += ip[y2 * 48 + x2] * w[ky * 3 + kx];
        }
      }
    }
    __hip_bfloat16 h = __float2bfloat16(a);
    oh[ob + (size_t)p * 32] = h;
    ol[ob + (size_t)p * 32] = __float2bfloat16(a - __bfloat162float(h));
  }
}

// ---------------- setup: 4x pwpack + DFT tables (one launch; NO pad-zero here — aliasing) ----------------
__global__ void setup_kernel(const float* __restrict__ q_pw_w, const float* __restrict__ kv_pw_w,
                             const float* __restrict__ ao_w, const float* __restrict__ w3,
                             __hip_bfloat16* __restrict__ QWH, __hip_bfloat16* __restrict__ QWL,
                             __hip_bfloat16* __restrict__ KWH, __hip_bfloat16* __restrict__ KWL,
                             __hip_bfloat16* __restrict__ AWH, __hip_bfloat16* __restrict__ AWL,
                             __hip_bfloat16* __restrict__ W3H, __hip_bfloat16* __restrict__ W3L,
                             __hip_bfloat16* __restrict__ mt) {
  const int b = blockIdx.x, tid = threadIdx.x;
  if (b < 1280) {
    const float* w; __hip_bfloat16 *WH, *WL; int O, q;
    if (b < 256)       { w = q_pw_w;  WH = QWH; WL = QWL; O = 256; q = b * 256 + tid; }
    else if (b < 768)  { w = kv_pw_w; WH = KWH; WL = KWL; O = 512; q = (b - 256) * 256 + tid; }
    else if (b < 1024) { w = ao_w;    WH = AWH; WL = AWL; O = 256; q = (b - 768) * 256 + tid; }
    else               { w = w3;      WH = W3H; WL = W3L; O = 256; q = (b - 1024) * 256 + tid; }
    int o = q >> 8, c = q & 255;
    float v = w[q];
    __hip_bfloat16 h = __float2bfloat16(v);
    size_t idx = ((size_t)(c >> 5) * O + o) * 32 + (c & 31);
    WH[idx] = h;
    WL[idx] = __float2bfloat16(v - __bfloat162float(h));
  } else {
    int t = (b - 1280) * 256 + tid;
    const float TP = 6.283185307179586f;
    if (t < 4096) {
      int up = t >> 6, w = t & 63;
      float v = 0.f;
      if (w < 48 && up < 50) {
        int u = (up < 25) ? up : up - 25;
        float ang = TP * (float)((w * u) % 48) / 48.f;
        v = ((up < 25) ? cosf(ang) : -sinf(ang)) * (1.f / 48.f);
      }
      __hip_bfloat16 h = __float2bfloat16(v);
      mt[t] = h; mt[4096 + t] = __float2bfloat16(v - __bfloat162float(h));
    } else if (t < 7168) {
      int q = t - 4096;
      int vv = q >> 6, h = q & 63;
      float c = 0.f, s = 0.f;
      if (h < 48) {
        float ang = TP * (float)((vv * h) % 48) / 48.f;
        c = cosf(ang); s = sinf(ang);
      }
      __hip_bfloat16 ch = __float2bfloat16(c);
      mt[8192 + q] = ch; mt[11264 + q] = __float2bfloat16(c - __bfloat162float(ch));
      __hip_bfloat16 sh = __float2bfloat16(s);
      mt[14336 + q] = sh; mt[17408 + q] = __float2bfloat16(s - __bfloat162float(sh));
    } else if (t < 8704) {
      int q = t - 7168;
      int w = q >> 5, u = q & 31;
      float c = 0.f, s = 0.f;
      if (u < 25) {
        float ang = TP * (float)((u * w) % 48) / 48.f;
        c = cosf(ang); s = -sinf(ang);
      }
      __hip_bfloat16 ch = __float2bfloat16(c);
      mt[20480 + q] = ch; mt[22016 + q] = __float2bfloat16(c - __bfloat162float(ch));
      __hip_bfloat16 sh = __float2bfloat16(s);
      mt[23552 + q] = sh; mt[25088 + q] = __float2bfloat16(s - __bfloat162float(sh));
    }
  }
}

// ---------------- Pointwise 1x1 conv v5: LDS-free hi/lo MFMA GEMM ----------------
template <bool RES>
__global__ void __launch_bounds__(256)
pw5_kernel(const __hip_bfloat16* __restrict__ XH, const __hip_bfloat16* __restrict__ XL,
           const __hip_bfloat16* __restrict__ WH, const __hip_bfloat16* __restrict__ WL,
           const float* __restrict__ bias, const float* __restrict__ res, size_t res_bs,
           float* __restrict__ out, size_t out_bs, int CO) {
  const int tid = threadIdx.x;
  const int wv = tid >> 6, lane = tid & 63, lm = lane & 15, kg = lane >> 4;
  const int px0 = blockIdx.x * 128;
  const int ob = blockIdx.y * 64;
  const int img = blockIdx.z;

  f32x4 acc[4][2];
#pragma unroll
  for (int mt = 0; mt < 4; ++mt) {
    acc[mt][0] = (f32x4){0.f, 0.f, 0.f, 0.f};
    acc[mt][1] = (f32x4){0.f, 0.f, 0.f, 0.f};
  }

  const size_t bb = (size_t)img * 589824 + (size_t)(px0 + wv * 32 + lm) * 32 + kg * 8;
#pragma unroll
  for (int ci = 0; ci < 8; ++ci) {
    const size_t bo = bb + (size_t)ci * 73728;
    bf16x8 BH0 = *(const bf16x8*)(XH + bo);
    bf16x8 BH1 = *(const bf16x8*)(XH + bo + 512);
    bf16x8 BL0 = *(const bf16x8*)(XL + bo);
    bf16x8 BL1 = *(const bf16x8*)(XL + bo + 512);
    const size_t wb = ((size_t)ci * CO + ob + lm) * 32 + kg * 8;
#pragma unroll
    for (int mt = 0; mt < 4; ++mt) {
      bf16x8 AH = *(const bf16x8*)(WH + wb + mt * 512);
      bf16x8 AL = *(const bf16x8*)(WL + wb + mt * 512);
      acc[mt][0] = MFMA16(AH, BH0, acc[mt][0]);
      acc[mt][0] = MFMA16(AH, BL0, acc[mt][0]);
      acc[mt][0] = MFMA16(AL, BH0, acc[mt][0]);
      acc[mt][1] = MFMA16(AH, BH1, acc[mt][1]);
      acc[mt][1] = MFMA16(AH, BL1, acc[mt][1]);
      acc[mt][1] = MFMA16(AL, BH1, acc[mt][1]);
    }
  }

#pragma unroll
  for (int mt = 0; mt < 4; ++mt) {
#pragma unroll
    for (int g = 0; g < 2; ++g) {
      int px = px0 + wv * 32 + g * 16 + lm;
#pragma unroll
      for (int r = 0; r < 4; ++r) {
        int o = ob + mt * 16 + kg * 4 + r;
        float v = acc[mt][g][r] + bias[o];
        if (RES) v += res[(size_t)img * res_bs + (size_t)o * HW + px];
        out[(size_t)img * out_bs + (size_t)o * HW + px] = v;
      }
    }
  }
}

// ---------------- L2 norm fused (q,k,v), grid (36,12) ----------------
__global__ void l2n3_kernel(float* __restrict__ Qb, float* __restrict__ KV) {
  int t = blockIdx.y >> 2;       // 0 q, 1 k, 2 v
  int img = blockIdx.y & 3;
  float* base = (t == 0) ? Qb : (t == 1 ? KV : KV + 589824);
  size_t bstride = (t == 0) ? (size_t)589824 : (size_t)1179648;
  int pxl = threadIdx.x & 63;
  int cg = threadIdx.x >> 6;
  int p = blockIdx.x * 64 + pxl;
  float* q = base + (size_t)img * bstride + p;
  float ss = 0.f;
#pragma unroll 8
  for (int c = cg * 64; c < cg * 64 + 64; ++c) { float v = q[(size_t)c * HW]; ss += v * v; }
  __shared__ float part[4][64];
  __shared__ float sinv[64];
  part[cg][pxl] = ss;
  __syncthreads();
  if (threadIdx.x < 64) {
    float tot = part[0][pxl] + part[1][pxl] + part[2][pxl] + part[3][pxl];
    sinv[pxl] = 1.f / fmaxf(sqrtf(tot), 1e-12f);
  }
  __syncthreads();
  float inv = sinv[pxl];
#pragma unroll 8
  for (int c = cg * 64; c < cg * 64 + 64; ++c) q[(size_t)c * HW] *= inv;
}

// ---------------- rfft2 fused (q,k,v) via MFMA; grid 3072 ----------------
__global__ void __launch_bounds__(256)
rfft2_all(const float* __restrict__ Qb, const float* __restrict__ KV,
          const __hip_bfloat16* __restrict__ mt, __hip_bfloat16* __restrict__ spec) {
  const int t = blockIdx.x >> 10;     // 0 q, 1 k, 2 v
  const int bc = blockIdx.x & 1023;
  const int bi = bc >> 8, ch = bc & 255;
  const float* src = (t == 0) ? Qb : (t == 1 ? KV : KV + 589824);
  const size_t bstride = (t == 0) ? (size_t)589824 : (size_t)1179648;
  const float* ip = src + (size_t)bi * bstride + (size_t)ch * HW;
  __hip_bfloat16* amp = spec + (size_t)(2 * t) * 1228800;
  __hip_bfloat16* pha = spec + (size_t)(2 * t + 1) * 1228800;
  const bool tlay = (t < 2);
  __shared__ __align__(16) __hip_bfloat16 XH[48 * 72], XL[48 * 72];
  __shared__ __align__(16) __hip_bfloat16 Yt[4][32 * 72];  // 0 reH 1 reL 2 imH 3 imL; [u][h]
  const int tid = threadIdx.x;
  const int lane = tid & 63, lm = lane & 15, kg = lane >> 4, wv = tid >> 6;

  for (int i = tid; i < 48 * 72; i += 256) {
    int r = i / 72, w = i - r * 72;
    float v = (w < 48) ? ip[r * 48 + w] : 0.f;
    __hip_bfloat16 h = __float2bfloat16(v);
    XH[i] = h;
    XL[i] = __float2bfloat16(v - __bfloat162float(h));
  }
  for (int i = tid; i < 4 * 32 * 72; i += 256) ((unsigned short*)Yt)[i] = 0;
  __syncthreads();

  {
    const __hip_bfloat16* W1TH = mt;
    const __hip_bfloat16* W1TL = mt + 4096;
    const int brow = wv * 16 + lm;
    bf16x8 BH0 = *(const bf16x8*)(W1TH + brow * 64 + kg * 8);
    bf16x8 BH1 = *(const bf16x8*)(W1TH + brow * 64 + 32 + kg * 8);
    bf16x8 BL0 = *(const bf16x8*)(W1TL + brow * 64 + kg * 8);
    bf16x8 BL1 = *(const bf16x8*)(W1TL + brow * 64 + 32 + kg * 8);
#pragma unroll
    for (int mtI = 0; mtI < 3; ++mtI) {
      f32x4 acc = {0.f, 0.f, 0.f, 0.f};
      bf16x8 AH = *(const bf16x8*)(&XH[(mtI * 16 + lm) * 72 + kg * 8]);
      bf16x8 AL = *(const bf16x8*)(&XL[(mtI * 16 + lm) * 72 + kg * 8]);
      acc = MFMA16(AH, BH0, acc); acc = MFMA16(AH, BL0, acc); acc = MFMA16(AL, BH0, acc);
      AH = *(const bf16x8*)(&XH[(mtI * 16 + lm) * 72 + 32 + kg * 8]);
      AL = *(const bf16x8*)(&XL[(mtI * 16 + lm) * 72 + 32 + kg * 8]);
      acc = MFMA16(AH, BH1, acc); acc = MFMA16(AH, BL1, acc); acc = MFMA16(AL, BH1, acc);
      if (brow < 50) {
        int aidx = (brow < 25) ? 0 : 2;
        int u = (brow < 25) ? brow : brow - 25;
#pragma unroll
        for (int r = 0; r < 4; ++r) {
          int h = mtI * 16 + kg * 4 + r;
          float v = acc[r];
          __hip_bfloat16 hh = __float2bfloat16(v);
          Yt[aidx][u * 72 + h] = hh;
          Yt[aidx + 1][u * 72 + h] = __float2bfloat16(v - __bfloat162float(hh));
        }
      }
    }
  }
  __syncthreads();

  {
    const __hip_bfloat16* M2CH = mt + 8192;
    const __hip_bfloat16* M2CL = mt + 11264;
    const __hip_bfloat16* M2SH = mt + 14336;
    const __hip_bfloat16* M2SL = mt + 17408;
    for (int tt = wv; tt < 6; tt += 4) {
      int mtI = tt >> 1, ntI = tt & 1;
      f32x4 aC1 = {0.f,0.f,0.f,0.f}, aS1 = {0.f,0.f,0.f,0.f};
      f32x4 aC2 = {0.f,0.f,0.f,0.f}, aS2 = {0.f,0.f,0.f,0.f};
#pragma unroll
      for (int ks = 0; ks < 2; ++ks) {
        int arow = mtI * 16 + lm;
        int k0 = ks * 32 + kg * 8;
        bf16x8 CH = *(const bf16x8*)(M2CH + arow * 64 + k0);
        bf16x8 CL = *(const bf16x8*)(M2CL + arow * 64 + k0);
        bf16x8 SH = *(const bf16x8*)(M2SH + arow * 64 + k0);
        bf16x8 SL = *(const bf16x8*)(M2SL + arow * 64 + k0);
        int brow = ntI * 16 + lm;
        bf16x8 ReH = *(const bf16x8*)(&Yt[0][brow * 72 + k0]);
        bf16x8 ReL = *(const bf16x8*)(&Yt[1][brow * 72 + k0]);
        bf16x8 ImH = *(const bf16x8*)(&Yt[2][brow * 72 + k0]);
        bf16x8 ImL = *(const bf16x8*)(&Yt[3][brow * 72 + k0]);
        aC1 = MFMA16(CH, ReH, aC1); aC1 = MFMA16(CH, ReL, aC1); aC1 = MFMA16(CL, ReH, aC1);
        aS2 = MFMA16(SH, ImH, aS2); aS2 = MFMA16(SH, ImL, aS2); aS2 = MFMA16(SL, ImH, aS2);
        aC2 = MFMA16(CH, ImH, aC2); aC2 = MFMA16(CH, ImL, aC2); aC2 = MFMA16(CL, ImH, aC2);
        aS1 = MFMA16(SH, ReH, aS1); aS1 = MFMA16(SH, ReL, aS1); aS1 = MFMA16(SL, ReH, aS1);
      }
      int u = ntI * 16 + lm;
      if (u < 25) {
#pragma unroll
        for (int r = 0; r < 4; ++r) {
          int v = mtI * 16 + kg * 4 + r;
          float zre = aC1[r] + aS2[r];
          float zim = aC2[r] - aS1[r];
          float am = sqrtf(zre * zre + zim * zim);
          float ph = atan2f(zim, zre);
          int i = v * 25 + u;
          size_t o;
          if (tlay) o = ((size_t)(bc >> 5) * 1200 + i) * 32 + (bc & 31);
          else      o = (size_t)bc * 1200 + i;
          amp[o] = __float2bfloat16(am);
          pha[o] = __float2bfloat16(ph);
        }
      }
    }
  }
}

// ---------------- polar + irfft2 via MFMA -> hi/lo bf16 chunk-planar ----------------
__global__ void __launch_bounds__(256)
polar_irfft2_mfma(const float* __restrict__ amp, const float* __restrict__ pha,
                  const __hip_bfloat16* __restrict__ mt,
                  __hip_bfloat16* __restrict__ oh, __hip_bfloat16* __restrict__ ol) {
  const int bc = blockIdx.x;
  __shared__ __align__(16) __hip_bfloat16 Zt[4][32 * 72];
  __shared__ __align__(16) __hip_bfloat16 Yp[4][48 * 56];
  const int tid = threadIdx.x;
  const int lane = tid & 63, lm = lane & 15, kg = lane >> 4, wv = tid >> 6;

  for (int i = tid; i < 4 * 32 * 72; i += 256) ((unsigned short*)Zt)[i] = 0;
  for (int i = tid; i < 4 * 48 * 56; i += 256) ((unsigned short*)Yp)[i] = 0;
  __syncthreads();
  for (int i = tid; i < 1200; i += 256) {
    int v = i / 25, u = i - v * 25;
    float a = amp[(size_t)bc * 1200 + i];
    float p = pha[(size_t)bc * 1200 + i];
    float sc = (u == 0 || u == 24) ? (1.f / 48.f) : (2.f / 48.f);
    float zre = a * cosf(p) * sc;
    float zim = a * sinf(p) * sc;
    __hip_bfloat16 h0 = __float2bfloat16(zre);
    Zt[0][u * 72 + v] = h0;
    Zt[1][u * 72 + v] = __float2bfloat16(zre - __bfloat162float(h0));
    __hip_bfloat16 h1 = __float2bfloat16(zim);
    Zt[2][u * 72 + v] = h1;
    Zt[3][u * 72 + v] = __float2bfloat16(zim - __bfloat162float(h1));
  }
  __syncthreads();

  {
    const __hip_bfloat16* M2CH = mt + 8192;
    const __hip_bfloat16* M2CL = mt + 11264;
    const __hip_bfloat16* M2SH = mt + 14336;
    const __hip_bfloat16* M2SL = mt + 17408;
    for (int t = wv; t < 6; t += 4) {
      int mtI = t >> 1, ntI = t & 1;
      f32x4 aC1 = {0.f,0.f,0.f,0.f}, aS1 = {0.f,0.f,0.f,0.f};
      f32x4 aC2 = {0.f,0.f,0.f,0.f}, aS2 = {0.f,0.f,0.f,0.f};
#pragma unroll
      for (int ks = 0; ks < 2; ++ks) {
        int arow = mtI * 16 + lm;
        int k0 = ks * 32 + kg * 8;
        bf16x8 CH = *(const bf16x8*)(M2CH + arow * 64 + k0);
        bf16x8 CL = *(const bf16x8*)(M2CL + arow * 64 + k0);
        bf16x8 SH = *(const bf16x8*)(M2SH + arow * 64 + k0);
        bf16x8 SL = *(const bf16x8*)(M2SL + arow * 64 + k0);
        int brow = ntI * 16 + lm;
        bf16x8 ReH = *(const bf16x8*)(&Zt[0][brow * 72 + k0]);
        bf16x8 ReL = *(const bf16x8*)(&Zt[1][brow * 72 + k0]);
        bf16x8 ImH = *(const bf16x8*)(&Zt[2][brow * 72 + k0]);
        bf16x8 ImL = *(const bf16x8*)(&Zt[3][brow * 72 + k0]);
        aC1 = MFMA16(CH, ReH, aC1); aC1 = MFMA16(CH, ReL, aC1); aC1 = MFMA16(CL, ReH, aC1);
        aS2 = MFMA16(SH, ImH, aS2); aS2 = MFMA16(SH, ImL, aS2); aS2 = MFMA16(SL, ImH, aS2);
        aC2 = MFMA16(CH, ImH, aC2); aC2 = MFMA16(CH, ImL, aC2); aC2 = MFMA16(CL, ImH, aC2);
        aS1 = MFMA16(SH, ReH, aS1); aS1 = MFMA16(SH, ReL, aS1); aS1 = MFMA16(SL, ReH, aS1);
      }
      int u = ntI * 16 + lm;
      if (u < 25) {
#pragma unroll
        for (int r = 0; r < 4; ++r) {
          int h = mtI * 16 + kg * 4 + r;
          float yre = aC1[r] - aS2[r];
          float yim = aS1[r] + aC2[r];
          __hip_bfloat16 h0 = __float2bfloat16(yre);
          Yp[0][h * 56 + u] = h0;
          Yp[1][h * 56 + u] = __float2bfloat16(yre - __bfloat162float(h0));
          __hip_bfloat16 h1 = __float2bfloat16(yim);
          Yp[2][h * 56 + u] = h1;
          Yp[3][h * 56 + u] = __float2bfloat16(yim - __bfloat162float(h1));
        }
      }
    }
  }
  __syncthreads();

  {
    const __hip_bfloat16* W3CH = mt + 20480;
    const __hip_bfloat16* W3CL = mt + 22016;
    const __hip_bfloat16* W3SH = mt + 23552;   // -sin
    const __hip_bfloat16* W3SL = mt + 25088;
    const int cch = bc & 255;
    const size_t obase = ((size_t)((bc >> 8) * 8 + (cch >> 5)) * HW) * 32 + (cch & 31);
    for (int t = wv; t < 9; t += 4) {
      int mtI = t / 3, ntI = t - (t / 3) * 3;
      f32x4 acc = {0.f, 0.f, 0.f, 0.f};
      int k0 = kg * 8;
      bf16x8 AH = *(const bf16x8*)(&Yp[0][(mtI * 16 + lm) * 56 + k0]);
      bf16x8 AL = *(const bf16x8*)(&Yp[1][(mtI * 16 + lm) * 56 + k0]);
      bf16x8 IH = *(const bf16x8*)(&Yp[2][(mtI * 16 + lm) * 56 + k0]);
      bf16x8 IL = *(const bf16x8*)(&Yp[3][(mtI * 16 + lm) * 56 + k0]);
      int brow = ntI * 16 + lm;
      bf16x8 CH = *(const bf16x8*)(W3CH + brow * 32 + k0);
      bf16x8 CL = *(const bf16x8*)(W3CL + brow * 32 + k0);
      bf16x8 SH = *(const bf16x8*)(W3SH + brow * 32 + k0);
      bf16x8 SL = *(const bf16x8*)(W3SL + brow * 32 + k0);
      acc = MFMA16(AH, CH, acc); acc = MFMA16(AH, CL, acc); acc = MFMA16(AL, CH, acc);
      acc = MFMA16(IH, SH, acc); acc = MFMA16(IH, SL, acc); acc = MFMA16(IL, SH, acc);
#pragma unroll
      for (int r = 0; r < 4; ++r) {
        int h = mtI * 16 + kg * 4 + r;
        int p = h * 48 + brow;
        float v = acc[r];
        __hip_bfloat16 hh = __float2bfloat16(v);
        oh[obase + (size_t)p * 32] = hh;
        ol[obase + (size_t)p * 32] = __float2bfloat16(v - __bfloat162float(hh));
      }
    }
  }
}

// ---------------- MFMA attention v5p: 64-key tiles + ballot defer-max + XCD swizzle + setprio ----------------
__global__ void __launch_bounds__(64)
attn_mfma5(const __hip_bfloat16* __restrict__ Qb, const __hip_bfloat16* __restrict__ Kb,
           const __hip_bfloat16* __restrict__ Vb, float* __restrict__ Ob) {
  const int lin = blockIdx.x;
  const int xcd = lin & 7;
  const int idx = lin >> 3;          // 0..599
  const int pr = xcd * 8 + idx / 75; // 0..63
  const int m0 = (idx % 75) * 16;
  const int z = pr >> 5;
  const int bh = pr & 31;
  const __hip_bfloat16* Qt = Qb + (size_t)z * 1228800;
  const __hip_bfloat16* Kt = Kb + (size_t)z * 1228800;
  const __hip_bfloat16* Vc = Vb + (size_t)z * 1228800;
  float* Om = Ob + (size_t)z * 1228800;
  const int lane = threadIdx.x;
  const int lm = lane & 15, kg = lane >> 4;
  __shared__ unsigned short Pl[2][16][40];
  __shared__ float fl[16];
  __shared__ float linv[16];
  const __hip_bfloat16* Qp = Qt + ((size_t)bh * 1200 + m0) * 32;
  const __hip_bfloat16* Kp = Kt + (size_t)bh * 38400;
  const __hip_bfloat16* Vp = Vc + (size_t)bh * 38400;
  const bf16x8 qf = *(const bf16x8*)(Qp + lm * 32 + kg * 8);
  const float Cs = ATT_SCALE * 1.44269504f;

  f32x4 acc0 = {0.f, 0.f, 0.f, 0.f}, acc1 = {0.f, 0.f, 0.f, 0.f};
  float psum = 0.f, mreg = -3.0e38f;

  for (int G = 0; G < 19; ++G) {
    const int n0 = G * 64;
    const bool s3ok = (G < 18);      // keys n0+48..n0+63 valid
    bf16x8 kf0 = *(const bf16x8*)(Kp + (size_t)(n0 + lm) * 32 + kg * 8);
    bf16x8 kf1 = *(const bf16x8*)(Kp + (size_t)(n0 + 16 + lm) * 32 + kg * 8);
    bf16x8 kf2 = *(const bf16x8*)(Kp + (size_t)(n0 + 32 + lm) * 32 + kg * 8);
    __builtin_amdgcn_s_setprio(1);
    f32x4 d0 = {0.f, 0.f, 0.f, 0.f}; d0 = MFMA16(kf0, qf, d0);
    f32x4 d1 = {0.f, 0.f, 0.f, 0.f}; d1 = MFMA16(kf1, qf, d1);
    f32x4 d2 = {0.f, 0.f, 0.f, 0.f}; d2 = MFMA16(kf2, qf, d2);
    f32x4 d3 = {0.f, 0.f, 0.f, 0.f};
    if (s3ok) {
      bf16x8 kf3 = *(const bf16x8*)(Kp + (size_t)(n0 + 48 + lm) * 32 + kg * 8);
      d3 = MFMA16(kf3, qf, d3);
    }
    __builtin_amdgcn_s_setprio(0);
    float tm = fmaxf(fmaxf(fmaxf(d0[0], d0[1]), fmaxf(d0[2], d0[3])),
                     fmaxf(fmaxf(d1[0], d1[1]), fmaxf(d1[2], d1[3])));
    tm = fmaxf(tm, fmaxf(fmaxf(d2[0], d2[1]), fmaxf(d2[2], d2[3])));
    if (s3ok) tm = fmaxf(tm, fmaxf(fmaxf(d3[0], d3[1]), fmaxf(d3[2], d3[3])));
    tm = fmaxf(tm, __shfl_xor(tm, 16));
    tm = fmaxf(tm, __shfl_xor(tm, 32));
    const bool grow = (__ballot(tm > mreg) != 0ull);   // wave-uniform
    if (grow) {
      float nm = fmaxf(mreg, tm);
      float ff = exp2f((mreg - nm) * Cs);
      mreg = nm;
      if (kg == 0) fl[lm] = ff;
      psum *= ff;
    }
    const float mb = mreg * Cs;
    float p0 = exp2f(d0[0] * Cs - mb), p1 = exp2f(d0[1] * Cs - mb);
    float p2 = exp2f(d0[2] * Cs - mb), p3 = exp2f(d0[3] * Cs - mb);
    float p4 = exp2f(d1[0] * Cs - mb), p5 = exp2f(d1[1] * Cs - mb);
    float p6 = exp2f(d1[2] * Cs - mb), p7 = exp2f(d1[3] * Cs - mb);
    float p8 = exp2f(d2[0] * Cs - mb), p9 = exp2f(d2[1] * Cs - mb);
    float pa_ = exp2f(d2[2] * Cs - mb), pb_ = exp2f(d2[3] * Cs - mb);
    float ps = p0 + p1 + p2 + p3 + p4 + p5 + p6 + p7 + p8 + p9 + pa_ + pb_;
    ushort4 w0, w1, w2, w3;
    w0.x = __builtin_bit_cast(unsigned short, __float2bfloat16(p0));
    w0.y = __builtin_bit_cast(unsigned short, __float2bfloat16(p1));
    w0.z = __builtin_bit_cast(unsigned short, __float2bfloat16(p2));
    w0.w = __builtin_bit_cast(unsigned short, __float2bfloat16(p3));
    w1.x = __builtin_bit_cast(unsigned short, __float2bfloat16(p4));
    w1.y = __builtin_bit_cast(unsigned short, __float2bfloat16(p5));
    w1.z = __builtin_bit_cast(unsigned short, __float2bfloat16(p6));
    w1.w = __builtin_bit_cast(unsigned short, __float2bfloat16(p7));
    w2.x = __builtin_bit_cast(unsigned short, __float2bfloat16(p8));
    w2.y = __builtin_bit_cast(unsigned short, __float2bfloat16(p9));
    w2.z = __builtin_bit_cast(unsigned short, __float2bfloat16(pa_));
    w2.w = __builtin_bit_cast(unsigned short, __float2bfloat16(pb_));
    if (s3ok) {
      float pc_ = exp2f(d3[0] * Cs - mb), pd_ = exp2f(d3[1] * Cs - mb);
      float pe_ = exp2f(d3[2] * Cs - mb), pf_ = exp2f(d3[3] * Cs - mb);
      ps += pc_ + pd_ + pe_ + pf_;
      w3.x = __builtin_bit_cast(unsigned short, __float2bfloat16(pc_));
      w3.y = __builtin_bit_cast(unsigned short, __float2bfloat16(pd_));
      w3.z = __builtin_bit_cast(unsigned short, __float2bfloat16(pe_));
      w3.w = __builtin_bit_cast(unsigned short, __float2bfloat16(pf_));
    } else {
      w3.x = w3.y = w3.z = w3.w = 0;
    }
    psum += ps;
    *(ushort4*)(&Pl[0][lm][kg * 4]) = w0;
    *(ushort4*)(&Pl[0][lm][16 + kg * 4]) = w1;
    *(ushort4*)(&Pl[1][lm][kg * 4]) = w2;
    *(ushort4*)(&Pl[1][lm][16 + kg * 4]) = w3;
    if (grow) {
      float4 f4 = *(const float4*)(&fl[kg * 4]);
      acc0[0] *= f4.x; acc0[1] *= f4.y; acc0[2] *= f4.z; acc0[3] *= f4.w;
      acc1[0] *= f4.x; acc1[1] *= f4.y; acc1[2] *= f4.z; acc1[3] *= f4.w;
    }
    bf16x8 pa0 = *(const bf16x8*)(&Pl[0][lm][kg * 8]);
    bf16x8 pa1 = *(const bf16x8*)(&Pl[1][lm][kg * 8]);
    bf16x8 v00 = *(const bf16x8*)(Vp + (size_t)lm * 1200 + n0 + kg * 8);
    bf16x8 v01 = *(const bf16x8*)(Vp + (size_t)(16 + lm) * 1200 + n0 + kg * 8);
    bf16x8 v10 = *(const bf16x8*)(Vp + (size_t)lm * 1200 + n0 + 32 + kg * 8);
    bf16x8 v11 = *(const bf16x8*)(Vp + (size_t)(16 + lm) * 1200 + n0 + 32 + kg * 8);
    __builtin_amdgcn_s_setprio(1);
    acc0 = MFMA16(pa0, v00, acc0);
    acc1 = MFMA16(pa0, v01, acc1);
    acc0 = MFMA16(pa1, v10, acc0);
    acc1 = MFMA16(pa1, v11, acc1);
    __builtin_amdgcn_s_setprio(0);
  }
  psum += __shfl_xor(psum, 16);
  psum += __shfl_xor(psum, 32);
  if (kg == 0) linv[lm] = 1.f / psum;
  __syncthreads();
#pragma unroll
  for (int r = 0; r < 4; ++r) {
    int m = m0 + kg * 4 + r;
    float li = linv[kg * 4 + r];
    Om[(size_t)bh * 38400 + (size_t)lm * 1200 + m] = acc0[r] * li;
    Om[(size_t)bh * 38400 + (size_t)(16 + lm) * 1200 + m] = acc1[r] * li;
  }
}

// ---------------- pack3: packw(w1) + packw(w2) + packx(ATT) + pad-zero Xp1/Xp2; grid 1290 ----------------
// Runs AFTER OUTH/Qb (which alias Xp1/Xp2) are dead — pads must be zeroed here, not earlier.
__global__ void pack3_kernel(const float* __restrict__ w1, const float* __restrict__ w2,
                             const float* __restrict__ att,
                             __hip_bfloat16* __restrict__ Wp1, __hip_bfloat16* __restrict__ Wp2,
                             __hip_bfloat16* __restrict__ xp, __hip_bfloat16* __restrict__ Xp2) {
  const int b = blockIdx.x, tid = threadIdx.x;
  if (b < 512) {              // w1: [512 o][256 c][9] -> [tap][8][512][32]
    int t = b * 256 + tid;
    int o = t >> 8, c = t & 255;
#pragma unroll
    for (int tap = 0; tap < 9; ++tap)
      Wp1[(((size_t)tap * 8 + (c >> 5)) * 512 + o) * 32 + (c & 31)] = __float2bfloat16(w1[(size_t)t * 9 + tap]);
  } else if (b < 1024) {      // w2: [256 o][512 c][9] -> [tap][16][256][32]
    int t = (b - 512) * 256 + tid;
    int o = t >> 9, c = t & 511;
#pragma unroll
    for (int tap = 0; tap < 9; ++tap)
      Wp2[(((size_t)tap * 16 + (c >> 5)) * 256 + o) * 32 + (c & 31)] = __float2bfloat16(w2[(size_t)t * 9 + tap]);
  } else if (b < 1216) {      // packx: ATT f32 NCHW -> bf16 chunk-planar padded (interior)
    int s = b - 1024;         // 0..191
    int y = s % 48, img = s / 48;
    int c = tid;
    const float* ip = att + ((size_t)(img * 256 + c) * 48 + y) * 48;
    __hip_bfloat16* op = xp + ((size_t)(img * 8 + (c >> 5)) * 2500 + (size_t)(y + 1) * 50 + 1) * 32 + (c & 31);
    for (int x = 0; x < 48; ++x) op[x * 32] = __float2bfloat16(ip[x]);
  } else {                    // pad-zero borders: Xp1 32 planes + Xp2 64 planes, 196 cells/plane
    int idx = (b - 1216) * 256 + tid;
    if (idx < 18816) {
      __hip_bfloat16* base;
      int plane, cell;
      if (idx < 6272) { base = xp; plane = idx / 196; cell = idx % 196; }
      else { int j = idx - 6272; base = Xp2; plane = j / 196; cell = j % 196; }
      int row, col;
      if (cell < 50) { row = 0; col = cell; }
      else if (cell < 100) { row = 49; col = cell - 50; }
      else if (cell < 148) { row = 1 + (cell - 100); col = 0; }
      else { row = 1 + (cell - 148); col = 49; }
      float4* p = (float4*)(base + ((size_t)plane * 2500 + row * 50 + col) * 32);
      float4 z = make_float4(0.f, 0.f, 0.f, 0.f);
      p[0] = z; p[1] = z; p[2] = z; p[3] = z;
    }
  }
}

// ---------------- addpack: (a + b) f32 NCHW -> hi/lo bf16 chunk-planar ----------------
__global__ void addpack_kernel(const float* __restrict__ a, const float* __restrict__ b,
                               __hip_bfloat16* __restrict__ oh, __hip_bfloat16* __restrict__ ol) {
  int i = blockIdx.x * 256 + threadIdx.x;   // float4 index over U/4
  float4 x = ((const float4*)a)[i];
  float4 y = ((const float4*)b)[i];
  x.x += y.x; x.y += y.y; x.z += y.z; x.w += y.w;
  int e = i * 4;
  int img = e / 589824, rem = e - img * 589824;
  int c = rem / 2304, px = rem - c * 2304;
  size_t ob = ((size_t)(img * 8 + (c >> 5)) * HW) * 32 + (c & 31);
  float vv[4] = {x.x, x.y, x.z, x.w};
#pragma unroll
  for (int j = 0; j < 4; ++j) {
    __hip_bfloat16 h = __float2bfloat16(vv[j]);
    oh[ob + (size_t)(px + j) * 32] = h;
    ol[ob + (size_t)(px + j) * 32] = __float2bfloat16(vv[j] - __bfloat162float(h));
  }
}

// ---------------- MFMA 3x3 conv v8: LDS-staged chunks (proven: 0 bank conflicts) ----------------
template <int CIN, int CO, bool TO_PAD, int KS>
__global__ void __launch_bounds__(256)
mfconv3x3(const __hip_bfloat16* __restrict__ Xp, const __hip_bfloat16* __restrict__ Wp,
          __hip_bfloat16* __restrict__ Op, float* __restrict__ Of) {
  constexpr int NC = CIN / 32;
  constexpr int KC = NC / KS;
  constexpr int MT = CO / 32;
  const int q = gridDim.x >> 3;
  const int swz = (blockIdx.x & 7) * q + (blockIdx.x >> 3);
  const int mt = swz % MT;
  const int ks = (swz / MT) % KS;
  const int rq = swz / (MT * KS);       // 0..47
  const int img = rq / 12;
  const int y0b = (rq % 12) * 4;
  const int tid = threadIdx.x;
  const int wv = tid >> 6;
  const int y = y0b + wv;
  const int lane = tid & 63;
  const int lm = lane & 15, kg = lane >> 4;
  const int o0 = mt * 32;
  const int ci0 = ks * KC;

  __shared__ __hip_bfloat16 Als[9216];   // [tap][32o][32c]
  __shared__ __hip_bfloat16 Bls[9600];   // [6 rows][50][32c]

  f32x4 acc[2][3];
#pragma unroll
  for (int f = 0; f < 2; ++f)
#pragma unroll
    for (int g = 0; g < 3; ++g) acc[f][g] = (f32x4){0.f, 0.f, 0.f, 0.f};

  for (int ci = 0; ci < KC; ++ci) {
    const int cic = ci0 + ci;
    const size_t wst = ((size_t)cic * CO + o0) * 32;
    const size_t bst = ((size_t)(img * NC + cic) * 2500 + (size_t)y0b * 50) * 32;
    __syncthreads();
    for (int c = tid; c < 2352; c += 256) {
      if (c < 1152) {
        int tap = c >> 7, rem = c & 127;
        float4 v = *(const float4*)(Wp + wst + (size_t)tap * (NC * CO * 32) + rem * 8);
        *(float4*)(&Als[c * 8]) = v;
      } else {
        int c2 = c - 1152;
        float4 v = *(const float4*)(Xp + bst + (size_t)c2 * 8);
        *(float4*)(&Bls[c2 * 8]) = v;
      }
    }
    __syncthreads();
#pragma unroll
    for (int tap = 0; tap < 9; ++tap) {
      const int dy = tap / 3 - 1, dx = tap - (tap / 3) * 3 - 1;
      bf16x8 A0 = *(const bf16x8*)(&Als[tap * 1024 + lm * 32 + kg * 8]);
      bf16x8 A1 = *(const bf16x8*)(&Als[tap * 1024 + 512 + lm * 32 + kg * 8]);
      const int bbase = ((wv + 1 + dy) * 50 + 1 + dx + lm) * 32 + kg * 8;
      bf16x8 B0 = *(const bf16x8*)(&Bls[bbase]);
      bf16x8 B1 = *(const bf16x8*)(&Bls[bbase + 512]);
      bf16x8 B2 = *(const bf16x8*)(&Bls[bbase + 1024]);
      acc[0][0] = MFMA16(A0, B0, acc[0][0]);
      acc[0][1] = MFMA16(A0, B1, acc[0][1]);
      acc[0][2] = MFMA16(A0, B2, acc[0][2]);
      acc[1][0] = MFMA16(A1, B0, acc[1][0]);
      acc[1][1] = MFMA16(A1, B1, acc[1][1]);
      acc[1][2] = MFMA16(A1, B2, acc[1][2]);
    }
  }

  if (TO_PAD) {
    const int cio = o0 >> 5;
#pragma unroll
    for (int f = 0; f < 2; ++f) {
      const int cc = f * 16 + kg * 4;
#pragma unroll
      for (int g = 0; g < 3; ++g) {
        int x = g * 16 + lm;
        ushort4 st;
        float v0 = acc[f][g][0], v1 = acc[f][g][1], v2 = acc[f][g][2], v3 = acc[f][g][3];
        v0 = v0 / (1.f + __expf(-v0)); v1 = v1 / (1.f + __expf(-v1));
        v2 = v2 / (1.f + __expf(-v2)); v3 = v3 / (1.f + __expf(-v3));
        st.x = __builtin_bit_cast(unsigned short, __float2bfloat16(v0));
        st.y = __builtin_bit_cast(unsigned short, __float2bfloat16(v1));
        st.z = __builtin_bit_cast(unsigned short, __float2bfloat16(v2));
        st.w = __builtin_bit_cast(unsigned short, __float2bfloat16(v3));
        *(ushort4*)(Op + (((size_t)(img * (CO / 32) + cio) * 2500 + (size_t)(y + 1) * 50 + (x + 1)) * 32 + cc)) = st;
      }
    }
  } else {
    float* Ofp = Of + (size_t)ks * 4 * CO * HW;
#pragma unroll
    for (int f = 0; f < 2; ++f)
#pragma unroll
      for (int g = 0; g < 3; ++g) {
        int x = g * 16 + lm;
#pragma unroll
        for (int r = 0; r < 4; ++r) {
          int o = o0 + f * 16 + kg * 4 + r;
          Ofp[((size_t)img * CO + o) * HW + y * 48 + x] = acc[f][g][r];
        }
      }
  }
}

extern "C" void kernel_launch(void* const* d_in, const int* in_sizes, int n_in,
                              void* d_out, int out_size, void* d_ws, size_t ws_size,
                              hipStream_t stream) {
  (void)in_sizes; (void)n_in; (void)out_size; (void)ws_size;
  const float* x      = (const float*)d_in[0];
  const float* cond   = (const float*)d_in[1];
  const float* gn_w   = (const float*)d_in[2];
  const float* gn_b   = (const float*)d_in[3];
  const float* q_dw   = (const float*)d_in[4];
  const float* q_pw_w = (const float*)d_in[5];
  const float* q_pw_b = (const float*)d_in[6];
  const float* kv_dw  = (const float*)d_in[7];
  const float* kv_pw_w= (const float*)d_in[8];
  const float* kv_pw_b= (const float*)d_in[9];
  const float* ao_w   = (const float*)d_in[10];
  const float* ao_b   = (const float*)d_in[11];
  const float* w1     = (const float*)d_in[12];
  const float* w2     = (const float*)d_in[13];
  const float* w3     = (const float*)d_in[14];
  const float* b3     = (const float*)d_in[15];
  float* ws = (float*)d_ws;
  float* Yo = (float*)d_out;

  const size_t U = 2359296;   // 4*256*48*48 (floats)
  const size_t Hf = 1228800;  // 4*256*48*25 (floats)
  const size_t CS = 589824;   // 256*2304
  const size_t CS2 = 1179648; // 512*2304

  float* XN  = ws;             // [0,U)
  __hip_bfloat16* DWH = (__hip_bfloat16*)(ws + U);       // [U,2U) as 2x bf16 planes
  __hip_bfloat16* DWL = DWH + 2359296;
  float* Qb  = ws + 2 * U;
  float* KV  = ws + 3 * U;     // 2U extent
  __hip_bfloat16* AQT = (__hip_bfloat16*)(ws + 5 * U);
  __hip_bfloat16* AKT = AQT + 2 * 1228800;
  __hip_bfloat16* AVc = AQT + 4 * 1228800;
  float* AO  = ws + 5 * U + 3 * Hf;
  float* PO  = AO + Hf;
  __hip_bfloat16* OUTH = (__hip_bfloat16*)(ws + U);      // reuse dead DW region
  __hip_bfloat16* OUTL = OUTH + 2359296;
  float* ATT = ws + 5 * U;
  __hip_bfloat16* Xp1 = (__hip_bfloat16*)(ws + U);
  __hip_bfloat16* Xp2 = (__hip_bfloat16*)(ws + 2 * U);
  __hip_bfloat16* Wp1 = (__hip_bfloat16*)(ws + 2 * U + 2600000);
  __hip_bfloat16* Wp2 = (__hip_bfloat16*)(ws + 2 * U + 3200000);
  float* H2  = ws;             // K-split partial 0 at [0,U); partial 1 at [U,2U)
  float* H2b = ws + U;
  __hip_bfloat16* H2H = (__hip_bfloat16*)(ws + 5 * U + 3 * Hf);  // reuse dead AO/PO
  __hip_bfloat16* H2L = H2H + 2359296;
  // pw weights (chunk-planar hi/lo bf16) + DFT matrices + gn partials in dead tail
  __hip_bfloat16* BW = (__hip_bfloat16*)(ws + 5 * U + 5 * Hf);
  __hip_bfloat16* QWH = BW,            * QWL = BW + 65536;
  __hip_bfloat16* KWH = BW + 131072,   * KWL = BW + 262144;
  __hip_bfloat16* AWH = BW + 393216,   * AWL = BW + 458752;
  __hip_bfloat16* W3H = BW + 524288,   * W3L = BW + 589824;
  __hip_bfloat16* MT  = BW + 655360;   // 26624 bf16
  float* GNP = ws + 5 * U + 5 * Hf + 341000;   // 1024 floats

  // 0. one-launch setup: pw weight packs + DFT tables
  setup_kernel<<<1314, 256, 0, stream>>>(q_pw_w, kv_pw_w, ao_w, w3,
                                         QWH, QWL, KWH, KWL, AWH, AWL, W3H, W3L, MT);
  // 1. GroupNorm
  gn1_kernel<<<512, 256, 0, stream>>>(x, GNP);
  gn2_kernel<<<512, 256, 0, stream>>>(x, GNP, gn_w, gn_b, XN);
  // 2-3. q path
  dw3x3_kernel<<<1024, 256, 0, stream>>>(XN, q_dw, DWH, DWL);
  pw5_kernel<false><<<dim3(18, 4, 4), 256, 0, stream>>>(DWH, DWL, QWH, QWL, q_pw_b, nullptr, 0, Qb, CS, 256);
  // 4-5. kv path
  dw3x3_kernel<<<1024, 256, 0, stream>>>(cond, kv_dw, DWH, DWL);
  pw5_kernel<false><<<dim3(18, 8, 4), 256, 0, stream>>>(DWH, DWL, KWH, KWL, kv_pw_b, nullptr, 0, KV, CS2, 512);
  // 6. L2 norm (q,k,v fused)
  l2n3_kernel<<<dim3(36, 12), 256, 0, stream>>>(Qb, KV);
  // 7. rfft2 (q,k,v fused) via MFMA -> bf16 spectra
  rfft2_all<<<3072, 256, 0, stream>>>(Qb, KV, MT, AQT);
  // 8. MFMA attention v5p
  attn_mfma5<<<4800, 64, 0, stream>>>(AQT, AKT, AVc, AO);
  // 9. polar + irfft2 via MFMA -> hi/lo chunk-planar
  polar_irfft2_mfma<<<1024, 256, 0, stream>>>(AO, PO, MT, OUTH, OUTL);
  // 10. attn_out = 1x1(out) + b + xn  -> ATT (f32 NCHW)
  pw5_kernel<true><<<dim3(18, 4, 4), 256, 0, stream>>>(OUTH, OUTL, AWH, AWL, ao_b, XN, CS, ATT, CS, 256);
  // 11. pack conv weights + input + pad-zero (fused; Xp1/Xp2 aliased regions now dead), then FFN convs
  pack3_kernel<<<1290, 256, 0, stream>>>(w1, w2, ATT, Wp1, Wp2, Xp1, Xp2);
  mfconv3x3<256, 512, true, 1><<<768, 256, 0, stream>>>(Xp1, Wp1, Xp2, nullptr);
  mfconv3x3<512, 256, false, 2><<<768, 256, 0, stream>>>(Xp2, Wp2, nullptr, H2);
  // merge K-split partials + pack to hi/lo chunk-planar
  addpack_kernel<<<2304, 256, 0, stream>>>(H2, H2b, H2H, H2L);
  // 12. out = 1x1(h2) + b3 + attn_out
  pw5_kernel<true><<<dim3(18, 4, 4), 256, 0, stream>>>(H2H, H2L, W3H, W3L, b3, ATT, CS, Yo, CS, 256);
}

// Round 24
// 426.640 us; speedup vs baseline: 1.1456x; 1.0040x over previous
//
#include <hip/hip_runtime.h>
#include <hip/hip_bf16.h>
#include <math.h>

// Problem constants
constexpr int Bn = 4, Cn = 256, Hn = 48, Wn = 48, HW = 2304;
constexpr float ATT_SCALE = 0.17677669529663687f;  // 1/sqrt(32)

typedef __attribute__((ext_vector_type(8))) short bf16x8;
typedef __attribute__((ext_vector_type(4))) float f32x4;

#define MFMA16(A, B, C) __builtin_amdgcn_mfma_f32_16x16x32_bf16(A, B, C, 0, 0, 0)

// ---------------- GroupNorm two-phase ----------------
__global__ void gn1_kernel(const float* __restrict__ x, float* __restrict__ part) {
  int bg = blockIdx.x >> 2, ck = blockIdx.x & 3;
  const float4* xp = (const float4*)(x + (size_t)bg * 18432 + ck * 4608);
  float s = 0.f, ss = 0.f;
  for (int i = threadIdx.x; i < 1152; i += 256) {
    float4 v = xp[i];
    s += v.x + v.y + v.z + v.w;
    ss += v.x * v.x + v.y * v.y + v.z * v.z + v.w * v.w;
  }
#pragma unroll
  for (int off = 32; off; off >>= 1) { s += __shfl_xor(s, off); ss += __shfl_xor(ss, off); }
  __shared__ float rs[4], rss[4];
  int wid = threadIdx.x >> 6;
  if ((threadIdx.x & 63) == 0) { rs[wid] = s; rss[wid] = ss; }
  __syncthreads();
  if (threadIdx.x == 0) {
    part[blockIdx.x * 2] = rs[0] + rs[1] + rs[2] + rs[3];
    part[blockIdx.x * 2 + 1] = rss[0] + rss[1] + rss[2] + rss[3];
  }
}

__global__ void gn2_kernel(const float* __restrict__ x, const float* __restrict__ part,
                           const float* __restrict__ gw, const float* __restrict__ gb,
                           float* __restrict__ y) {
  int bg = blockIdx.x >> 2, ck = blockIdx.x & 3;
  float s = part[bg * 8] + part[bg * 8 + 2] + part[bg * 8 + 4] + part[bg * 8 + 6];
  float ss = part[bg * 8 + 1] + part[bg * 8 + 3] + part[bg * 8 + 5] + part[bg * 8 + 7];
  float mean = s * (1.f / 18432.f);
  float var = ss * (1.f / 18432.f) - mean * mean;
  float inv = rsqrtf(var + 1e-5f);
  int g = bg & 31;
  const float4* xp = (const float4*)(x + (size_t)bg * 18432 + ck * 4608);
  float4* yp = (float4*)(y + (size_t)bg * 18432 + ck * 4608);
  for (int i = threadIdx.x; i < 1152; i += 256) {
    int c = (g << 3) + ((ck * 1152 + i) / 576);
    float w = gw[c] * inv, b = gb[c];
    float4 v = xp[i];
    v.x = (v.x - mean) * w + b; v.y = (v.y - mean) * w + b;
    v.z = (v.z - mean) * w + b; v.w = (v.w - mean) * w + b;
    yp[i] = v;
  }
}

// ---------------- Depthwise 3x3 -> hi/lo bf16 chunk-planar [img][8ci][2304][32] ----------------
// XCD line-locality swizzle: the 32 blocks of a channel-chunk share output cache lines; keep
// them on one XCD so lines merge in local L2 (grid 1024 = 8 x 128, 128 % 32 == 0).
__global__ void dw3x3_kernel(const float* __restrict__ in, const float* __restrict__ wd,
                             __hip_bfloat16* __restrict__ oh, __hip_bfloat16* __restrict__ ol) {
  int bc = (blockIdx.x & 7) * 128 + (blockIdx.x >> 3);
  int c = bc & 255;
  const float* ip = in + (size_t)bc * HW;
  const size_t ob = ((size_t)((bc >> 8) * 8 + (c >> 5)) * HW) * 32 + (c & 31);
  float w[9];
#pragma unroll
  for (int k = 0; k < 9; ++k) w[k] = wd[c * 9 + k];
  for (int p = threadIdx.x; p < HW; p += 256) {
    int yy = p / 48, xx = p - yy * 48;
    float a = 0.f;
#pragma unroll
    for (int ky = 0; ky < 3; ++ky) {
      int y2 = yy + ky - 1;
      if ((unsigned)y2 < 48u) {
#pragma unroll
        for (int kx = 0; kx < 3; ++kx) {
          int x2 = xx + kx - 1;
          if ((unsigned)x2 < 48u) a += ip[y2 * 48 + x2] * w[ky * 3 + kx];
        }
      }
    }
    __hip_bfloat16 h = __float2bfloat16(a);
    oh[ob + (size_t)p * 32] = h;
    ol[ob + (size_t)p * 32] = __float2bfloat16(a - __bfloat162float(h));
  }
}

// ---------------- setup: 4x pwpack + DFT tables (one launch; NO pad-zero here — aliasing) ----------------
__global__ void setup_kernel(const float* __restrict__ q_pw_w, const float* __restrict__ kv_pw_w,
                             const float* __restrict__ ao_w, const float* __restrict__ w3,
                             __hip_bfloat16* __restrict__ QWH, __hip_bfloat16* __restrict__ QWL,
                             __hip_bfloat16* __restrict__ KWH, __hip_bfloat16* __restrict__ KWL,
                             __hip_bfloat16* __restrict__ AWH, __hip_bfloat16* __restrict__ AWL,
                             __hip_bfloat16* __restrict__ W3H, __hip_bfloat16* __restrict__ W3L,
                             __hip_bfloat16* __restrict__ mt) {
  const int b = blockIdx.x, tid = threadIdx.x;
  if (b < 1280) {
    const float* w; __hip_bfloat16 *WH, *WL; int O, q;
    if (b < 256)       { w = q_pw_w;  WH = QWH; WL = QWL; O = 256; q = b * 256 + tid; }
    else if (b < 768)  { w = kv_pw_w; WH = KWH; WL = KWL; O = 512; q = (b - 256) * 256 + tid; }
    else if (b < 1024) { w = ao_w;    WH = AWH; WL = AWL; O = 256; q = (b - 768) * 256 + tid; }
    else               { w = w3;      WH = W3H; WL = W3L; O = 256; q = (b - 1024) * 256 + tid; }
    int o = q >> 8, c = q & 255;
    float v = w[q];
    __hip_bfloat16 h = __float2bfloat16(v);
    size_t idx = ((size_t)(c >> 5) * O + o) * 32 + (c & 31);
    WH[idx] = h;
    WL[idx] = __float2bfloat16(v - __bfloat162float(h));
  } else {
    int t = (b - 1280) * 256 + tid;
    const float TP = 6.283185307179586f;
    if (t < 4096) {
      int up = t >> 6, w = t & 63;
      float v = 0.f;
      if (w < 48 && up < 50) {
        int u = (up < 25) ? up : up - 25;
        float ang = TP * (float)((w * u) % 48) / 48.f;
        v = ((up < 25) ? cosf(ang) : -sinf(ang)) * (1.f / 48.f);
      }
      __hip_bfloat16 h = __float2bfloat16(v);
      mt[t] = h; mt[4096 + t] = __float2bfloat16(v - __bfloat162float(h));
    } else if (t < 7168) {
      int q = t - 4096;
      int vv = q >> 6, h = q & 63;
      float c = 0.f, s = 0.f;
      if (h < 48) {
        float ang = TP * (float)((vv * h) % 48) / 48.f;
        c = cosf(ang); s = sinf(ang);
      }
      __hip_bfloat16 ch = __float2bfloat16(c);
      mt[8192 + q] = ch; mt[11264 + q] = __float2bfloat16(c - __bfloat162float(ch));
      __hip_bfloat16 sh = __float2bfloat16(s);
      mt[14336 + q] = sh; mt[17408 + q] = __float2bfloat16(s - __bfloat162float(sh));
    } else if (t < 8704) {
      int q = t - 7168;
      int w = q >> 5, u = q & 31;
      float c = 0.f, s = 0.f;
      if (u < 25) {
        float ang = TP * (float)((u * w) % 48) / 48.f;
        c = cosf(ang); s = -sinf(ang);
      }
      __hip_bfloat16 ch = __float2bfloat16(c);
      mt[20480 + q] = ch; mt[22016 + q] = __float2bfloat16(c - __bfloat162float(ch));
      __hip_bfloat16 sh = __float2bfloat16(s);
      mt[23552 + q] = sh; mt[25088 + q] = __float2bfloat16(s - __bfloat162float(sh));
    }
  }
}

// ---------------- Pointwise 1x1 conv v5: LDS-free hi/lo MFMA GEMM ----------------
template <bool RES>
__global__ void __launch_bounds__(256)
pw5_kernel(const __hip_bfloat16* __restrict__ XH, const __hip_bfloat16* __restrict__ XL,
           const __hip_bfloat16* __restrict__ WH, const __hip_bfloat16* __restrict__ WL,
           const float* __restrict__ bias, const float* __restrict__ res, size_t res_bs,
           float* __restrict__ out, size_t out_bs, int CO) {
  const int tid = threadIdx.x;
  const int wv = tid >> 6, lane = tid & 63, lm = lane & 15, kg = lane >> 4;
  const int px0 = blockIdx.x * 128;
  const int ob = blockIdx.y * 64;
  const int img = blockIdx.z;

  f32x4 acc[4][2];
#pragma unroll
  for (int mt = 0; mt < 4; ++mt) {
    acc[mt][0] = (f32x4){0.f, 0.f, 0.f, 0.f};
    acc[mt][1] = (f32x4){0.f, 0.f, 0.f, 0.f};
  }

  const size_t bb = (size_t)img * 589824 + (size_t)(px0 + wv * 32 + lm) * 32 + kg * 8;
#pragma unroll
  for (int ci = 0; ci < 8; ++ci) {
    const size_t bo = bb + (size_t)ci * 73728;
    bf16x8 BH0 = *(const bf16x8*)(XH + bo);
    bf16x8 BH1 = *(const bf16x8*)(XH + bo + 512);
    bf16x8 BL0 = *(const bf16x8*)(XL + bo);
    bf16x8 BL1 = *(const bf16x8*)(XL + bo + 512);
    const size_t wb = ((size_t)ci * CO + ob + lm) * 32 + kg * 8;
#pragma unroll
    for (int mt = 0; mt < 4; ++mt) {
      bf16x8 AH = *(const bf16x8*)(WH + wb + mt * 512);
      bf16x8 AL = *(const bf16x8*)(WL + wb + mt * 512);
      acc[mt][0] = MFMA16(AH, BH0, acc[mt][0]);
      acc[mt][0] = MFMA16(AH, BL0, acc[mt][0]);
      acc[mt][0] = MFMA16(AL, BH0, acc[mt][0]);
      acc[mt][1] = MFMA16(AH, BH1, acc[mt][1]);
      acc[mt][1] = MFMA16(AH, BL1, acc[mt][1]);
      acc[mt][1] = MFMA16(AL, BH1, acc[mt][1]);
    }
  }

#pragma unroll
  for (int mt = 0; mt < 4; ++mt) {
#pragma unroll
    for (int g = 0; g < 2; ++g) {
      int px = px0 + wv * 32 + g * 16 + lm;
#pragma unroll
      for (int r = 0; r < 4; ++r) {
        int o = ob + mt * 16 + kg * 4 + r;
        float v = acc[mt][g][r] + bias[o];
        if (RES) v += res[(size_t)img * res_bs + (size_t)o * HW + px];
        out[(size_t)img * out_bs + (size_t)o * HW + px] = v;
      }
    }
  }
}

// ---------------- L2 norm fused (q,k,v), grid (36,12) ----------------
__global__ void l2n3_kernel(float* __restrict__ Qb, float* __restrict__ KV) {
  int t = blockIdx.y >> 2;       // 0 q, 1 k, 2 v
  int img = blockIdx.y & 3;
  float* base = (t == 0) ? Qb : (t == 1 ? KV : KV + 589824);
  size_t bstride = (t == 0) ? (size_t)589824 : (size_t)1179648;
  int pxl = threadIdx.x & 63;
  int cg = threadIdx.x >> 6;
  int p = blockIdx.x * 64 + pxl;
  float* q = base + (size_t)img * bstride + p;
  float ss = 0.f;
#pragma unroll 8
  for (int c = cg * 64; c < cg * 64 + 64; ++c) { float v = q[(size_t)c * HW]; ss += v * v; }
  __shared__ float part[4][64];
  __shared__ float sinv[64];
  part[cg][pxl] = ss;
  __syncthreads();
  if (threadIdx.x < 64) {
    float tot = part[0][pxl] + part[1][pxl] + part[2][pxl] + part[3][pxl];
    sinv[pxl] = 1.f / fmaxf(sqrtf(tot), 1e-12f);
  }
  __syncthreads();
  float inv = sinv[pxl];
#pragma unroll 8
  for (int c = cg * 64; c < cg * 64 + 64; ++c) q[(size_t)c * HW] *= inv;
}

// ---------------- rfft2 fused (q,k,v) via MFMA; grid 3072, XCD line-locality swizzle ----------------
// 3072 = 8 x 384; 384 % 32 == 0 so each 32-block line-sharing group stays on one XCD.
__global__ void __launch_bounds__(256)
rfft2_all(const float* __restrict__ Qb, const float* __restrict__ KV,
          const __hip_bfloat16* __restrict__ mt, __hip_bfloat16* __restrict__ spec) {
  const int w_ = (blockIdx.x & 7) * 384 + (blockIdx.x >> 3);   // 0..3071
  const int t = w_ >> 10;     // 0 q, 1 k, 2 v
  const int bc = w_ & 1023;
  const int bi = bc >> 8, ch = bc & 255;
  const float* src = (t == 0) ? Qb : (t == 1 ? KV : KV + 589824);
  const size_t bstride = (t == 0) ? (size_t)589824 : (size_t)1179648;
  const float* ip = src + (size_t)bi * bstride + (size_t)ch * HW;
  __hip_bfloat16* amp = spec + (size_t)(2 * t) * 1228800;
  __hip_bfloat16* pha = spec + (size_t)(2 * t + 1) * 1228800;
  const bool tlay = (t < 2);
  __shared__ __align__(16) __hip_bfloat16 XH[48 * 72], XL[48 * 72];
  __shared__ __align__(16) __hip_bfloat16 Yt[4][32 * 72];  // 0 reH 1 reL 2 imH 3 imL; [u][h]
  const int tid = threadIdx.x;
  const int lane = tid & 63, lm = lane & 15, kg = lane >> 4, wv = tid >> 6;

  for (int i = tid; i < 48 * 72; i += 256) {
    int r = i / 72, w = i - r * 72;
    float v = (w < 48) ? ip[r * 48 + w] : 0.f;
    __hip_bfloat16 h = __float2bfloat16(v);
    XH[i] = h;
    XL[i] = __float2bfloat16(v - __bfloat162float(h));
  }
  for (int i = tid; i < 4 * 32 * 72; i += 256) ((unsigned short*)Yt)[i] = 0;
  __syncthreads();

  {
    const __hip_bfloat16* W1TH = mt;
    const __hip_bfloat16* W1TL = mt + 4096;
    const int brow = wv * 16 + lm;
    bf16x8 BH0 = *(const bf16x8*)(W1TH + brow * 64 + kg * 8);
    bf16x8 BH1 = *(const bf16x8*)(W1TH + brow * 64 + 32 + kg * 8);
    bf16x8 BL0 = *(const bf16x8*)(W1TL + brow * 64 + kg * 8);
    bf16x8 BL1 = *(const bf16x8*)(W1TL + brow * 64 + 32 + kg * 8);
#pragma unroll
    for (int mtI = 0; mtI < 3; ++mtI) {
      f32x4 acc = {0.f, 0.f, 0.f, 0.f};
      bf16x8 AH = *(const bf16x8*)(&XH[(mtI * 16 + lm) * 72 + kg * 8]);
      bf16x8 AL = *(const bf16x8*)(&XL[(mtI * 16 + lm) * 72 + kg * 8]);
      acc = MFMA16(AH, BH0, acc); acc = MFMA16(AH, BL0, acc); acc = MFMA16(AL, BH0, acc);
      AH = *(const bf16x8*)(&XH[(mtI * 16 + lm) * 72 + 32 + kg * 8]);
      AL = *(const bf16x8*)(&XL[(mtI * 16 + lm) * 72 + 32 + kg * 8]);
      acc = MFMA16(AH, BH1, acc); acc = MFMA16(AH, BL1, acc); acc = MFMA16(AL, BH1, acc);
      if (brow < 50) {
        int aidx = (brow < 25) ? 0 : 2;
        int u = (brow < 25) ? brow : brow - 25;
#pragma unroll
        for (int r = 0; r < 4; ++r) {
          int h = mtI * 16 + kg * 4 + r;
          float v = acc[r];
          __hip_bfloat16 hh = __float2bfloat16(v);
          Yt[aidx][u * 72 + h] = hh;
          Yt[aidx + 1][u * 72 + h] = __float2bfloat16(v - __bfloat162float(hh));
        }
      }
    }
  }
  __syncthreads();

  {
    const __hip_bfloat16* M2CH = mt + 8192;
    const __hip_bfloat16* M2CL = mt + 11264;
    const __hip_bfloat16* M2SH = mt + 14336;
    const __hip_bfloat16* M2SL = mt + 17408;
    for (int tt = wv; tt < 6; tt += 4) {
      int mtI = tt >> 1, ntI = tt & 1;
      f32x4 aC1 = {0.f,0.f,0.f,0.f}, aS1 = {0.f,0.f,0.f,0.f};
      f32x4 aC2 = {0.f,0.f,0.f,0.f}, aS2 = {0.f,0.f,0.f,0.f};
#pragma unroll
      for (int ks = 0; ks < 2; ++ks) {
        int arow = mtI * 16 + lm;
        int k0 = ks * 32 + kg * 8;
        bf16x8 CH = *(const bf16x8*)(M2CH + arow * 64 + k0);
        bf16x8 CL = *(const bf16x8*)(M2CL + arow * 64 + k0);
        bf16x8 SH = *(const bf16x8*)(M2SH + arow * 64 + k0);
        bf16x8 SL = *(const bf16x8*)(M2SL + arow * 64 + k0);
        int brow = ntI * 16 + lm;
        bf16x8 ReH = *(const bf16x8*)(&Yt[0][brow * 72 + k0]);
        bf16x8 ReL = *(const bf16x8*)(&Yt[1][brow * 72 + k0]);
        bf16x8 ImH = *(const bf16x8*)(&Yt[2][brow * 72 + k0]);
        bf16x8 ImL = *(const bf16x8*)(&Yt[3][brow * 72 + k0]);
        aC1 = MFMA16(CH, ReH, aC1); aC1 = MFMA16(CH, ReL, aC1); aC1 = MFMA16(CL, ReH, aC1);
        aS2 = MFMA16(SH, ImH, aS2); aS2 = MFMA16(SH, ImL, aS2); aS2 = MFMA16(SL, ImH, aS2);
        aC2 = MFMA16(CH, ImH, aC2); aC2 = MFMA16(CH, ImL, aC2); aC2 = MFMA16(CL, ImH, aC2);
        aS1 = MFMA16(SH, ReH, aS1); aS1 = MFMA16(SH, ReL, aS1); aS1 = MFMA16(SL, ReH, aS1);
      }
      int u = ntI * 16 + lm;
      if (u < 25) {
#pragma unroll
        for (int r = 0; r < 4; ++r) {
          int v = mtI * 16 + kg * 4 + r;
          float zre = aC1[r] + aS2[r];
          float zim = aC2[r] - aS1[r];
          float am = sqrtf(zre * zre + zim * zim);
          float ph = atan2f(zim, zre);
          int i = v * 25 + u;
          size_t o;
          if (tlay) o = ((size_t)(bc >> 5) * 1200 + i) * 32 + (bc & 31);
          else      o = (size_t)bc * 1200 + i;
          amp[o] = __float2bfloat16(am);
          pha[o] = __float2bfloat16(ph);
        }
      }
    }
  }
}

// ---------------- polar + irfft2 via MFMA -> hi/lo bf16 chunk-planar; XCD line-locality swizzle ----------------
// grid 1024 = 8 x 128; 128 % 32 == 0.
__global__ void __launch_bounds__(256)
polar_irfft2_mfma(const float* __restrict__ amp, const float* __restrict__ pha,
                  const __hip_bfloat16* __restrict__ mt,
                  __hip_bfloat16* __restrict__ oh, __hip_bfloat16* __restrict__ ol) {
  const int bc = (blockIdx.x & 7) * 128 + (blockIdx.x >> 3);
  __shared__ __align__(16) __hip_bfloat16 Zt[4][32 * 72];
  __shared__ __align__(16) __hip_bfloat16 Yp[4][48 * 56];
  const int tid = threadIdx.x;
  const int lane = tid & 63, lm = lane & 15, kg = lane >> 4, wv = tid >> 6;

  for (int i = tid; i < 4 * 32 * 72; i += 256) ((unsigned short*)Zt)[i] = 0;
  for (int i = tid; i < 4 * 48 * 56; i += 256) ((unsigned short*)Yp)[i] = 0;
  __syncthreads();
  for (int i = tid; i < 1200; i += 256) {
    int v = i / 25, u = i - v * 25;
    float a = amp[(size_t)bc * 1200 + i];
    float p = pha[(size_t)bc * 1200 + i];
    float sc = (u == 0 || u == 24) ? (1.f / 48.f) : (2.f / 48.f);
    float zre = a * cosf(p) * sc;
    float zim = a * sinf(p) * sc;
    __hip_bfloat16 h0 = __float2bfloat16(zre);
    Zt[0][u * 72 + v] = h0;
    Zt[1][u * 72 + v] = __float2bfloat16(zre - __bfloat162float(h0));
    __hip_bfloat16 h1 = __float2bfloat16(zim);
    Zt[2][u * 72 + v] = h1;
    Zt[3][u * 72 + v] = __float2bfloat16(zim - __bfloat162float(h1));
  }
  __syncthreads();

  {
    const __hip_bfloat16* M2CH = mt + 8192;
    const __hip_bfloat16* M2CL = mt + 11264;
    const __hip_bfloat16* M2SH = mt + 14336;
    const __hip_bfloat16* M2SL = mt + 17408;
    for (int t = wv; t < 6; t += 4) {
      int mtI = t >> 1, ntI = t & 1;
      f32x4 aC1 = {0.f,0.f,0.f,0.f}, aS1 = {0.f,0.f,0.f,0.f};
      f32x4 aC2 = {0.f,0.f,0.f,0.f}, aS2 = {0.f,0.f,0.f,0.f};
#pragma unroll
      for (int ks = 0; ks < 2; ++ks) {
        int arow = mtI * 16 + lm;
        int k0 = ks * 32 + kg * 8;
        bf16x8 CH = *(const bf16x8*)(M2CH + arow * 64 + k0);
        bf16x8 CL = *(const bf16x8*)(M2CL + arow * 64 + k0);
        bf16x8 SH = *(const bf16x8*)(M2SH + arow * 64 + k0);
        bf16x8 SL = *(const bf16x8*)(M2SL + arow * 64 + k0);
        int brow = ntI * 16 + lm;
        bf16x8 ReH = *(const bf16x8*)(&Zt[0][brow * 72 + k0]);
        bf16x8 ReL = *(const bf16x8*)(&Zt[1][brow * 72 + k0]);
        bf16x8 ImH = *(const bf16x8*)(&Zt[2][brow * 72 + k0]);
        bf16x8 ImL = *(const bf16x8*)(&Zt[3][brow * 72 + k0]);
        aC1 = MFMA16(CH, ReH, aC1); aC1 = MFMA16(CH, ReL, aC1); aC1 = MFMA16(CL, ReH, aC1);
        aS2 = MFMA16(SH, ImH, aS2); aS2 = MFMA16(SH, ImL, aS2); aS2 = MFMA16(SL, ImH, aS2);
        aC2 = MFMA16(CH, ImH, aC2); aC2 = MFMA16(CH, ImL, aC2); aC2 = MFMA16(CL, ImH, aC2);
        aS1 = MFMA16(SH, ReH, aS1); aS1 = MFMA16(SH, ReL, aS1); aS1 = MFMA16(SL, ReH, aS1);
      }
      int u = ntI * 16 + lm;
      if (u < 25) {
#pragma unroll
        for (int r = 0; r < 4; ++r) {
          int h = mtI * 16 + kg * 4 + r;
          float yre = aC1[r] - aS2[r];
          float yim = aS1[r] + aC2[r];
          __hip_bfloat16 h0 = __float2bfloat16(yre);
          Yp[0][h * 56 + u] = h0;
          Yp[1][h * 56 + u] = __float2bfloat16(yre - __bfloat162float(h0));
          __hip_bfloat16 h1 = __float2bfloat16(yim);
          Yp[2][h * 56 + u] = h1;
          Yp[3][h * 56 + u] = __float2bfloat16(yim - __bfloat162float(h1));
        }
      }
    }
  }
  __syncthreads();

  {
    const __hip_bfloat16* W3CH = mt + 20480;
    const __hip_bfloat16* W3CL = mt + 22016;
    const __hip_bfloat16* W3SH = mt + 23552;   // -sin
    const __hip_bfloat16* W3SL = mt + 25088;
    const int cch = bc & 255;
    const size_t obase = ((size_t)((bc >> 8) * 8 + (cch >> 5)) * HW) * 32 + (cch & 31);
    for (int t = wv; t < 9; t += 4) {
      int mtI = t / 3, ntI = t - (t / 3) * 3;
      f32x4 acc = {0.f, 0.f, 0.f, 0.f};
      int k0 = kg * 8;
      bf16x8 AH = *(const bf16x8*)(&Yp[0][(mtI * 16 + lm) * 56 + k0]);
      bf16x8 AL = *(const bf16x8*)(&Yp[1][(mtI * 16 + lm) * 56 + k0]);
      bf16x8 IH = *(const bf16x8*)(&Yp[2][(mtI * 16 + lm) * 56 + k0]);
      bf16x8 IL = *(const bf16x8*)(&Yp[3][(mtI * 16 + lm) * 56 + k0]);
      int brow = ntI * 16 + lm;
      bf16x8 CH = *(const bf16x8*)(W3CH + brow * 32 + k0);
      bf16x8 CL = *(const bf16x8*)(W3CL + brow * 32 + k0);
      bf16x8 SH = *(const bf16x8*)(W3SH + brow * 32 + k0);
      bf16x8 SL = *(const bf16x8*)(W3SL + brow * 32 + k0);
      acc = MFMA16(AH, CH, acc); acc = MFMA16(AH, CL, acc); acc = MFMA16(AL, CH, acc);
      acc = MFMA16(IH, SH, acc); acc = MFMA16(IH, SL, acc); acc = MFMA16(IL, SH, acc);
#pragma unroll
      for (int r = 0; r < 4; ++r) {
        int h = mtI * 16 + kg * 4 + r;
        int p = h * 48 + brow;
        float v = acc[r];
        __hip_bfloat16 hh = __float2bfloat16(v);
        oh[obase + (size_t)p * 32] = hh;
        ol[obase + (size_t)p * 32] = __float2bfloat16(v - __bfloat162float(hh));
      }
    }
  }
}

// ---------------- MFMA attention v5p: 64-key tiles + ballot defer-max + XCD swizzle + setprio ----------------
__global__ void __launch_bounds__(64)
attn_mfma5(const __hip_bfloat16* __restrict__ Qb, const __hip_bfloat16* __restrict__ Kb,
           const __hip_bfloat16* __restrict__ Vb, float* __restrict__ Ob) {
  const int lin = blockIdx.x;
  const int xcd = lin & 7;
  const int idx = lin >> 3;          // 0..599
  const int pr = xcd * 8 + idx / 75; // 0..63
  const int m0 = (idx % 75) * 16;
  const int z = pr >> 5;
  const int bh = pr & 31;
  const __hip_bfloat16* Qt = Qb + (size_t)z * 1228800;
  const __hip_bfloat16* Kt = Kb + (size_t)z * 1228800;
  const __hip_bfloat16* Vc = Vb + (size_t)z * 1228800;
  float* Om = Ob + (size_t)z * 1228800;
  const int lane = threadIdx.x;
  const int lm = lane & 15, kg = lane >> 4;
  __shared__ unsigned short Pl[2][16][40];
  __shared__ float fl[16];
  __shared__ float linv[16];
  const __hip_bfloat16* Qp = Qt + ((size_t)bh * 1200 + m0) * 32;
  const __hip_bfloat16* Kp = Kt + (size_t)bh * 38400;
  const __hip_bfloat16* Vp = Vc + (size_t)bh * 38400;
  const bf16x8 qf = *(const bf16x8*)(Qp + lm * 32 + kg * 8);
  const float Cs = ATT_SCALE * 1.44269504f;

  f32x4 acc0 = {0.f, 0.f, 0.f, 0.f}, acc1 = {0.f, 0.f, 0.f, 0.f};
  float psum = 0.f, mreg = -3.0e38f;

  for (int G = 0; G < 19; ++G) {
    const int n0 = G * 64;
    const bool s3ok = (G < 18);      // keys n0+48..n0+63 valid
    bf16x8 kf0 = *(const bf16x8*)(Kp + (size_t)(n0 + lm) * 32 + kg * 8);
    bf16x8 kf1 = *(const bf16x8*)(Kp + (size_t)(n0 + 16 + lm) * 32 + kg * 8);
    bf16x8 kf2 = *(const bf16x8*)(Kp + (size_t)(n0 + 32 + lm) * 32 + kg * 8);
    __builtin_amdgcn_s_setprio(1);
    f32x4 d0 = {0.f, 0.f, 0.f, 0.f}; d0 = MFMA16(kf0, qf, d0);
    f32x4 d1 = {0.f, 0.f, 0.f, 0.f}; d1 = MFMA16(kf1, qf, d1);
    f32x4 d2 = {0.f, 0.f, 0.f, 0.f}; d2 = MFMA16(kf2, qf, d2);
    f32x4 d3 = {0.f, 0.f, 0.f, 0.f};
    if (s3ok) {
      bf16x8 kf3 = *(const bf16x8*)(Kp + (size_t)(n0 + 48 + lm) * 32 + kg * 8);
      d3 = MFMA16(kf3, qf, d3);
    }
    __builtin_amdgcn_s_setprio(0);
    float tm = fmaxf(fmaxf(fmaxf(d0[0], d0[1]), fmaxf(d0[2], d0[3])),
                     fmaxf(fmaxf(d1[0], d1[1]), fmaxf(d1[2], d1[3])));
    tm = fmaxf(tm, fmaxf(fmaxf(d2[0], d2[1]), fmaxf(d2[2], d2[3])));
    if (s3ok) tm = fmaxf(tm, fmaxf(fmaxf(d3[0], d3[1]), fmaxf(d3[2], d3[3])));
    tm = fmaxf(tm, __shfl_xor(tm, 16));
    tm = fmaxf(tm, __shfl_xor(tm, 32));
    const bool grow = (__ballot(tm > mreg) != 0ull);   // wave-uniform
    if (grow) {
      float nm = fmaxf(mreg, tm);
      float ff = exp2f((mreg - nm) * Cs);
      mreg = nm;
      if (kg == 0) fl[lm] = ff;
      psum *= ff;
    }
    const float mb = mreg * Cs;
    float p0 = exp2f(d0[0] * Cs - mb), p1 = exp2f(d0[1] * Cs - mb);
    float p2 = exp2f(d0[2] * Cs - mb), p3 = exp2f(d0[3] * Cs - mb);
    float p4 = exp2f(d1[0] * Cs - mb), p5 = exp2f(d1[1] * Cs - mb);
    float p6 = exp2f(d1[2] * Cs - mb), p7 = exp2f(d1[3] * Cs - mb);
    float p8 = exp2f(d2[0] * Cs - mb), p9 = exp2f(d2[1] * Cs - mb);
    float pa_ = exp2f(d2[2] * Cs - mb), pb_ = exp2f(d2[3] * Cs - mb);
    float ps = p0 + p1 + p2 + p3 + p4 + p5 + p6 + p7 + p8 + p9 + pa_ + pb_;
    ushort4 w0, w1, w2, w3;
    w0.x = __builtin_bit_cast(unsigned short, __float2bfloat16(p0));
    w0.y = __builtin_bit_cast(unsigned short, __float2bfloat16(p1));
    w0.z = __builtin_bit_cast(unsigned short, __float2bfloat16(p2));
    w0.w = __builtin_bit_cast(unsigned short, __float2bfloat16(p3));
    w1.x = __builtin_bit_cast(unsigned short, __float2bfloat16(p4));
    w1.y = __builtin_bit_cast(unsigned short, __float2bfloat16(p5));
    w1.z = __builtin_bit_cast(unsigned short, __float2bfloat16(p6));
    w1.w = __builtin_bit_cast(unsigned short, __float2bfloat16(p7));
    w2.x = __builtin_bit_cast(unsigned short, __float2bfloat16(p8));
    w2.y = __builtin_bit_cast(unsigned short, __float2bfloat16(p9));
    w2.z = __builtin_bit_cast(unsigned short, __float2bfloat16(pa_));
    w2.w = __builtin_bit_cast(unsigned short, __float2bfloat16(pb_));
    if (s3ok) {
      float pc_ = exp2f(d3[0] * Cs - mb), pd_ = exp2f(d3[1] * Cs - mb);
      float pe_ = exp2f(d3[2] * Cs - mb), pf_ = exp2f(d3[3] * Cs - mb);
      ps += pc_ + pd_ + pe_ + pf_;
      w3.x = __builtin_bit_cast(unsigned short, __float2bfloat16(pc_));
      w3.y = __builtin_bit_cast(unsigned short, __float2bfloat16(pd_));
      w3.z = __builtin_bit_cast(unsigned short, __float2bfloat16(pe_));
      w3.w = __builtin_bit_cast(unsigned short, __float2bfloat16(pf_));
    } else {
      w3.x = w3.y = w3.z = w3.w = 0;
    }
    psum += ps;
    *(ushort4*)(&Pl[0][lm][kg * 4]) = w0;
    *(ushort4*)(&Pl[0][lm][16 + kg * 4]) = w1;
    *(ushort4*)(&Pl[1][lm][kg * 4]) = w2;
    *(ushort4*)(&Pl[1][lm][16 + kg * 4]) = w3;
    if (grow) {
      float4 f4 = *(const float4*)(&fl[kg * 4]);
      acc0[0] *= f4.x; acc0[1] *= f4.y; acc0[2] *= f4.z; acc0[3] *= f4.w;
      acc1[0] *= f4.x; acc1[1] *= f4.y; acc1[2] *= f4.z; acc1[3] *= f4.w;
    }
    bf16x8 pa0 = *(const bf16x8*)(&Pl[0][lm][kg * 8]);
    bf16x8 pa1 = *(const bf16x8*)(&Pl[1][lm][kg * 8]);
    bf16x8 v00 = *(const bf16x8*)(Vp + (size_t)lm * 1200 + n0 + kg * 8);
    bf16x8 v01 = *(const bf16x8*)(Vp + (size_t)(16 + lm) * 1200 + n0 + kg * 8);
    bf16x8 v10 = *(const bf16x8*)(Vp + (size_t)lm * 1200 + n0 + 32 + kg * 8);
    bf16x8 v11 = *(const bf16x8*)(Vp + (size_t)(16 + lm) * 1200 + n0 + 32 + kg * 8);
    __builtin_amdgcn_s_setprio(1);
    acc0 = MFMA16(pa0, v00, acc0);
    acc1 = MFMA16(pa0, v01, acc1);
    acc0 = MFMA16(pa1, v10, acc0);
    acc1 = MFMA16(pa1, v11, acc1);
    __builtin_amdgcn_s_setprio(0);
  }
  psum += __shfl_xor(psum, 16);
  psum += __shfl_xor(psum, 32);
  if (kg == 0) linv[lm] = 1.f / psum;
  __syncthreads();
#pragma unroll
  for (int r = 0; r < 4; ++r) {
    int m = m0 + kg * 4 + r;
    float li = linv[kg * 4 + r];
    Om[(size_t)bh * 38400 + (size_t)lm * 1200 + m] = acc0[r] * li;
    Om[(size_t)bh * 38400 + (size_t)(16 + lm) * 1200 + m] = acc1[r] * li;
  }
}

// ---------------- pack3: packw(w1) + packw(w2) + packx(ATT) + pad-zero Xp1/Xp2; grid 1290 ----------------
// Runs AFTER OUTH/Qb (which alias Xp1/Xp2) are dead — pads must be zeroed here, not earlier.
__global__ void pack3_kernel(const float* __restrict__ w1, const float* __restrict__ w2,
                             const float* __restrict__ att,
                             __hip_bfloat16* __restrict__ Wp1, __hip_bfloat16* __restrict__ Wp2,
                             __hip_bfloat16* __restrict__ xp, __hip_bfloat16* __restrict__ Xp2) {
  const int b = blockIdx.x, tid = threadIdx.x;
  if (b < 512) {              // w1: [512 o][256 c][9] -> [tap][8][512][32]
    int t = b * 256 + tid;
    int o = t >> 8, c = t & 255;
#pragma unroll
    for (int tap = 0; tap < 9; ++tap)
      Wp1[(((size_t)tap * 8 + (c >> 5)) * 512 + o) * 32 + (c & 31)] = __float2bfloat16(w1[(size_t)t * 9 + tap]);
  } else if (b < 1024) {      // w2: [256 o][512 c][9] -> [tap][16][256][32]
    int t = (b - 512) * 256 + tid;
    int o = t >> 9, c = t & 511;
#pragma unroll
    for (int tap = 0; tap < 9; ++tap)
      Wp2[(((size_t)tap * 16 + (c >> 5)) * 256 + o) * 32 + (c & 31)] = __float2bfloat16(w2[(size_t)t * 9 + tap]);
  } else if (b < 1216) {      // packx: ATT f32 NCHW -> bf16 chunk-planar padded (interior)
    int s = b - 1024;         // 0..191
    int y = s % 48, img = s / 48;
    int c = tid;
    const float* ip = att + ((size_t)(img * 256 + c) * 48 + y) * 48;
    __hip_bfloat16* op = xp + ((size_t)(img * 8 + (c >> 5)) * 2500 + (size_t)(y + 1) * 50 + 1) * 32 + (c & 31);
    for (int x = 0; x < 48; ++x) op[x * 32] = __float2bfloat16(ip[x]);
  } else {                    // pad-zero borders: Xp1 32 planes + Xp2 64 planes, 196 cells/plane
    int idx = (b - 1216) * 256 + tid;
    if (idx < 18816) {
      __hip_bfloat16* base;
      int plane, cell;
      if (idx < 6272) { base = xp; plane = idx / 196; cell = idx % 196; }
      else { int j = idx - 6272; base = Xp2; plane = j / 196; cell = j % 196; }
      int row, col;
      if (cell < 50) { row = 0; col = cell; }
      else if (cell < 100) { row = 49; col = cell - 50; }
      else if (cell < 148) { row = 1 + (cell - 100); col = 0; }
      else { row = 1 + (cell - 148); col = 49; }
      float4* p = (float4*)(base + ((size_t)plane * 2500 + row * 50 + col) * 32);
      float4 z = make_float4(0.f, 0.f, 0.f, 0.f);
      p[0] = z; p[1] = z; p[2] = z; p[3] = z;
    }
  }
}

// ---------------- addpack: (a + b) f32 NCHW -> hi/lo bf16 chunk-planar; XCD line-locality swizzle ----------------
// grid 2304 = 8 x 288; one 32-channel chunk = 72 blocks; 288 % 72 == 0.
__global__ void addpack_kernel(const float* __restrict__ a, const float* __restrict__ b,
                               __hip_bfloat16* __restrict__ oh, __hip_bfloat16* __restrict__ ol) {
  int i = ((blockIdx.x & 7) * 288 + (blockIdx.x >> 3)) * 256 + threadIdx.x;  // float4 index over U/4
  float4 x = ((const float4*)a)[i];
  float4 y = ((const float4*)b)[i];
  x.x += y.x; x.y += y.y; x.z += y.z; x.w += y.w;
  int e = i * 4;
  int img = e / 589824, rem = e - img * 589824;
  int c = rem / 2304, px = rem - c * 2304;
  size_t ob = ((size_t)(img * 8 + (c >> 5)) * HW) * 32 + (c & 31);
  float vv[4] = {x.x, x.y, x.z, x.w};
#pragma unroll
  for (int j = 0; j < 4; ++j) {
    __hip_bfloat16 h = __float2bfloat16(vv[j]);
    oh[ob + (size_t)(px + j) * 32] = h;
    ol[ob + (size_t)(px + j) * 32] = __float2bfloat16(vv[j] - __bfloat162float(h));
  }
}

// ---------------- MFMA 3x3 conv v8: LDS-staged chunks (proven: 0 bank conflicts) ----------------
template <int CIN, int CO, bool TO_PAD, int KS>
__global__ void __launch_bounds__(256)
mfconv3x3(const __hip_bfloat16* __restrict__ Xp, const __hip_bfloat16* __restrict__ Wp,
          __hip_bfloat16* __restrict__ Op, float* __restrict__ Of) {
  constexpr int NC = CIN / 32;
  constexpr int KC = NC / KS;
  constexpr int MT = CO / 32;
  const int q = gridDim.x >> 3;
  const int swz = (blockIdx.x & 7) * q + (blockIdx.x >> 3);
  const int mt = swz % MT;
  const int ks = (swz / MT) % KS;
  const int rq = swz / (MT * KS);       // 0..47
  const int img = rq / 12;
  const int y0b = (rq % 12) * 4;
  const int tid = threadIdx.x;
  const int wv = tid >> 6;
  const int y = y0b + wv;
  const int lane = tid & 63;
  const int lm = lane & 15, kg = lane >> 4;
  const int o0 = mt * 32;
  const int ci0 = ks * KC;

  __shared__ __hip_bfloat16 Als[9216];   // [tap][32o][32c]
  __shared__ __hip_bfloat16 Bls[9600];   // [6 rows][50][32c]

  f32x4 acc[2][3];
#pragma unroll
  for (int f = 0; f < 2; ++f)
#pragma unroll
    for (int g = 0; g < 3; ++g) acc[f][g] = (f32x4){0.f, 0.f, 0.f, 0.f};

  for (int ci = 0; ci < KC; ++ci) {
    const int cic = ci0 + ci;
    const size_t wst = ((size_t)cic * CO + o0) * 32;
    const size_t bst = ((size_t)(img * NC + cic) * 2500 + (size_t)y0b * 50) * 32;
    __syncthreads();
    for (int c = tid; c < 2352; c += 256) {
      if (c < 1152) {
        int tap = c >> 7, rem = c & 127;
        float4 v = *(const float4*)(Wp + wst + (size_t)tap * (NC * CO * 32) + rem * 8);
        *(float4*)(&Als[c * 8]) = v;
      } else {
        int c2 = c - 1152;
        float4 v = *(const float4*)(Xp + bst + (size_t)c2 * 8);
        *(float4*)(&Bls[c2 * 8]) = v;
      }
    }
    __syncthreads();
#pragma unroll
    for (int tap = 0; tap < 9; ++tap) {
      const int dy = tap / 3 - 1, dx = tap - (tap / 3) * 3 - 1;
      bf16x8 A0 = *(const bf16x8*)(&Als[tap * 1024 + lm * 32 + kg * 8]);
      bf16x8 A1 = *(const bf16x8*)(&Als[tap * 1024 + 512 + lm * 32 + kg * 8]);
      const int bbase = ((wv + 1 + dy) * 50 + 1 + dx + lm) * 32 + kg * 8;
      bf16x8 B0 = *(const bf16x8*)(&Bls[bbase]);
      bf16x8 B1 = *(const bf16x8*)(&Bls[bbase + 512]);
      bf16x8 B2 = *(const bf16x8*)(&Bls[bbase + 1024]);
      acc[0][0] = MFMA16(A0, B0, acc[0][0]);
      acc[0][1] = MFMA16(A0, B1, acc[0][1]);
      acc[0][2] = MFMA16(A0, B2, acc[0][2]);
      acc[1][0] = MFMA16(A1, B0, acc[1][0]);
      acc[1][1] = MFMA16(A1, B1, acc[1][1]);
      acc[1][2] = MFMA16(A1, B2, acc[1][2]);
    }
  }

  if (TO_PAD) {
    const int cio = o0 >> 5;
#pragma unroll
    for (int f = 0; f < 2; ++f) {
      const int cc = f * 16 + kg * 4;
#pragma unroll
      for (int g = 0; g < 3; ++g) {
        int x = g * 16 + lm;
        ushort4 st;
        float v0 = acc[f][g][0], v1 = acc[f][g][1], v2 = acc[f][g][2], v3 = acc[f][g][3];
        v0 = v0 / (1.f + __expf(-v0)); v1 = v1 / (1.f + __expf(-v1));
        v2 = v2 / (1.f + __expf(-v2)); v3 = v3 / (1.f + __expf(-v3));
        st.x = __builtin_bit_cast(unsigned short, __float2bfloat16(v0));
        st.y = __builtin_bit_cast(unsigned short, __float2bfloat16(v1));
        st.z = __builtin_bit_cast(unsigned short, __float2bfloat16(v2));
        st.w = __builtin_bit_cast(unsigned short, __float2bfloat16(v3));
        *(ushort4*)(Op + (((size_t)(img * (CO / 32) + cio) * 2500 + (size_t)(y + 1) * 50 + (x + 1)) * 32 + cc)) = st;
      }
    }
  } else {
    float* Ofp = Of + (size_t)ks * 4 * CO * HW;
#pragma unroll
    for (int f = 0; f < 2; ++f)
#pragma unroll
      for (int g = 0; g < 3; ++g) {
        int x = g * 16 + lm;
#pragma unroll
        for (int r = 0; r < 4; ++r) {
          int o = o0 + f * 16 + kg * 4 + r;
          Ofp[((size_t)img * CO + o) * HW + y * 48 + x] = acc[f][g][r];
        }
      }
  }
}

extern "C" void kernel_launch(void* const* d_in, const int* in_sizes, int n_in,
                              void* d_out, int out_size, void* d_ws, size_t ws_size,
                              hipStream_t stream) {
  (void)in_sizes; (void)n_in; (void)out_size; (void)ws_size;
  const float* x      = (const float*)d_in[0];
  const float* cond   = (const float*)d_in[1];
  const float* gn_w   = (const float*)d_in[2];
  const float* gn_b   = (const float*)d_in[3];
  const float* q_dw   = (const float*)d_in[4];
  const float* q_pw_w = (const float*)d_in[5];
  const float* q_pw_b = (const float*)d_in[6];
  const float* kv_dw  = (const float*)d_in[7];
  const float* kv_pw_w= (const float*)d_in[8];
  const float* kv_pw_b= (const float*)d_in[9];
  const float* ao_w   = (const float*)d_in[10];
  const float* ao_b   = (const float*)d_in[11];
  const float* w1     = (const float*)d_in[12];
  const float* w2     = (const float*)d_in[13];
  const float* w3     = (const float*)d_in[14];
  const float* b3     = (const float*)d_in[15];
  float* ws = (float*)d_ws;
  float* Yo = (float*)d_out;

  const size_t U = 2359296;   // 4*256*48*48 (floats)
  const size_t Hf = 1228800;  // 4*256*48*25 (floats)
  const size_t CS = 589824;   // 256*2304
  const size_t CS2 = 1179648; // 512*2304

  float* XN  = ws;             // [0,U)
  __hip_bfloat16* DWH = (__hip_bfloat16*)(ws + U);       // [U,2U) as 2x bf16 planes
  __hip_bfloat16* DWL = DWH + 2359296;
  float* Qb  = ws + 2 * U;
  float* KV  = ws + 3 * U;     // 2U extent
  __hip_bfloat16* AQT = (__hip_bfloat16*)(ws + 5 * U);
  __hip_bfloat16* AKT = AQT + 2 * 1228800;
  __hip_bfloat16* AVc = AQT + 4 * 1228800;
  float* AO  = ws + 5 * U + 3 * Hf;
  float* PO  = AO + Hf;
  __hip_bfloat16* OUTH = (__hip_bfloat16*)(ws + U);      // reuse dead DW region
  __hip_bfloat16* OUTL = OUTH + 2359296;
  float* ATT = ws + 5 * U;
  __hip_bfloat16* Xp1 = (__hip_bfloat16*)(ws + U);
  __hip_bfloat16* Xp2 = (__hip_bfloat16*)(ws + 2 * U);
  __hip_bfloat16* Wp1 = (__hip_bfloat16*)(ws + 2 * U + 2600000);
  __hip_bfloat16* Wp2 = (__hip_bfloat16*)(ws + 2 * U + 3200000);
  float* H2  = ws;             // K-split partial 0 at [0,U); partial 1 at [U,2U)
  float* H2b = ws + U;
  __hip_bfloat16* H2H = (__hip_bfloat16*)(ws + 5 * U + 3 * Hf);  // reuse dead AO/PO
  __hip_bfloat16* H2L = H2H + 2359296;
  // pw weights (chunk-planar hi/lo bf16) + DFT matrices + gn partials in dead tail
  __hip_bfloat16* BW = (__hip_bfloat16*)(ws + 5 * U + 5 * Hf);
  __hip_bfloat16* QWH = BW,            * QWL = BW + 65536;
  __hip_bfloat16* KWH = BW + 131072,   * KWL = BW + 262144;
  __hip_bfloat16* AWH = BW + 393216,   * AWL = BW + 458752;
  __hip_bfloat16* W3H = BW + 524288,   * W3L = BW + 589824;
  __hip_bfloat16* MT  = BW + 655360;   // 26624 bf16
  float* GNP = ws + 5 * U + 5 * Hf + 341000;   // 1024 floats

  // 0. one-launch setup: pw weight packs + DFT tables
  setup_kernel<<<1314, 256, 0, stream>>>(q_pw_w, kv_pw_w, ao_w, w3,
                                         QWH, QWL, KWH, KWL, AWH, AWL, W3H, W3L, MT);
  // 1. GroupNorm
  gn1_kernel<<<512, 256, 0, stream>>>(x, GNP);
  gn2_kernel<<<512, 256, 0, stream>>>(x, GNP, gn_w, gn_b, XN);
  // 2-3. q path
  dw3x3_kernel<<<1024, 256, 0, stream>>>(XN, q_dw, DWH, DWL);
  pw5_kernel<false><<<dim3(18, 4, 4), 256, 0, stream>>>(DWH, DWL, QWH, QWL, q_pw_b, nullptr, 0, Qb, CS, 256);
  // 4-5. kv path
  dw3x3_kernel<<<1024, 256, 0, stream>>>(cond, kv_dw, DWH, DWL);
  pw5_kernel<false><<<dim3(18, 8, 4), 256, 0, stream>>>(DWH, DWL, KWH, KWL, kv_pw_b, nullptr, 0, KV, CS2, 512);
  // 6. L2 norm (q,k,v fused)
  l2n3_kernel<<<dim3(36, 12), 256, 0, stream>>>(Qb, KV);
  // 7. rfft2 (q,k,v fused) via MFMA -> bf16 spectra
  rfft2_all<<<3072, 256, 0, stream>>>(Qb, KV, MT, AQT);
  // 8. MFMA attention v5p
  attn_mfma5<<<4800, 64, 0, stream>>>(AQT, AKT, AVc, AO);
  // 9. polar + irfft2 via MFMA -> hi/lo chunk-planar
  polar_irfft2_mfma<<<1024, 256, 0, stream>>>(AO, PO, MT, OUTH, OUTL);
  // 10. attn_out = 1x1(out) + b + xn  -> ATT (f32 NCHW)
  pw5_kernel<true><<<dim3(18, 4, 4), 256, 0, stream>>>(OUTH, OUTL, AWH, AWL, ao_b, XN, CS, ATT, CS, 256);
  // 11. pack conv weights + input + pad-zero (fused), then FFN convs
  pack3_kernel<<<1290, 256, 0, stream>>>(w1, w2, ATT, Wp1, Wp2, Xp1, Xp2);
  mfconv3x3<256, 512, true, 1><<<768, 256, 0, stream>>>(Xp1, Wp1, Xp2, nullptr);
  mfconv3x3<512, 256, false, 2><<<768, 256, 0, stream>>>(Xp2, Wp2, nullptr, H2);
  // merge K-split partials + pack to hi/lo chunk-planar
  addpack_kernel<<<2304, 256, 0, stream>>>(H2, H2b, H2H, H2L);
  // 12. out = 1x1(h2) + b3 + attn_out
  pw5_kernel<true><<<dim3(18, 4, 4), 256, 0, stream>>>(H2H, H2L, W3H, W3L, b3, ATT, CS, Yo, CS, 256);
}